// Round 1
// baseline (174.490 us; speedup 1.0000x reference)
//
#include <hip/hip_runtime.h>

// Problem shapes (fixed by setup_inputs)
#define B_  16
#define TE_ 256
#define TD_ 128
#define H_  512

#define C_TANH 2.88539008177792681472f  // 2*log2(e):  tanh(x) = 1 - 2/(exp2(C*x)+1)
#define LOG2E  1.44269504088896340736f

__device__ __forceinline__ float wave_sum(float v) {
#pragma unroll
  for (int m = 32; m; m >>= 1) v += __shfl_xor(v, m, 64);
  return v;
}
__device__ __forceinline__ float wave_max(float v) {
#pragma unroll
  for (int m = 32; m; m >>= 1) v = fmaxf(v, __shfl_xor(v, m, 64));
  return v;
}

// ---------------------------------------------------------------------------
// Generic fp32 tiled GEMM: C[M,N] = A[M,K] @ B[K,N], row-major, optional batch
// via blockIdx.z with element strides sA/sB/sC. BM=BN=64, BK=16, 256 threads,
// 4x4 micro-tile per thread. M,N multiples of 64; K multiple of 16.
// ---------------------------------------------------------------------------
__global__ __launch_bounds__(256) void gemm_f32(
    const float* __restrict__ A, int lda, long sA,
    const float* __restrict__ Bm, int ldb, long sB,
    float* __restrict__ C, int ldc, long sC, int K)
{
  __shared__ float As[16][68];   // transposed A tile [k][m], padded (68: 2-way max)
  __shared__ float Bs[16][64];   // B tile [k][n]

  const int tid = threadIdx.x;
  const int tx = tid & 15, ty = tid >> 4;
  const long bz = blockIdx.z;

  const float* Ap = A + bz * sA + (long)(blockIdx.y * 64 + (tid >> 2)) * lda + ((tid & 3) << 2);
  const float* Bp = Bm + bz * sB + (long)(tid >> 4) * ldb + blockIdx.x * 64 + ((tid & 15) << 2);
  float* Cp = C + bz * sC;

  float acc[4][4] = {};

  for (int kt = 0; kt < K; kt += 16) {
    float4 av = *(const float4*)(Ap + kt);
    float4 bv = *(const float4*)(Bp + (long)kt * ldb);
    const int ar = tid >> 2, ac = (tid & 3) << 2;
    As[ac + 0][ar] = av.x;
    As[ac + 1][ar] = av.y;
    As[ac + 2][ar] = av.z;
    As[ac + 3][ar] = av.w;
    *(float4*)&Bs[tid >> 4][(tid & 15) << 2] = bv;
    __syncthreads();
#pragma unroll
    for (int k = 0; k < 16; ++k) {
      float4 a = *(const float4*)&As[k][ty << 2];
      float4 b = *(const float4*)&Bs[k][tx << 2];
      float ae[4] = {a.x, a.y, a.z, a.w};
      float be[4] = {b.x, b.y, b.z, b.w};
#pragma unroll
      for (int i = 0; i < 4; ++i)
#pragma unroll
        for (int j = 0; j < 4; ++j)
          acc[i][j] = fmaf(ae[i], be[j], acc[i][j]);
    }
    __syncthreads();
  }

  const int r0 = blockIdx.y * 64 + (ty << 2);
  const int c0 = blockIdx.x * 64 + (tx << 2);
#pragma unroll
  for (int i = 0; i < 4; ++i) {
    float4 v = {acc[i][0], acc[i][1], acc[i][2], acc[i][3]};
    *(float4*)(Cp + (long)(r0 + i) * ldc + c0) = v;
  }
}

// ---------------------------------------------------------------------------
// Energies + softmax.
// One workgroup = (batch b, block of DT decoder rows). 4 waves; wave w streams
// encoder rows t = w*64 + i. Lane owns h-slices [lane*4, lane*4+4) and
// [256+lane*4, 256+lane*4+4); Uh*C and V live in registers for the whole
// t-loop.  logit[d][t] = sum_h V_h * tanh(Ws+Uh)
//                      = sum_h V_h - 2 * sum_h V_h * rcp(exp2(C*(Ws+Uh))+1)
// Then per-row softmax over t, written to e_out.
// ---------------------------------------------------------------------------
#define DT 4
__global__ __launch_bounds__(256) void energies_softmax(
    const float* __restrict__ Ws, const float* __restrict__ Uh,
    const float* __restrict__ Va, float* __restrict__ e_out)
{
  __shared__ float logits[DT][TE_];
  const int lane = threadIdx.x & 63;
  const int wv = threadIdx.x >> 6;
  const int b = blockIdx.y;
  const int d0 = blockIdx.x * DT;
  const int h0 = lane << 2;

  float uhc[DT][8], vr[8];
#pragma unroll
  for (int d = 0; d < DT; ++d) {
    const float* up = Uh + (size_t)(b * TD_ + d0 + d) * H_;
    float4 u0 = *(const float4*)(up + h0);
    float4 u1 = *(const float4*)(up + 256 + h0);
    uhc[d][0] = u0.x * C_TANH; uhc[d][1] = u0.y * C_TANH;
    uhc[d][2] = u0.z * C_TANH; uhc[d][3] = u0.w * C_TANH;
    uhc[d][4] = u1.x * C_TANH; uhc[d][5] = u1.y * C_TANH;
    uhc[d][6] = u1.z * C_TANH; uhc[d][7] = u1.w * C_TANH;
  }
  {
    float4 v0 = *(const float4*)(Va + h0);
    float4 v1 = *(const float4*)(Va + 256 + h0);
    vr[0] = v0.x; vr[1] = v0.y; vr[2] = v0.z; vr[3] = v0.w;
    vr[4] = v1.x; vr[5] = v1.y; vr[6] = v1.z; vr[7] = v1.w;
  }
  float sv = 0.f;
#pragma unroll
  for (int j = 0; j < 8; ++j) sv += vr[j];
  const float svtot = wave_sum(sv);

  const float4* wp = (const float4*)(Ws + (size_t)(b * TE_) * H_);  // 128 float4 per row

  float4 a0 = wp[(wv * 64) * 128 + lane];
  float4 a1 = wp[(wv * 64) * 128 + 64 + lane];
  for (int i = 0; i < 64; ++i) {
    const int t = wv * 64 + i;
    float4 c0 = a0, c1 = a1;
    if (i + 1 < 64) {  // uniform branch; prefetch next encoder row
      a0 = wp[(t + 1) * 128 + lane];
      a1 = wp[(t + 1) * 128 + 64 + lane];
    }
    float wsc[8] = {c0.x * C_TANH, c0.y * C_TANH, c0.z * C_TANH, c0.w * C_TANH,
                    c1.x * C_TANH, c1.y * C_TANH, c1.z * C_TANH, c1.w * C_TANH};
    float acc[DT] = {0.f, 0.f, 0.f, 0.f};
#pragma unroll
    for (int d = 0; d < DT; ++d)
#pragma unroll
      for (int j = 0; j < 8; ++j) {
        float r = __builtin_amdgcn_rcpf(
            __builtin_amdgcn_exp2f(wsc[j] + uhc[d][j]) + 1.0f);
        acc[d] = fmaf(vr[j], r, acc[d]);
      }
#pragma unroll
    for (int d = 0; d < DT; ++d) {
      float s = wave_sum(acc[d]);
      if (lane == 0) logits[d][t] = svtot - 2.0f * s;
    }
  }
  __syncthreads();

  // softmax over t for row d = wv (DT == number of waves)
  {
    float l[4];
#pragma unroll
    for (int q = 0; q < 4; ++q) l[q] = logits[wv][lane + 64 * q];
    float m = fmaxf(fmaxf(l[0], l[1]), fmaxf(l[2], l[3]));
    m = wave_max(m);
    float p[4];
    float s = 0.f;
#pragma unroll
    for (int q = 0; q < 4; ++q) {
      p[q] = __builtin_amdgcn_exp2f((l[q] - m) * LOG2E);
      s += p[q];
    }
    s = wave_sum(s);
    const float inv = 1.0f / s;
    float* ep = e_out + (size_t)(b * TD_ + d0 + wv) * TE_;
#pragma unroll
    for (int q = 0; q < 4; ++q) ep[lane + 64 * q] = p[q] * inv;
  }
}

// ---------------------------------------------------------------------------
extern "C" void kernel_launch(void* const* d_in, const int* in_sizes, int n_in,
                              void* d_out, int out_size, void* d_ws, size_t ws_size,
                              hipStream_t stream) {
  const float* enc = (const float*)d_in[0];  // [B, TE, H]
  const float* dec = (const float*)d_in[1];  // [B, TD, H]
  const float* Wa  = (const float*)d_in[2];  // [H, H]
  const float* Ua  = (const float*)d_in[3];  // [H, H]
  const float* Va  = (const float*)d_in[4];  // [H, 1] -> flat [H]

  float* out_c = (float*)d_out;                       // [B, TD, H]
  float* out_e = out_c + (size_t)B_ * TD_ * H_;       // [B, TD, TE]

  float* ws = (float*)d_ws;                           // Ws: [B*TE, H]  (8 MB)
  float* uh = ws + (size_t)B_ * TE_ * H_;             // Uh: [B*TD, H]  (4 MB)

  // Phase A: Ws = enc @ Wa   (M=4096, N=512, K=512)
  gemm_f32<<<dim3(H_ / 64, (B_ * TE_) / 64, 1), 256, 0, stream>>>(
      enc, H_, 0, Wa, H_, 0, ws, H_, 0, H_);
  // Phase A: Uh = dec @ Ua   (M=2048, N=512, K=512)
  gemm_f32<<<dim3(H_ / 64, (B_ * TD_) / 64, 1), 256, 0, stream>>>(
      dec, H_, 0, Ua, H_, 0, uh, H_, 0, H_);

  // Phase B: energies + softmax -> out_e
  energies_softmax<<<dim3(TD_ / DT, B_, 1), 256, 0, stream>>>(ws, uh, Va, out_e);

  // Phase C: context c[b] = e[b] @ enc[b]  (M=128, N=512, K=256, batched over B)
  gemm_f32<<<dim3(H_ / 64, TD_ / 64, B_), 256, 0, stream>>>(
      out_e, TE_, (long)TD_ * TE_,
      enc, H_, (long)TE_ * H_,
      out_c, H_, (long)TD_ * H_, TE_);
}

// Round 2
// 153.618 us; speedup vs baseline: 1.1359x; 1.1359x over previous
//
#include <hip/hip_runtime.h>

// Problem shapes (fixed by setup_inputs)
#define B_  16
#define TE_ 256
#define TD_ 128
#define H_  512

#define C_TANH 2.88539008177792681472f  // 2*log2(e):  tanh(x) = 1 - 2/(exp2(C*x)+1)
#define LOG2E  1.44269504088896340736f

__device__ __forceinline__ float wave_sum(float v) {
#pragma unroll
  for (int m = 32; m; m >>= 1) v += __shfl_xor(v, m, 64);
  return v;
}
__device__ __forceinline__ float wave_max(float v) {
#pragma unroll
  for (int m = 32; m; m >>= 1) v = fmaxf(v, __shfl_xor(v, m, 64));
  return v;
}

// ---------------------------------------------------------------------------
// Generic fp32 tiled GEMM: C[M,N] = alpha * A[M,K] @ B[K,N], row-major,
// optional batch via blockIdx.z. BM=BN=64, BK=16, 256 threads, 4x4 microtile.
// ---------------------------------------------------------------------------
__global__ __launch_bounds__(256) void gemm_f32(
    const float* __restrict__ A, int lda, long sA,
    const float* __restrict__ Bm, int ldb, long sB,
    float* __restrict__ C, int ldc, long sC, int K, float alpha)
{
  __shared__ float As[16][68];   // transposed A tile [k][m], padded
  __shared__ float Bs[16][64];   // B tile [k][n]

  const int tid = threadIdx.x;
  const int tx = tid & 15, ty = tid >> 4;
  const long bz = blockIdx.z;

  const float* Ap = A + bz * sA + (long)(blockIdx.y * 64 + (tid >> 2)) * lda + ((tid & 3) << 2);
  const float* Bp = Bm + bz * sB + (long)(tid >> 4) * ldb + blockIdx.x * 64 + ((tid & 15) << 2);
  float* Cp = C + bz * sC;

  float acc[4][4] = {};

  for (int kt = 0; kt < K; kt += 16) {
    float4 av = *(const float4*)(Ap + kt);
    float4 bv = *(const float4*)(Bp + (long)kt * ldb);
    const int ar = tid >> 2, ac = (tid & 3) << 2;
    As[ac + 0][ar] = av.x;
    As[ac + 1][ar] = av.y;
    As[ac + 2][ar] = av.z;
    As[ac + 3][ar] = av.w;
    *(float4*)&Bs[tid >> 4][(tid & 15) << 2] = bv;
    __syncthreads();
#pragma unroll
    for (int k = 0; k < 16; ++k) {
      float4 a = *(const float4*)&As[k][ty << 2];
      float4 b = *(const float4*)&Bs[k][tx << 2];
      float ae[4] = {a.x, a.y, a.z, a.w};
      float be[4] = {b.x, b.y, b.z, b.w};
#pragma unroll
      for (int i = 0; i < 4; ++i)
#pragma unroll
        for (int j = 0; j < 4; ++j)
          acc[i][j] = fmaf(ae[i], be[j], acc[i][j]);
    }
    __syncthreads();
  }

  const int r0 = blockIdx.y * 64 + (ty << 2);
  const int c0 = blockIdx.x * 64 + (tx << 2);
#pragma unroll
  for (int i = 0; i < 4; ++i) {
    float4 v = {alpha * acc[i][0], alpha * acc[i][1], alpha * acc[i][2], alpha * acc[i][3]};
    *(float4*)(Cp + (long)(r0 + i) * ldc + c0) = v;
  }
}

// ---------------------------------------------------------------------------
// Energies + softmax.
// Ws, Uh arrive PRE-SCALED by C_TANH (folded into gemm alpha).
// Block = (batch b, 2 decoder rows). 4 waves: wave wv -> (d = d0+(wv>>1),
// h-half = wv&1). Lane owns 4 contiguous h (one float4). Per lane:
//   acc_t = sum_{h in slice} V_h * rcp(exp2(ws+uh)+1)
// Batched over 4 t per reduction: pair-merge butterfly reduces 4 accs with
// 7 shuffles; per-wave partials combined across h-halves in LDS; then one
// wave per d does the 256-wide softmax.
// ---------------------------------------------------------------------------
__global__ __launch_bounds__(256) void energies_softmax(
    const float* __restrict__ Ws, const float* __restrict__ Uh,
    const float* __restrict__ Va, float* __restrict__ e_out)
{
  __shared__ float part[4][TE_];
  const int lane = threadIdx.x & 63;
  const int wv   = threadIdx.x >> 6;
  const int b    = blockIdx.y;
  const int d0   = blockIdx.x * 2;
  const int dd   = wv >> 1;   // which of the block's 2 d rows
  const int half = wv & 1;    // which h-half [0,256) / [256,512)

  // V: total sum over all h (for tanh identity), plus this wave's slice
  float4 v0 = *(const float4*)(Va + (lane << 2));
  float4 v1 = *(const float4*)(Va + 256 + (lane << 2));
  const float svtot =
      wave_sum(v0.x + v0.y + v0.z + v0.w + v1.x + v1.y + v1.z + v1.w);
  float vr[4];
  { float4 vh = half ? v1 : v0; vr[0]=vh.x; vr[1]=vh.y; vr[2]=vh.z; vr[3]=vh.w; }

  // Uh slice (pre-scaled) for this wave's d
  float uh[4];
  {
    const float* up = Uh + (size_t)(b * TD_ + d0 + dd) * H_ + half * 256 + (lane << 2);
    float4 u = *(const float4*)up;
    uh[0] = u.x; uh[1] = u.y; uh[2] = u.z; uh[3] = u.w;
  }

  // Ws rows (pre-scaled), float4 view; row stride = 128 float4
  const float4* wp4 = (const float4*)(Ws + (size_t)b * TE_ * H_) + half * 64 + lane;

  float4 cur[4], nxt[4];
#pragma unroll
  for (int i = 0; i < 4; ++i) nxt[i] = wp4[i * 128];

  for (int g = 0; g < 64; ++g) {
    const int t0 = g * 4;
#pragma unroll
    for (int i = 0; i < 4; ++i) cur[i] = nxt[i];
    if (g < 63) {
#pragma unroll
      for (int i = 0; i < 4; ++i) nxt[i] = wp4[(t0 + 4 + i) * 128];
    }

    float acc[4];
#pragma unroll
    for (int i = 0; i < 4; ++i) {
      float w[4] = {cur[i].x, cur[i].y, cur[i].z, cur[i].w};
      float a = 0.f;
#pragma unroll
      for (int j = 0; j < 4; ++j) {
        float r = __builtin_amdgcn_rcpf(
            __builtin_amdgcn_exp2f(w[j] + uh[j]) + 1.0f);
        a = fmaf(vr[j], r, a);
      }
      acc[i] = a;
    }

    // merged reduction of acc[0..3] over 64 lanes; result for acc[i] lands in
    // lanes with (lane&3)==i.
    float z0, z1;
    {
      const bool odd = lane & 1;
      float s01 = odd ? acc[0] : acc[1];
      float r01 = __shfl_xor(s01, 1, 64);
      z0 = (odd ? acc[1] : acc[0]) + r01;   // tracks acc[lane&1]
      float s23 = odd ? acc[2] : acc[3];
      float r23 = __shfl_xor(s23, 1, 64);
      z1 = (odd ? acc[3] : acc[2]) + r23;   // tracks acc[2+(lane&1)]
    }
    {
      const bool hi = lane & 2;
      float s = hi ? z0 : z1;
      float r = __shfl_xor(s, 2, 64);
      z0 = (hi ? z1 : z0) + r;              // tracks acc[lane&3]
    }
    z0 += __shfl_xor(z0, 4, 64);
    z0 += __shfl_xor(z0, 8, 64);
    z0 += __shfl_xor(z0, 16, 64);
    z0 += __shfl_xor(z0, 32, 64);

    if (lane < 4) part[wv][t0 + lane] = z0;
  }
  __syncthreads();

  // softmax over t: wave 0 -> d0, wave 1 -> d0+1
  if (wv < 2) {
    float l[4];
#pragma unroll
    for (int q = 0; q < 4; ++q) {
      float p = part[wv * 2][lane + 64 * q] + part[wv * 2 + 1][lane + 64 * q];
      l[q] = svtot - 2.0f * p;
    }
    float m = wave_max(fmaxf(fmaxf(l[0], l[1]), fmaxf(l[2], l[3])));
    float p[4];
    float s = 0.f;
#pragma unroll
    for (int q = 0; q < 4; ++q) {
      p[q] = __builtin_amdgcn_exp2f((l[q] - m) * LOG2E);
      s += p[q];
    }
    s = wave_sum(s);
    const float inv = 1.0f / s;
    float* ep = e_out + (size_t)(b * TD_ + d0 + wv) * TE_;
#pragma unroll
    for (int q = 0; q < 4; ++q) ep[lane + 64 * q] = p[q] * inv;
  }
}

// ---------------------------------------------------------------------------
extern "C" void kernel_launch(void* const* d_in, const int* in_sizes, int n_in,
                              void* d_out, int out_size, void* d_ws, size_t ws_size,
                              hipStream_t stream) {
  const float* enc = (const float*)d_in[0];  // [B, TE, H]
  const float* dec = (const float*)d_in[1];  // [B, TD, H]
  const float* Wa  = (const float*)d_in[2];  // [H, H]
  const float* Ua  = (const float*)d_in[3];  // [H, H]
  const float* Va  = (const float*)d_in[4];  // [H, 1] -> flat [H]

  float* out_c = (float*)d_out;                       // [B, TD, H]
  float* out_e = out_c + (size_t)B_ * TD_ * H_;       // [B, TD, TE]

  float* ws = (float*)d_ws;                           // Ws: [B*TE, H] (pre-scaled)
  float* uh = ws + (size_t)B_ * TE_ * H_;             // Uh: [B*TD, H] (pre-scaled)

  // Phase A: Ws = C_TANH * enc @ Wa   (M=4096, N=512, K=512)
  gemm_f32<<<dim3(H_ / 64, (B_ * TE_) / 64, 1), 256, 0, stream>>>(
      enc, H_, 0, Wa, H_, 0, ws, H_, 0, H_, C_TANH);
  // Phase A: Uh = C_TANH * dec @ Ua   (M=2048, N=512, K=512)
  gemm_f32<<<dim3(H_ / 64, (B_ * TD_) / 64, 1), 256, 0, stream>>>(
      dec, H_, 0, Ua, H_, 0, uh, H_, 0, H_, C_TANH);

  // Phase B: energies + softmax -> out_e
  energies_softmax<<<dim3(TD_ / 2, B_, 1), 256, 0, stream>>>(ws, uh, Va, out_e);

  // Phase C: context c[b] = e[b] @ enc[b]  (M=128, N=512, K=256, batched over B)
  gemm_f32<<<dim3(H_ / 64, TD_ / 64, B_), 256, 0, stream>>>(
      out_e, TE_, (long)TD_ * TE_,
      enc, H_, (long)TE_ * H_,
      out_c, H_, (long)TD_ * H_, TE_, 1.0f);
}

// Round 3
// 150.668 us; speedup vs baseline: 1.1581x; 1.0196x over previous
//
#include <hip/hip_runtime.h>

// Problem shapes (fixed by setup_inputs)
#define B_  16
#define TE_ 256
#define TD_ 128
#define H_  512

#define C_TANH 2.88539008177792681472f  // 2*log2(e):  tanh(x) = 1 - 2/(exp2(C*x)+1)
#define LOG2E  1.44269504088896340736f

__device__ __forceinline__ float wave_sum(float v) {
#pragma unroll
  for (int m = 32; m; m >>= 1) v += __shfl_xor(v, m, 64);
  return v;
}
__device__ __forceinline__ float wave_max(float v) {
#pragma unroll
  for (int m = 32; m; m >>= 1) v = fmaxf(v, __shfl_xor(v, m, 64));
  return v;
}

// ---------------------------------------------------------------------------
// Generic fp32 tiled GEMM: C[M,N] = alpha * A[M,K] @ B[K,N], row-major,
// optional batch via blockIdx.z. BM=BN=64, BK=16, 256 threads, 4x4 microtile.
// ---------------------------------------------------------------------------
__global__ __launch_bounds__(256) void gemm_f32(
    const float* __restrict__ A, int lda, long sA,
    const float* __restrict__ Bm, int ldb, long sB,
    float* __restrict__ C, int ldc, long sC, int K, float alpha)
{
  __shared__ float As[16][68];   // transposed A tile [k][m], padded
  __shared__ float Bs[16][64];   // B tile [k][n]

  const int tid = threadIdx.x;
  const int tx = tid & 15, ty = tid >> 4;
  const long bz = blockIdx.z;

  const float* Ap = A + bz * sA + (long)(blockIdx.y * 64 + (tid >> 2)) * lda + ((tid & 3) << 2);
  const float* Bp = Bm + bz * sB + (long)(tid >> 4) * ldb + blockIdx.x * 64 + ((tid & 15) << 2);
  float* Cp = C + bz * sC;

  float acc[4][4] = {};

  for (int kt = 0; kt < K; kt += 16) {
    float4 av = *(const float4*)(Ap + kt);
    float4 bv = *(const float4*)(Bp + (long)kt * ldb);
    const int ar = tid >> 2, ac = (tid & 3) << 2;
    As[ac + 0][ar] = av.x;
    As[ac + 1][ar] = av.y;
    As[ac + 2][ar] = av.z;
    As[ac + 3][ar] = av.w;
    *(float4*)&Bs[tid >> 4][(tid & 15) << 2] = bv;
    __syncthreads();
#pragma unroll
    for (int k = 0; k < 16; ++k) {
      float4 a = *(const float4*)&As[k][ty << 2];
      float4 b = *(const float4*)&Bs[k][tx << 2];
      float ae[4] = {a.x, a.y, a.z, a.w};
      float be[4] = {b.x, b.y, b.z, b.w};
#pragma unroll
      for (int i = 0; i < 4; ++i)
#pragma unroll
        for (int j = 0; j < 4; ++j)
          acc[i][j] = fmaf(ae[i], be[j], acc[i][j]);
    }
    __syncthreads();
  }

  const int r0 = blockIdx.y * 64 + (ty << 2);
  const int c0 = blockIdx.x * 64 + (tx << 2);
#pragma unroll
  for (int i = 0; i < 4; ++i) {
    float4 v = {alpha * acc[i][0], alpha * acc[i][1], alpha * acc[i][2], alpha * acc[i][3]};
    *(float4*)(Cp + (long)(r0 + i) * ldc + c0) = v;
  }
}

// ---------------------------------------------------------------------------
// Energies + softmax, lane = encoder step t (NO per-group shuffles).
// Ws, Uh arrive PRE-SCALED by C_TANH.
// Block = (b, d-pair). 4 waves: wave w -> (h-half = w>>1, d = d0 + (w&1)).
// Ws[b][:,h-chunk] is staged into LDS transposed: buf[half][h][t] (stride 257,
// conflict-free reads). Lane L owns t in {L, L+64, L+128, L+192}; per h,
// Uh[d][h] and V[h] are wave-uniform scalars (s_load), so inner element =
// v_add, v_exp, v_add, v_rcp, v_fmac. Partials per (d,t) combined across the
// two h-half waves in LDS at the end, then one wave per d does softmax.
// ---------------------------------------------------------------------------
#define CH 16
__global__ __launch_bounds__(256) void energies_softmax(
    const float* __restrict__ Ws, const float* __restrict__ Uh,
    const float* __restrict__ Va, float* __restrict__ e_out)
{
  __shared__ float buf[2][CH * 257];
  __shared__ float part[4][TE_];

  const int tid  = threadIdx.x;
  const int lane = tid & 63;
  const int wv   = __builtin_amdgcn_readfirstlane(tid >> 6);
  const int half = wv >> 1;    // h-half [0,256) / [256,512)
  const int dd   = wv & 1;     // which of the block's 2 d rows
  const int b    = blockIdx.y;
  const int d0   = blockIdx.x * 2;
  const int tid2 = tid & 127;  // id within the half-pair (2 waves)

  const float* WsB = Ws + (size_t)b * TE_ * H_;
  const float* up  = Uh + (size_t)(b * TD_ + d0 + dd) * H_ + half * 256;  // scaled
  const float* vp  = Va + half * 256;                                     // unscaled

  // total sum of V over all h (for the tanh identity)
  float4 v0 = *(const float4*)(Va + (lane << 2));
  float4 v1 = *(const float4*)(Va + 256 + (lane << 2));
  const float svtot =
      wave_sum(v0.x + v0.y + v0.z + v0.w + v1.x + v1.y + v1.z + v1.w);

  float* mybuf = buf[half];
  float plog[4] = {0.f, 0.f, 0.f, 0.f};

  for (int ch = 0; ch < 256 / CH; ++ch) {
    const int hbase = half * 256 + ch * CH;
    __syncthreads();  // previous chunk's readers done before overwrite
    // stage CH x 256 transposed; h-major lanes => 64B-coalesced global reads
#pragma unroll
    for (int k = 0; k < 8; ++k) {
      int task = k * 128 + tid2;      // 0..1023
      int hg = task & 3;              // float4 group along h
      int t  = task >> 2;             // 0..255
      float4 w = *(const float4*)(WsB + (size_t)t * H_ + hbase + (hg << 2));
      float* dst = &mybuf[(hg << 2) * 257 + t];
      dst[0]       = w.x;
      dst[257]     = w.y;
      dst[2 * 257] = w.z;
      dst[3 * 257] = w.w;
    }
    __syncthreads();
    // compute: per h, 4 t-values per lane; uh/V are wave-uniform scalars
#pragma unroll
    for (int h = 0; h < CH; ++h) {
      const float sU = up[ch * CH + h];
      const float sV = vp[ch * CH + h];
      const float* r = &mybuf[h * 257 + lane];
      float w0 = r[0], w1 = r[64], w2 = r[128], w3 = r[192];
      plog[0] = fmaf(sV, __builtin_amdgcn_rcpf(__builtin_amdgcn_exp2f(w0 + sU) + 1.f), plog[0]);
      plog[1] = fmaf(sV, __builtin_amdgcn_rcpf(__builtin_amdgcn_exp2f(w1 + sU) + 1.f), plog[1]);
      plog[2] = fmaf(sV, __builtin_amdgcn_rcpf(__builtin_amdgcn_exp2f(w2 + sU) + 1.f), plog[2]);
      plog[3] = fmaf(sV, __builtin_amdgcn_rcpf(__builtin_amdgcn_exp2f(w3 + sU) + 1.f), plog[3]);
    }
  }

  // combine partials across h-halves: d row dd gets waves {dd, dd+2}
#pragma unroll
  for (int q = 0; q < 4; ++q) part[wv][lane + (q << 6)] = plog[q];
  __syncthreads();

  if (wv < 2) {  // wave wv -> d = d0 + wv
    float l[4];
#pragma unroll
    for (int q = 0; q < 4; ++q) {
      float p = part[wv][lane + (q << 6)] + part[wv + 2][lane + (q << 6)];
      l[q] = svtot - 2.0f * p;
    }
    float m = wave_max(fmaxf(fmaxf(l[0], l[1]), fmaxf(l[2], l[3])));
    float p[4];
    float s = 0.f;
#pragma unroll
    for (int q = 0; q < 4; ++q) {
      p[q] = __builtin_amdgcn_exp2f((l[q] - m) * LOG2E);
      s += p[q];
    }
    s = wave_sum(s);
    const float inv = 1.0f / s;
    float* ep = e_out + (size_t)(b * TD_ + d0 + wv) * TE_;
#pragma unroll
    for (int q = 0; q < 4; ++q) ep[lane + (q << 6)] = p[q] * inv;
  }
}

// ---------------------------------------------------------------------------
extern "C" void kernel_launch(void* const* d_in, const int* in_sizes, int n_in,
                              void* d_out, int out_size, void* d_ws, size_t ws_size,
                              hipStream_t stream) {
  const float* enc = (const float*)d_in[0];  // [B, TE, H]
  const float* dec = (const float*)d_in[1];  // [B, TD, H]
  const float* Wa  = (const float*)d_in[2];  // [H, H]
  const float* Ua  = (const float*)d_in[3];  // [H, H]
  const float* Va  = (const float*)d_in[4];  // [H, 1] -> flat [H]

  float* out_c = (float*)d_out;                       // [B, TD, H]
  float* out_e = out_c + (size_t)B_ * TD_ * H_;       // [B, TD, TE]

  float* ws = (float*)d_ws;                           // Ws: [B*TE, H] (pre-scaled)
  float* uh = ws + (size_t)B_ * TE_ * H_;             // Uh: [B*TD, H] (pre-scaled)

  // Phase A: Ws = C_TANH * enc @ Wa   (M=4096, N=512, K=512)
  gemm_f32<<<dim3(H_ / 64, (B_ * TE_) / 64, 1), 256, 0, stream>>>(
      enc, H_, 0, Wa, H_, 0, ws, H_, 0, H_, C_TANH);
  // Phase A: Uh = C_TANH * dec @ Ua   (M=2048, N=512, K=512)
  gemm_f32<<<dim3(H_ / 64, (B_ * TD_) / 64, 1), 256, 0, stream>>>(
      dec, H_, 0, Ua, H_, 0, uh, H_, 0, H_, C_TANH);

  // Phase B: energies + softmax -> out_e
  energies_softmax<<<dim3(TD_ / 2, B_, 1), 256, 0, stream>>>(ws, uh, Va, out_e);

  // Phase C: context c[b] = e[b] @ enc[b]  (M=128, N=512, K=256, batched over B)
  gemm_f32<<<dim3(H_ / 64, TD_ / 64, B_), 256, 0, stream>>>(
      out_e, TE_, (long)TD_ * TE_,
      enc, H_, (long)TE_ * H_,
      out_c, H_, (long)TD_ * H_, TE_, 1.0f);
}

// Round 4
// 126.674 us; speedup vs baseline: 1.3775x; 1.1894x over previous
//
#include <hip/hip_runtime.h>

// Problem shapes (fixed by setup_inputs)
#define B_  16
#define TE_ 256
#define TD_ 128
#define H_  512

#define C_TANH 2.88539008177792681472f  // 2*log2(e):  tanh(x) = 1 - 2/(exp2(C*x)+1)
#define LOG2E  1.44269504088896340736f

__device__ __forceinline__ float wave_sum(float v) {
#pragma unroll
  for (int m = 32; m; m >>= 1) v += __shfl_xor(v, m, 64);
  return v;
}
__device__ __forceinline__ float wave_max(float v) {
#pragma unroll
  for (int m = 32; m; m >>= 1) v = fmaxf(v, __shfl_xor(v, m, 64));
  return v;
}

// ---------------------------------------------------------------------------
// fp32 tiled GEMM with fused epilogue. BM=BN=64, BK=16, 256 thr, 4x4 microtile.
// MODE 0: C = alpha * A@B (row-major store)
// MODE 1: E_T[b][n][t] = exp2(alpha * (A@B)[m][n]),  m = b*256 + t  (transposed)
// MODE 2: C = exp2(alpha * A@B) (row-major store)
// ---------------------------------------------------------------------------
template <int MODE>
__global__ __launch_bounds__(256) void gemm_f32_ep(
    const float* __restrict__ A, int lda, long sA,
    const float* __restrict__ Bm, int ldb, long sB,
    float* __restrict__ C, int ldc, long sC, int K, float alpha)
{
  __shared__ float As[16][68];   // transposed A tile [k][m], padded
  __shared__ float Bs[16][64];   // B tile [k][n]

  const int tid = threadIdx.x;
  const int tx = tid & 15, ty = tid >> 4;
  const long bz = blockIdx.z;

  const float* Ap = A + bz * sA + (long)(blockIdx.y * 64 + (tid >> 2)) * lda + ((tid & 3) << 2);
  const float* Bp = Bm + bz * sB + (long)(tid >> 4) * ldb + blockIdx.x * 64 + ((tid & 15) << 2);
  float* Cp = C + bz * sC;

  float acc[4][4] = {};

  for (int kt = 0; kt < K; kt += 16) {
    float4 av = *(const float4*)(Ap + kt);
    float4 bv = *(const float4*)(Bp + (long)kt * ldb);
    const int ar = tid >> 2, ac = (tid & 3) << 2;
    As[ac + 0][ar] = av.x;
    As[ac + 1][ar] = av.y;
    As[ac + 2][ar] = av.z;
    As[ac + 3][ar] = av.w;
    *(float4*)&Bs[tid >> 4][(tid & 15) << 2] = bv;
    __syncthreads();
#pragma unroll
    for (int k = 0; k < 16; ++k) {
      float4 a = *(const float4*)&As[k][ty << 2];
      float4 b = *(const float4*)&Bs[k][tx << 2];
      float ae[4] = {a.x, a.y, a.z, a.w};
      float be[4] = {b.x, b.y, b.z, b.w};
#pragma unroll
      for (int i = 0; i < 4; ++i)
#pragma unroll
        for (int j = 0; j < 4; ++j)
          acc[i][j] = fmaf(ae[i], be[j], acc[i][j]);
    }
    __syncthreads();
  }

  const int r0 = blockIdx.y * 64 + (ty << 2);
  const int c0 = blockIdx.x * 64 + (tx << 2);

  if (MODE == 1) {
    // transposed + exp2: dest row = n (h), dest col = t = m % 256, batch = m/256
    const int b = r0 >> 8, t = r0 & 255;
#pragma unroll
    for (int j = 0; j < 4; ++j) {
      float4 ev;
      ev.x = __builtin_amdgcn_exp2f(alpha * acc[0][j]);
      ev.y = __builtin_amdgcn_exp2f(alpha * acc[1][j]);
      ev.z = __builtin_amdgcn_exp2f(alpha * acc[2][j]);
      ev.w = __builtin_amdgcn_exp2f(alpha * acc[3][j]);
      *(float4*)(C + (size_t)(b * H_ + c0 + j) * TE_ + t) = ev;
    }
  } else {
#pragma unroll
    for (int i = 0; i < 4; ++i) {
      float4 v;
      if (MODE == 2) {
        v.x = __builtin_amdgcn_exp2f(alpha * acc[i][0]);
        v.y = __builtin_amdgcn_exp2f(alpha * acc[i][1]);
        v.z = __builtin_amdgcn_exp2f(alpha * acc[i][2]);
        v.w = __builtin_amdgcn_exp2f(alpha * acc[i][3]);
      } else {
        v.x = alpha * acc[i][0]; v.y = alpha * acc[i][1];
        v.z = alpha * acc[i][2]; v.w = alpha * acc[i][3];
      }
      *(float4*)(Cp + (long)(r0 + i) * ldc + c0) = v;
    }
  }
}

// ---------------------------------------------------------------------------
// Energies + softmax from precomputed exponentials.
//   E_T[b][h][t] = exp2(C*Ws),  eU[b][d][h] = exp2(C*Uh)
//   tanh(Ws+Uh) = 1 - 2 * rcp(E*eU + 1)
// Block = (b, 4 decoder rows). 4 waves: wave w -> (half = w&1, dpair = w>>1);
// each wave owns d = d0+2*dp+{0,1} and h in its half. Lane owns t-quad
// [4L..4L+3] (one dwordx4 per h, coalesced; reused for both d). eU, Va are
// wave-uniform scalars. No staging, no transpose, no shuffles in the hot loop.
// ---------------------------------------------------------------------------
__global__ __launch_bounds__(256) void energies_softmax(
    const float* __restrict__ E_T, const float* __restrict__ eU,
    const float* __restrict__ Va, float* __restrict__ e_out)
{
  __shared__ float part[4][2][TE_];

  const int tid  = threadIdx.x;
  const int lane = tid & 63;
  const int wv   = __builtin_amdgcn_readfirstlane(tid >> 6);
  const int half = wv & 1;
  const int dp   = wv >> 1;
  const int b    = blockIdx.y;
  const int d0   = blockIdx.x << 2;

  // total sum of V over all h (tanh identity constant)
  float4 v0 = *(const float4*)(Va + (lane << 2));
  float4 v1 = *(const float4*)(Va + 256 + (lane << 2));
  const float svtot =
      wave_sum(v0.x + v0.y + v0.z + v0.w + v1.x + v1.y + v1.z + v1.w);

  const int dA = d0 + 2 * dp, dB = dA + 1;
  const float* uA = eU + (size_t)(b * TD_ + dA) * H_ + half * 256;
  const float* uB = eU + (size_t)(b * TD_ + dB) * H_ + half * 256;
  const float* vp = Va + half * 256;
  const float4* ep = (const float4*)(E_T + (size_t)(b * H_ + half * 256) * TE_) + lane;

  float pA[4] = {0.f, 0.f, 0.f, 0.f};
  float pB[4] = {0.f, 0.f, 0.f, 0.f};

#pragma unroll 4
  for (int h = 0; h < 256; ++h) {
    const float sUA = uA[h];
    const float sUB = uB[h];
    const float sV  = vp[h];
    float4 w = ep[(size_t)h * (TE_ / 4)];
    pA[0] = fmaf(sV, __builtin_amdgcn_rcpf(fmaf(w.x, sUA, 1.f)), pA[0]);
    pA[1] = fmaf(sV, __builtin_amdgcn_rcpf(fmaf(w.y, sUA, 1.f)), pA[1]);
    pA[2] = fmaf(sV, __builtin_amdgcn_rcpf(fmaf(w.z, sUA, 1.f)), pA[2]);
    pA[3] = fmaf(sV, __builtin_amdgcn_rcpf(fmaf(w.w, sUA, 1.f)), pA[3]);
    pB[0] = fmaf(sV, __builtin_amdgcn_rcpf(fmaf(w.x, sUB, 1.f)), pB[0]);
    pB[1] = fmaf(sV, __builtin_amdgcn_rcpf(fmaf(w.y, sUB, 1.f)), pB[1]);
    pB[2] = fmaf(sV, __builtin_amdgcn_rcpf(fmaf(w.z, sUB, 1.f)), pB[2]);
    pB[3] = fmaf(sV, __builtin_amdgcn_rcpf(fmaf(w.w, sUB, 1.f)), pB[3]);
  }

  // partials: lane L holds t = 4L+q for rows dA, dB of this h-half
  *(float4*)&part[2 * dp + 0][half][lane << 2] = *(float4*)pA;
  *(float4*)&part[2 * dp + 1][half][lane << 2] = *(float4*)pB;
  __syncthreads();

  // softmax: wave w handles d = d0 + w
  {
    float4 qa = *(const float4*)&part[wv][0][lane << 2];
    float4 qb = *(const float4*)&part[wv][1][lane << 2];
    float l[4] = {svtot - 2.f * (qa.x + qb.x), svtot - 2.f * (qa.y + qb.y),
                  svtot - 2.f * (qa.z + qb.z), svtot - 2.f * (qa.w + qb.w)};
    float m = wave_max(fmaxf(fmaxf(l[0], l[1]), fmaxf(l[2], l[3])));
    float p[4];
    float s = 0.f;
#pragma unroll
    for (int q = 0; q < 4; ++q) {
      p[q] = __builtin_amdgcn_exp2f((l[q] - m) * LOG2E);
      s += p[q];
    }
    s = wave_sum(s);
    const float inv = 1.0f / s;
    float4 ov = {p[0] * inv, p[1] * inv, p[2] * inv, p[3] * inv};
    *(float4*)(e_out + (size_t)(b * TD_ + d0 + wv) * TE_ + (lane << 2)) = ov;
  }
}

// ---------------------------------------------------------------------------
extern "C" void kernel_launch(void* const* d_in, const int* in_sizes, int n_in,
                              void* d_out, int out_size, void* d_ws, size_t ws_size,
                              hipStream_t stream) {
  const float* enc = (const float*)d_in[0];  // [B, TE, H]
  const float* dec = (const float*)d_in[1];  // [B, TD, H]
  const float* Wa  = (const float*)d_in[2];  // [H, H]
  const float* Ua  = (const float*)d_in[3];  // [H, H]
  const float* Va  = (const float*)d_in[4];  // [H, 1] -> flat [H]

  float* out_c = (float*)d_out;                       // [B, TD, H]
  float* out_e = out_c + (size_t)B_ * TD_ * H_;       // [B, TD, TE]

  float* E_T = (float*)d_ws;                          // [B][H][TE] = 8 MB
  float* eUw = E_T + (size_t)B_ * H_ * TE_;           // [B][TD][H] = 4 MB

  // Phase A1: E_T = exp2(C * enc @ Wa), stored transposed per batch
  gemm_f32_ep<1><<<dim3(H_ / 64, (B_ * TE_) / 64, 1), 256, 0, stream>>>(
      enc, H_, 0, Wa, H_, 0, E_T, 0, 0, H_, C_TANH);
  // Phase A2: eU = exp2(C * dec @ Ua), row-major
  gemm_f32_ep<2><<<dim3(H_ / 64, (B_ * TD_) / 64, 1), 256, 0, stream>>>(
      dec, H_, 0, Ua, H_, 0, eUw, H_, 0, H_, C_TANH);

  // Phase B: energies + softmax -> out_e
  energies_softmax<<<dim3(TD_ / 4, B_, 1), 256, 0, stream>>>(E_T, eUw, Va, out_e);

  // Phase C: context c[b] = e[b] @ enc[b]  (M=128, N=512, K=256, batched over B)
  gemm_f32_ep<0><<<dim3(H_ / 64, TD_ / 64, B_), 256, 0, stream>>>(
      out_e, TE_, (long)TD_ * TE_,
      enc, H_, (long)TE_ * H_,
      out_c, H_, (long)TD_ * H_, TE_, 1.0f);
}

// Round 5
// 97.884 us; speedup vs baseline: 1.7826x; 1.2941x over previous
//
#include <hip/hip_runtime.h>

// Problem shapes (fixed by setup_inputs)
#define B_  16
#define TE_ 256
#define TD_ 128
#define H_  512

#define C_TANH 2.88539008177792681472f  // 2*log2(e):  tanh(x) = 1 - 2/(exp2(C*x)+1)
#define LOG2E  1.44269504088896340736f

typedef __attribute__((ext_vector_type(8))) short short8v;   // 8 x bf16 (4 VGPR)
typedef __attribute__((ext_vector_type(4))) float floatx4;   // MFMA acc

__device__ __forceinline__ float wave_sum(float v) {
#pragma unroll
  for (int m = 32; m; m >>= 1) v += __shfl_xor(v, m, 64);
  return v;
}
__device__ __forceinline__ float wave_max(float v) {
#pragma unroll
  for (int m = 32; m; m >>= 1) v = fmaxf(v, __shfl_xor(v, m, 64));
  return v;
}
__device__ __forceinline__ ushort f2bf(float f) {  // RNE fp32->bf16
  unsigned u = __builtin_bit_cast(unsigned, f);
  u += 0x7fffu + ((u >> 16) & 1u);
  return (ushort)(u >> 16);
}

// ---------------------------------------------------------------------------
// fp32 -> bf16 row-major convert, two buffers in one launch (quad-vectorized)
// ---------------------------------------------------------------------------
__global__ __launch_bounds__(256) void cvt_bf16_dual(
    const float* __restrict__ s0, ushort* __restrict__ d0, int q0,
    const float* __restrict__ s1, ushort* __restrict__ d1, int q1)
{
  int idx = blockIdx.x * 256 + threadIdx.x;
  const float* s; ushort* d;
  if (idx < q0) { s = s0; d = d0; }
  else { idx -= q0; if (idx >= q1) return; s = s1; d = d1; }
  float4 v = *(const float4*)(s + 4 * (size_t)idx);
  ushort4 o = {f2bf(v.x), f2bf(v.y), f2bf(v.z), f2bf(v.w)};
  *(ushort4*)(d + 4 * (size_t)idx) = o;
}

// ---------------------------------------------------------------------------
// fp32 [z][R][C] -> bf16 [z][C][R] transpose-convert (32x32 LDS tiles).
// z < z0 uses (s0,d0), else (s1,d1) with z-=z0. R,C multiples of 32.
// ---------------------------------------------------------------------------
__global__ __launch_bounds__(256) void transpose_cvt(
    const float* __restrict__ s0, ushort* __restrict__ d0, int z0,
    const float* __restrict__ s1, ushort* __restrict__ d1,
    int R, int C, long sStr, long dStr)
{
  __shared__ float tl[32][33];
  int z = blockIdx.z;
  const float* s; ushort* d;
  if (z < z0) { s = s0 + (size_t)z * sStr; d = d0 + (size_t)z * dStr; }
  else        { s = s1 + (size_t)(z - z0) * sStr; d = d1 + (size_t)(z - z0) * dStr; }
  const int tx = threadIdx.x & 31, ty = threadIdx.x >> 5;
  const int r0 = blockIdx.y * 32, c0 = blockIdx.x * 32;
#pragma unroll
  for (int i = 0; i < 4; ++i)
    tl[ty + 8 * i][tx] = s[(size_t)(r0 + ty + 8 * i) * C + c0 + tx];
  __syncthreads();
#pragma unroll
  for (int i = 0; i < 4; ++i)
    d[(size_t)(c0 + ty + 8 * i) * R + r0 + tx] = f2bf(tl[tx][ty + 8 * i]);
}

// ---------------------------------------------------------------------------
// bf16 MFMA GEMM: C[M,N] = ep(alpha * A[M,K] @ B[K,N]) with B supplied
// TRANSPOSED as BT[N,K] (both operands K-contiguous). BM=64, BN=128, BK=32,
// 128 threads = 2 waves (wave w owns rows [32w,32w+32): 2x8 tiles of 16x16).
// MODE 0: plain alpha* store (row-major, batched via z)
// MODE 1: E_T[b][n][t] = exp2(alpha*v), b = m>>8, t = m&255 (transposed)
// MODE 2: exp2(alpha*v) row-major
// mfma_f32_16x16x32_bf16 layout: A lane=(m=l&15, k=8*(l>>4)+j);
// B lane=(n=l&15, k=8*(l>>4)+j) from BT; D col=l&15, row=4*(l>>4)+r.
// ---------------------------------------------------------------------------
template <int MODE>
__global__ __launch_bounds__(128) void gemm_bf16(
    const ushort* __restrict__ A, int lda, long sA,
    const ushort* __restrict__ BT, int ldb, long sB,
    float* __restrict__ C, int ldc, long sC, int K, float alpha)
{
  __shared__ __attribute__((aligned(16))) ushort As[64 * 40];   // pitch 40 (pad)
  __shared__ __attribute__((aligned(16))) ushort Bs[128 * 40];

  const int tid = threadIdx.x;
  const int l = tid & 63;
  const int w = tid >> 6;
  const int l15 = l & 15, l4 = l >> 4;
  const long z = blockIdx.z;
  const int bn = blockIdx.x * 128, bm = blockIdx.y * 64;

  const ushort* Ag = A + z * sA + (long)bm * lda;
  const ushort* Bg = BT + z * sB + (long)bn * ldb;

  floatx4 acc[2][8] = {};

  for (int kt = 0; kt < K; kt += 32) {
    __syncthreads();
    // stage A tile: 64x32, 2 chunks of 8 bf16 per thread
#pragma unroll
    for (int q = 0; q < 2; ++q) {
      int tau = q * 128 + tid;
      int row = tau >> 2, kc = (tau & 3) << 3;
      *(short8v*)&As[row * 40 + kc] =
          *(const short8v*)(Ag + (long)row * lda + kt + kc);
    }
    // stage BT tile: 128x32, 4 chunks per thread
#pragma unroll
    for (int q = 0; q < 4; ++q) {
      int tau = q * 128 + tid;
      int row = tau >> 2, kc = (tau & 3) << 3;
      *(short8v*)&Bs[row * 40 + kc] =
          *(const short8v*)(Bg + (long)row * ldb + kt + kc);
    }
    __syncthreads();

    short8v a0 = *(short8v*)&As[(w * 32 + l15) * 40 + l4 * 8];
    short8v a1 = *(short8v*)&As[(w * 32 + 16 + l15) * 40 + l4 * 8];
#pragma unroll
    for (int nt = 0; nt < 8; ++nt) {
      short8v bf = *(short8v*)&Bs[(nt * 16 + l15) * 40 + l4 * 8];
      acc[0][nt] = __builtin_amdgcn_mfma_f32_16x16x32_bf16(a0, bf, acc[0][nt], 0, 0, 0);
      acc[1][nt] = __builtin_amdgcn_mfma_f32_16x16x32_bf16(a1, bf, acc[1][nt], 0, 0, 0);
    }
  }

  const int rb = l4 << 2;
#pragma unroll
  for (int mt = 0; mt < 2; ++mt) {
    const int growb = bm + w * 32 + mt * 16 + rb;
#pragma unroll
    for (int nt = 0; nt < 8; ++nt) {
      const int gcol = bn + nt * 16 + l15;
#pragma unroll
      for (int r = 0; r < 4; ++r) {
        const float v = alpha * acc[mt][nt][r];
        const int grow = growb + r;
        if (MODE == 0) {
          C[z * sC + (long)grow * ldc + gcol] = v;
        } else if (MODE == 1) {
          const int bb = grow >> 8, t = grow & 255;
          C[(size_t)(bb * H_ + gcol) * TE_ + t] = __builtin_amdgcn_exp2f(v);
        } else {
          C[(long)grow * ldc + gcol] = __builtin_amdgcn_exp2f(v);
        }
      }
    }
  }
}

// ---------------------------------------------------------------------------
// Energies + softmax from precomputed exponentials (round-4 structure), plus
// a bf16 copy of e for the MFMA context GEMM.
// ---------------------------------------------------------------------------
__global__ __launch_bounds__(256) void energies_softmax(
    const float* __restrict__ E_T, const float* __restrict__ eU,
    const float* __restrict__ Va, float* __restrict__ e_out,
    ushort* __restrict__ eB)
{
  __shared__ float part[4][2][TE_];

  const int tid  = threadIdx.x;
  const int lane = tid & 63;
  const int wv   = __builtin_amdgcn_readfirstlane(tid >> 6);
  const int half = wv & 1;
  const int dp   = wv >> 1;
  const int b    = blockIdx.y;
  const int d0   = blockIdx.x << 2;

  float4 v0 = *(const float4*)(Va + (lane << 2));
  float4 v1 = *(const float4*)(Va + 256 + (lane << 2));
  const float svtot =
      wave_sum(v0.x + v0.y + v0.z + v0.w + v1.x + v1.y + v1.z + v1.w);

  const int dA = d0 + 2 * dp, dB = dA + 1;
  const float* uA = eU + (size_t)(b * TD_ + dA) * H_ + half * 256;
  const float* uB = eU + (size_t)(b * TD_ + dB) * H_ + half * 256;
  const float* vp = Va + half * 256;
  const float4* ep = (const float4*)(E_T + (size_t)(b * H_ + half * 256) * TE_) + lane;

  float pA[4] = {0.f, 0.f, 0.f, 0.f};
  float pB[4] = {0.f, 0.f, 0.f, 0.f};

#pragma unroll 4
  for (int h = 0; h < 256; ++h) {
    const float sUA = uA[h];
    const float sUB = uB[h];
    const float sV  = vp[h];
    float4 ww = ep[(size_t)h * (TE_ / 4)];
    pA[0] = fmaf(sV, __builtin_amdgcn_rcpf(fmaf(ww.x, sUA, 1.f)), pA[0]);
    pA[1] = fmaf(sV, __builtin_amdgcn_rcpf(fmaf(ww.y, sUA, 1.f)), pA[1]);
    pA[2] = fmaf(sV, __builtin_amdgcn_rcpf(fmaf(ww.z, sUA, 1.f)), pA[2]);
    pA[3] = fmaf(sV, __builtin_amdgcn_rcpf(fmaf(ww.w, sUA, 1.f)), pA[3]);
    pB[0] = fmaf(sV, __builtin_amdgcn_rcpf(fmaf(ww.x, sUB, 1.f)), pB[0]);
    pB[1] = fmaf(sV, __builtin_amdgcn_rcpf(fmaf(ww.y, sUB, 1.f)), pB[1]);
    pB[2] = fmaf(sV, __builtin_amdgcn_rcpf(fmaf(ww.z, sUB, 1.f)), pB[2]);
    pB[3] = fmaf(sV, __builtin_amdgcn_rcpf(fmaf(ww.w, sUB, 1.f)), pB[3]);
  }

  *(float4*)&part[2 * dp + 0][half][lane << 2] = *(float4*)pA;
  *(float4*)&part[2 * dp + 1][half][lane << 2] = *(float4*)pB;
  __syncthreads();

  {
    float4 qa = *(const float4*)&part[wv][0][lane << 2];
    float4 qb = *(const float4*)&part[wv][1][lane << 2];
    float l4v[4] = {svtot - 2.f * (qa.x + qb.x), svtot - 2.f * (qa.y + qb.y),
                    svtot - 2.f * (qa.z + qb.z), svtot - 2.f * (qa.w + qb.w)};
    float m = wave_max(fmaxf(fmaxf(l4v[0], l4v[1]), fmaxf(l4v[2], l4v[3])));
    float p[4];
    float s = 0.f;
#pragma unroll
    for (int q = 0; q < 4; ++q) {
      p[q] = __builtin_amdgcn_exp2f((l4v[q] - m) * LOG2E);
      s += p[q];
    }
    s = wave_sum(s);
    const float inv = 1.0f / s;
    float4 ov = {p[0] * inv, p[1] * inv, p[2] * inv, p[3] * inv};
    const size_t ro = (size_t)(b * TD_ + d0 + wv) * TE_ + (lane << 2);
    *(float4*)(e_out + ro) = ov;
    ushort4 ob = {f2bf(ov.x), f2bf(ov.y), f2bf(ov.z), f2bf(ov.w)};
    *(ushort4*)(eB + ro) = ob;
  }
}

// ---------------------------------------------------------------------------
extern "C" void kernel_launch(void* const* d_in, const int* in_sizes, int n_in,
                              void* d_out, int out_size, void* d_ws, size_t ws_size,
                              hipStream_t stream) {
  const float* enc = (const float*)d_in[0];  // [B, TE, H]
  const float* dec = (const float*)d_in[1];  // [B, TD, H]
  const float* Wa  = (const float*)d_in[2];  // [H, H]
  const float* Ua  = (const float*)d_in[3];  // [H, H]
  const float* Va  = (const float*)d_in[4];  // [H]

  float* out_c = (float*)d_out;                       // [B, TD, H]
  float* out_e = out_c + (size_t)B_ * TD_ * H_;       // [B, TD, TE]

  char* w8 = (char*)d_ws;                             // 24 MB total
  float*  E_T  = (float*)(w8);                        // [B][H][TE] f32   8 MB
  float*  eU   = (float*)(w8 + (8u << 20));           // [B][TD][H] f32   4 MB
  ushort* encB = (ushort*)(w8 + (12u << 20));         // [B*TE][H] bf16   4 MB
  ushort* decB = (ushort*)(w8 + (16u << 20));         // [B*TD][H] bf16   2 MB
  ushort* WaT  = (ushort*)(w8 + (18u << 20));         // [H][H]    bf16 0.5 MB
  ushort* UaT  = (ushort*)(w8 + (18u << 20) + (512u << 10));
  ushort* encT = (ushort*)(w8 + (19u << 20));         // [B][H][TE] bf16  4 MB
  ushort* eB   = (ushort*)(w8 + (23u << 20));         // [B][TD][TE] bf16 1 MB

  // Pre-pass: conversions/transposes
  cvt_bf16_dual<<<3072, 256, 0, stream>>>(
      enc, encB, (B_ * TE_ * H_) / 4, dec, decB, (B_ * TD_ * H_) / 4);
  transpose_cvt<<<dim3(16, 16, 2), 256, 0, stream>>>(
      Wa, WaT, 1, Ua, UaT, H_, H_, 0, 0);
  transpose_cvt<<<dim3(16, 8, 16), 256, 0, stream>>>(
      enc, encT, 16, enc, encT, TE_, H_, (long)TE_ * H_, (long)H_ * TE_);

  // A1: E_T = exp2(C * enc @ Wa), stored [b][h][t]
  gemm_bf16<1><<<dim3(4, 64, 1), 128, 0, stream>>>(
      encB, H_, 0, WaT, H_, 0, E_T, 0, 0, H_, C_TANH);
  // A2: eU = exp2(C * dec @ Ua), row-major
  gemm_bf16<2><<<dim3(4, 32, 1), 128, 0, stream>>>(
      decB, H_, 0, UaT, H_, 0, eU, H_, 0, H_, C_TANH);

  // B: energies + softmax -> out_e (f32) + eB (bf16)
  energies_softmax<<<dim3(TD_ / 4, B_, 1), 256, 0, stream>>>(E_T, eU, Va, out_e, eB);

  // C: c[b] = e[b] @ enc[b] via bf16 MFMA (BT = encT)
  gemm_bf16<0><<<dim3(4, 2, 16), 128, 0, stream>>>(
      eB, TE_, (long)TD_ * TE_, encT, TE_, (long)H_ * TE_,
      out_c, H_, (long)TD_ * H_, TE_, 1.0f);
}

// Round 6
// 89.362 us; speedup vs baseline: 1.9526x; 1.0954x over previous
//
#include <hip/hip_runtime.h>

// Problem shapes (fixed by setup_inputs)
#define B_  16
#define TE_ 256
#define TD_ 128
#define H_  512

#define C_TANH 2.88539008177792681472f  // 2*log2(e):  tanh(x) = 1 - 2/(exp2(C*x)+1)
#define LOG2E  1.44269504088896340736f

typedef __attribute__((ext_vector_type(8))) short short8v;   // 8 x bf16 (4 VGPR)
typedef __attribute__((ext_vector_type(4))) float floatx4;   // MFMA acc

__device__ __forceinline__ float wave_sum(float v) {
#pragma unroll
  for (int m = 32; m; m >>= 1) v += __shfl_xor(v, m, 64);
  return v;
}
__device__ __forceinline__ float wave_max(float v) {
#pragma unroll
  for (int m = 32; m; m >>= 1) v = fmaxf(v, __shfl_xor(v, m, 64));
  return v;
}
__device__ __forceinline__ ushort f2bf(float f) {  // RNE fp32->bf16
  unsigned u = __builtin_bit_cast(unsigned, f);
  u += 0x7fffu + ((u >> 16) & 1u);
  return (ushort)(u >> 16);
}

// ---------------------------------------------------------------------------
// enc prep: one read of enc produces encB (bf16 row-major [b*TE][H]) and
// encT (bf16 transposed [b][H][TE]). 32x32 LDS tiles.
// ---------------------------------------------------------------------------
__global__ __launch_bounds__(256) void prep_enc(
    const float* __restrict__ enc, ushort* __restrict__ encB,
    ushort* __restrict__ encT)
{
  __shared__ float tl[32][33];
  const int z = blockIdx.z;
  const float* s = enc + (size_t)z * TE_ * H_;
  ushort* dB = encB + (size_t)z * TE_ * H_;
  ushort* dT = encT + (size_t)z * H_ * TE_;
  const int tx = threadIdx.x & 31, ty = threadIdx.x >> 5;
  const int r0 = blockIdx.y * 32, c0 = blockIdx.x * 32;
#pragma unroll
  for (int i = 0; i < 4; ++i) {
    float v = s[(size_t)(r0 + ty + 8 * i) * H_ + c0 + tx];
    tl[ty + 8 * i][tx] = v;
    dB[(size_t)(r0 + ty + 8 * i) * H_ + c0 + tx] = f2bf(v);
  }
  __syncthreads();
#pragma unroll
  for (int i = 0; i < 4; ++i)
    dT[(size_t)(c0 + ty + 8 * i) * TE_ + r0 + tx] = f2bf(tl[tx][ty + 8 * i]);
}

// fp32 -> bf16 row-major convert (quad-vectorized), n4 = count/4
__global__ __launch_bounds__(256) void cvt_bf16(
    const float* __restrict__ s, ushort* __restrict__ d, int n4)
{
  int idx = blockIdx.x * 256 + threadIdx.x;
  if (idx >= n4) return;
  float4 v = *(const float4*)(s + 4 * (size_t)idx);
  ushort4 o = {f2bf(v.x), f2bf(v.y), f2bf(v.z), f2bf(v.w)};
  *(ushort4*)(d + 4 * (size_t)idx) = o;
}

// ---------------------------------------------------------------------------
// fp32 [z][R][C] -> bf16 [z][C][R] transpose-convert (32x32 LDS tiles).
// z < z0 uses (s0,d0), else (s1,d1) with z-=z0.
// ---------------------------------------------------------------------------
__global__ __launch_bounds__(256) void transpose_cvt(
    const float* __restrict__ s0, ushort* __restrict__ d0, int z0,
    const float* __restrict__ s1, ushort* __restrict__ d1,
    int R, int C, long sStr, long dStr)
{
  __shared__ float tl[32][33];
  int z = blockIdx.z;
  const float* s; ushort* d;
  if (z < z0) { s = s0 + (size_t)z * sStr; d = d0 + (size_t)z * dStr; }
  else        { s = s1 + (size_t)(z - z0) * sStr; d = d1 + (size_t)(z - z0) * dStr; }
  const int tx = threadIdx.x & 31, ty = threadIdx.x >> 5;
  const int r0 = blockIdx.y * 32, c0 = blockIdx.x * 32;
#pragma unroll
  for (int i = 0; i < 4; ++i)
    tl[ty + 8 * i][tx] = s[(size_t)(r0 + ty + 8 * i) * C + c0 + tx];
  __syncthreads();
#pragma unroll
  for (int i = 0; i < 4; ++i)
    d[(size_t)(c0 + ty + 8 * i) * R + r0 + tx] = f2bf(tl[tx][ty + 8 * i]);
}

// ---------------------------------------------------------------------------
// bf16 MFMA GEMM: C[M,N] = ep(alpha * A[M,K] @ B[K,N]) with B supplied
// TRANSPOSED as BT[N,K]. BM=64, BN=128, BK=32, 128 threads = 2 waves.
// MODE 0: plain alpha* store (row-major, batched via z)
// MODE 1: E_T[b][n][t] = exp2(alpha*v), b = m>>8, t = m&255 (transposed)
// MODE 2: exp2(alpha*v) row-major
// ---------------------------------------------------------------------------
template <int MODE>
__global__ __launch_bounds__(128) void gemm_bf16(
    const ushort* __restrict__ A, int lda, long sA,
    const ushort* __restrict__ BT, int ldb, long sB,
    float* __restrict__ C, int ldc, long sC, int K, float alpha)
{
  __shared__ __attribute__((aligned(16))) ushort As[64 * 40];   // pitch 40 (pad)
  __shared__ __attribute__((aligned(16))) ushort Bs[128 * 40];

  const int tid = threadIdx.x;
  const int l = tid & 63;
  const int w = tid >> 6;
  const int l15 = l & 15, l4 = l >> 4;
  const long z = blockIdx.z;
  const int bn = blockIdx.x * 128, bm = blockIdx.y * 64;

  const ushort* Ag = A + z * sA + (long)bm * lda;
  const ushort* Bg = BT + z * sB + (long)bn * ldb;

  floatx4 acc[2][8] = {};

  for (int kt = 0; kt < K; kt += 32) {
    __syncthreads();
#pragma unroll
    for (int q = 0; q < 2; ++q) {
      int tau = q * 128 + tid;
      int row = tau >> 2, kc = (tau & 3) << 3;
      *(short8v*)&As[row * 40 + kc] =
          *(const short8v*)(Ag + (long)row * lda + kt + kc);
    }
#pragma unroll
    for (int q = 0; q < 4; ++q) {
      int tau = q * 128 + tid;
      int row = tau >> 2, kc = (tau & 3) << 3;
      *(short8v*)&Bs[row * 40 + kc] =
          *(const short8v*)(Bg + (long)row * ldb + kt + kc);
    }
    __syncthreads();

    short8v a0 = *(short8v*)&As[(w * 32 + l15) * 40 + l4 * 8];
    short8v a1 = *(short8v*)&As[(w * 32 + 16 + l15) * 40 + l4 * 8];
#pragma unroll
    for (int nt = 0; nt < 8; ++nt) {
      short8v bf = *(short8v*)&Bs[(nt * 16 + l15) * 40 + l4 * 8];
      acc[0][nt] = __builtin_amdgcn_mfma_f32_16x16x32_bf16(a0, bf, acc[0][nt], 0, 0, 0);
      acc[1][nt] = __builtin_amdgcn_mfma_f32_16x16x32_bf16(a1, bf, acc[1][nt], 0, 0, 0);
    }
  }

  const int rb = l4 << 2;
#pragma unroll
  for (int mt = 0; mt < 2; ++mt) {
    const int growb = bm + w * 32 + mt * 16 + rb;
#pragma unroll
    for (int nt = 0; nt < 8; ++nt) {
      const int gcol = bn + nt * 16 + l15;
#pragma unroll
      for (int r = 0; r < 4; ++r) {
        const float v = alpha * acc[mt][nt][r];
        const int grow = growb + r;
        if (MODE == 0) {
          C[z * sC + (long)grow * ldc + gcol] = v;
        } else if (MODE == 1) {
          const int bb = grow >> 8, t = grow & 255;
          C[(size_t)(bb * H_ + gcol) * TE_ + t] = __builtin_amdgcn_exp2f(v);
        } else {
          C[(long)grow * ldc + gcol] = __builtin_amdgcn_exp2f(v);
        }
      }
    }
  }
}

// ---------------------------------------------------------------------------
// Energies + softmax from precomputed exponentials.
//   E_T[b][h][t] = exp2(C*Ws),  eU[b][d][h] = exp2(C*Uh)
//   tanh(Ws+Uh) = 1 - 2 * rcp(E*eU + 1)
// Block = (b, 4 decoder rows), 512 threads = 8 waves; wave w owns h-slice
// [64w, 64w+64) and accumulates ALL 4 d rows (16 indep rcp chains/lane).
// Lane owns t-quad [4L..4L+3]; one E float4 feeds 16 elements. Partials
// part[d][w][t] combined by waves 0-3 (one per d) for the softmax.
// ---------------------------------------------------------------------------
__global__ __launch_bounds__(512) void energies_softmax(
    const float* __restrict__ E_T, const float* __restrict__ eU,
    const float* __restrict__ Va, float* __restrict__ e_out,
    ushort* __restrict__ eB)
{
  __shared__ float part[4][8][TE_];

  const int tid  = threadIdx.x;
  const int lane = tid & 63;
  const int wv   = __builtin_amdgcn_readfirstlane(tid >> 6);  // h-eighth
  const int b    = blockIdx.y;
  const int d0   = blockIdx.x << 2;

  // total sum of V over all h (tanh identity constant)
  float4 v0 = *(const float4*)(Va + (lane << 2));
  float4 v1 = *(const float4*)(Va + 256 + (lane << 2));
  const float svtot =
      wave_sum(v0.x + v0.y + v0.z + v0.w + v1.x + v1.y + v1.z + v1.w);

  const float* u0 = eU + (size_t)(b * TD_ + d0 + 0) * H_ + wv * 64;
  const float* u1 = eU + (size_t)(b * TD_ + d0 + 1) * H_ + wv * 64;
  const float* u2 = eU + (size_t)(b * TD_ + d0 + 2) * H_ + wv * 64;
  const float* u3 = eU + (size_t)(b * TD_ + d0 + 3) * H_ + wv * 64;
  const float* vp = Va + wv * 64;
  const float4* ep = (const float4*)(E_T + (size_t)(b * H_ + wv * 64) * TE_) + lane;

  float p0[4] = {}, p1[4] = {}, p2[4] = {}, p3[4] = {};

#pragma unroll 2
  for (int h = 0; h < 64; ++h) {
    const float sV = vp[h];
    const float sU0 = u0[h], sU1 = u1[h], sU2 = u2[h], sU3 = u3[h];
    float4 w = ep[(size_t)h * (TE_ / 4)];
    float e0 = w.x, e1 = w.y, e2 = w.z, e3 = w.w;
    p0[0] = fmaf(sV, __builtin_amdgcn_rcpf(fmaf(e0, sU0, 1.f)), p0[0]);
    p0[1] = fmaf(sV, __builtin_amdgcn_rcpf(fmaf(e1, sU0, 1.f)), p0[1]);
    p0[2] = fmaf(sV, __builtin_amdgcn_rcpf(fmaf(e2, sU0, 1.f)), p0[2]);
    p0[3] = fmaf(sV, __builtin_amdgcn_rcpf(fmaf(e3, sU0, 1.f)), p0[3]);
    p1[0] = fmaf(sV, __builtin_amdgcn_rcpf(fmaf(e0, sU1, 1.f)), p1[0]);
    p1[1] = fmaf(sV, __builtin_amdgcn_rcpf(fmaf(e1, sU1, 1.f)), p1[1]);
    p1[2] = fmaf(sV, __builtin_amdgcn_rcpf(fmaf(e2, sU1, 1.f)), p1[2]);
    p1[3] = fmaf(sV, __builtin_amdgcn_rcpf(fmaf(e3, sU1, 1.f)), p1[3]);
    p2[0] = fmaf(sV, __builtin_amdgcn_rcpf(fmaf(e0, sU2, 1.f)), p2[0]);
    p2[1] = fmaf(sV, __builtin_amdgcn_rcpf(fmaf(e1, sU2, 1.f)), p2[1]);
    p2[2] = fmaf(sV, __builtin_amdgcn_rcpf(fmaf(e2, sU2, 1.f)), p2[2]);
    p2[3] = fmaf(sV, __builtin_amdgcn_rcpf(fmaf(e3, sU2, 1.f)), p2[3]);
    p3[0] = fmaf(sV, __builtin_amdgcn_rcpf(fmaf(e0, sU3, 1.f)), p3[0]);
    p3[1] = fmaf(sV, __builtin_amdgcn_rcpf(fmaf(e1, sU3, 1.f)), p3[1]);
    p3[2] = fmaf(sV, __builtin_amdgcn_rcpf(fmaf(e2, sU3, 1.f)), p3[2]);
    p3[3] = fmaf(sV, __builtin_amdgcn_rcpf(fmaf(e3, sU3, 1.f)), p3[3]);
  }

  *(float4*)&part[0][wv][lane << 2] = *(float4*)p0;
  *(float4*)&part[1][wv][lane << 2] = *(float4*)p1;
  *(float4*)&part[2][wv][lane << 2] = *(float4*)p2;
  *(float4*)&part[3][wv][lane << 2] = *(float4*)p3;
  __syncthreads();

  // softmax: wave w in 0..3 handles d = d0 + w
  if (wv < 4) {
    float l[4] = {0.f, 0.f, 0.f, 0.f};
#pragma unroll
    for (int w = 0; w < 8; ++w) {
      float4 q = *(const float4*)&part[wv][w][lane << 2];
      l[0] += q.x; l[1] += q.y; l[2] += q.z; l[3] += q.w;
    }
#pragma unroll
    for (int q = 0; q < 4; ++q) l[q] = svtot - 2.f * l[q];
    float m = wave_max(fmaxf(fmaxf(l[0], l[1]), fmaxf(l[2], l[3])));
    float p[4];
    float s = 0.f;
#pragma unroll
    for (int q = 0; q < 4; ++q) {
      p[q] = __builtin_amdgcn_exp2f((l[q] - m) * LOG2E);
      s += p[q];
    }
    s = wave_sum(s);
    const float inv = 1.0f / s;
    float4 ov = {p[0] * inv, p[1] * inv, p[2] * inv, p[3] * inv};
    const size_t ro = (size_t)(b * TD_ + d0 + wv) * TE_ + (lane << 2);
    *(float4*)(e_out + ro) = ov;
    ushort4 ob = {f2bf(ov.x), f2bf(ov.y), f2bf(ov.z), f2bf(ov.w)};
    *(ushort4*)(eB + ro) = ob;
  }
}

// ---------------------------------------------------------------------------
extern "C" void kernel_launch(void* const* d_in, const int* in_sizes, int n_in,
                              void* d_out, int out_size, void* d_ws, size_t ws_size,
                              hipStream_t stream) {
  const float* enc = (const float*)d_in[0];  // [B, TE, H]
  const float* dec = (const float*)d_in[1];  // [B, TD, H]
  const float* Wa  = (const float*)d_in[2];  // [H, H]
  const float* Ua  = (const float*)d_in[3];  // [H, H]
  const float* Va  = (const float*)d_in[4];  // [H]

  float* out_c = (float*)d_out;                       // [B, TD, H]
  float* out_e = out_c + (size_t)B_ * TD_ * H_;       // [B, TD, TE]

  char* w8 = (char*)d_ws;                             // 24 MB total
  float*  E_T  = (float*)(w8);                        // [B][H][TE] f32   8 MB
  float*  eU   = (float*)(w8 + (8u << 20));           // [B][TD][H] f32   4 MB
  ushort* encB = (ushort*)(w8 + (12u << 20));         // [B*TE][H] bf16   4 MB
  ushort* decB = (ushort*)(w8 + (16u << 20));         // [B*TD][H] bf16   2 MB
  ushort* WaT  = (ushort*)(w8 + (18u << 20));         // [H][H]    bf16 0.5 MB
  ushort* UaT  = (ushort*)(w8 + (18u << 20) + (512u << 10));
  ushort* encT = (ushort*)(w8 + (19u << 20));         // [B][H][TE] bf16  4 MB
  ushort* eB   = (ushort*)(w8 + (23u << 20));         // [B][TD][TE] bf16 1 MB

  // Pre-pass
  prep_enc<<<dim3(H_ / 32, TE_ / 32, B_), 256, 0, stream>>>(enc, encB, encT);
  cvt_bf16<<<(B_ * TD_ * H_) / 4 / 256, 256, 0, stream>>>(
      dec, decB, (B_ * TD_ * H_) / 4);
  transpose_cvt<<<dim3(16, 16, 2), 256, 0, stream>>>(
      Wa, WaT, 1, Ua, UaT, H_, H_, 0, 0);

  // A1: E_T = exp2(C * enc @ Wa), stored [b][h][t]
  gemm_bf16<1><<<dim3(4, 64, 1), 128, 0, stream>>>(
      encB, H_, 0, WaT, H_, 0, E_T, 0, 0, H_, C_TANH);
  // A2: eU = exp2(C * dec @ Ua), row-major
  gemm_bf16<2><<<dim3(4, 32, 1), 128, 0, stream>>>(
      decB, H_, 0, UaT, H_, 0, eU, H_, 0, H_, C_TANH);

  // B: energies + softmax -> out_e (f32) + eB (bf16)
  energies_softmax<<<dim3(TD_ / 4, B_, 1), 512, 0, stream>>>(E_T, eU, Va, out_e, eB);

  // C: c[b] = e[b] @ enc[b] via bf16 MFMA (BT = encT)
  gemm_bf16<0><<<dim3(4, 2, 16), 128, 0, stream>>>(
      eB, TE_, (long)TD_ * TE_, encT, TE_, (long)H_ * TE_,
      out_c, H_, (long)TD_ * H_, TE_, 1.0f);
}

// Round 7
// 71.315 us; speedup vs baseline: 2.4467x; 1.2531x over previous
//
#include <hip/hip_runtime.h>

// Problem shapes (fixed by setup_inputs)
#define B_  16
#define TE_ 256
#define TD_ 128
#define H_  512

#define C_TANH 2.88539008177792681472f  // 2*log2(e):  tanh(x) = 1 - 2/(exp2(C*x)+1)
#define LOG2E  1.44269504088896340736f

typedef __attribute__((ext_vector_type(8))) short short8v;   // 8 x bf16 (4 VGPR)
typedef __attribute__((ext_vector_type(4))) float floatx4;   // MFMA acc

__device__ __forceinline__ float wave_sum(float v) {
#pragma unroll
  for (int m = 32; m; m >>= 1) v += __shfl_xor(v, m, 64);
  return v;
}
__device__ __forceinline__ float wave_max(float v) {
#pragma unroll
  for (int m = 32; m; m >>= 1) v = fmaxf(v, __shfl_xor(v, m, 64));
  return v;
}
__device__ __forceinline__ ushort f2bf(float f) {  // RNE fp32->bf16
  unsigned u = __builtin_bit_cast(unsigned, f);
  u += 0x7fffu + ((u >> 16) & 1u);
  return (ushort)(u >> 16);
}
__device__ __forceinline__ float bf2f(ushort u) {
  return __builtin_bit_cast(float, (unsigned)u << 16);
}

// ---------------------------------------------------------------------------
// One prep kernel for everything (grid (16, 14, 16), 256 thr):
//  y in [0,8):  enc b=z tile (r0=y*32 in Te, c0=x*32 in H) -> encB (row cvt)
//               + encT (transpose cvt)
//  y in [8,12): dec b=z tile (r0=(y-8)*32 in Td) -> decB (row cvt)
//  y == 12/13:  Wa/Ua tile (r0=z*32, c0=x*32) -> WaT/UaT (transpose cvt)
// ---------------------------------------------------------------------------
__global__ __launch_bounds__(256) void prep_all(
    const float* __restrict__ enc, const float* __restrict__ dec,
    const float* __restrict__ Wa, const float* __restrict__ Ua,
    ushort* __restrict__ encB, ushort* __restrict__ decB,
    ushort* __restrict__ encT, ushort* __restrict__ WaT,
    ushort* __restrict__ UaT)
{
  __shared__ float tl[32][33];
  const int tx = threadIdx.x & 31, ty = threadIdx.x >> 5;
  const int x = blockIdx.x, y = blockIdx.y, z = blockIdx.z;

  if (y < 8) {
    const float* s = enc + (size_t)z * TE_ * H_;
    ushort* dB = encB + (size_t)z * TE_ * H_;
    ushort* dT = encT + (size_t)z * H_ * TE_;
    const int r0 = y * 32, c0 = x * 32;
#pragma unroll
    for (int i = 0; i < 4; ++i) {
      float v = s[(size_t)(r0 + ty + 8 * i) * H_ + c0 + tx];
      tl[ty + 8 * i][tx] = v;
      dB[(size_t)(r0 + ty + 8 * i) * H_ + c0 + tx] = f2bf(v);
    }
    __syncthreads();
#pragma unroll
    for (int i = 0; i < 4; ++i)
      dT[(size_t)(c0 + ty + 8 * i) * TE_ + r0 + tx] = f2bf(tl[tx][ty + 8 * i]);
  } else if (y < 12) {
    const float* s = dec + (size_t)z * TD_ * H_;
    ushort* d = decB + (size_t)z * TD_ * H_;
    const int r0 = (y - 8) * 32, c0 = x * 32;
#pragma unroll
    for (int i = 0; i < 4; ++i)
      d[(size_t)(r0 + ty + 8 * i) * H_ + c0 + tx] =
          f2bf(s[(size_t)(r0 + ty + 8 * i) * H_ + c0 + tx]);
  } else {
    const float* s = (y == 12) ? Wa : Ua;
    ushort* d = (y == 12) ? WaT : UaT;
    const int r0 = z * 32, c0 = x * 32;
#pragma unroll
    for (int i = 0; i < 4; ++i)
      tl[ty + 8 * i][tx] = s[(size_t)(r0 + ty + 8 * i) * H_ + c0 + tx];
    __syncthreads();
#pragma unroll
    for (int i = 0; i < 4; ++i)
      d[(size_t)(c0 + ty + 8 * i) * H_ + r0 + tx] = f2bf(tl[tx][ty + 8 * i]);
  }
}

// ---------------------------------------------------------------------------
// Fused phase-A GEMM (grid (4, 96), 128 thr = 2 waves). BM=64 BN=128 BK=32.
//  y < 64:  E_T[b][h][t] = bf16(exp2(C * (enc@Wa)[m][h])),  m = b*256+t
//  y >= 64: eU[m][h]     = f32 (exp2(C * (dec@Ua)[m][h])),  row-major
// Both operands bf16 K-contiguous (A row-major, BT = B^T).
// ---------------------------------------------------------------------------
__global__ __launch_bounds__(128) void gemm_phaseA(
    const ushort* __restrict__ encB, const ushort* __restrict__ WaT,
    ushort* __restrict__ E_T,
    const ushort* __restrict__ decB, const ushort* __restrict__ UaT,
    float* __restrict__ eU)
{
  __shared__ __attribute__((aligned(16))) ushort As[64 * 40];
  __shared__ __attribute__((aligned(16))) ushort Bs[128 * 40];

  const int tid = threadIdx.x;
  const int l = tid & 63;
  const int w = tid >> 6;
  const int l15 = l & 15, l4 = l >> 4;
  const bool isA1 = blockIdx.y < 64;
  const int my = isA1 ? blockIdx.y : blockIdx.y - 64;
  const int bn = blockIdx.x * 128, bm = my * 64;

  const ushort* Ag = (isA1 ? encB : decB) + (long)bm * H_;
  const ushort* Bg = (isA1 ? WaT : UaT) + (long)bn * H_;

  floatx4 acc[2][8] = {};

  for (int kt = 0; kt < H_; kt += 32) {
    __syncthreads();
#pragma unroll
    for (int q = 0; q < 2; ++q) {
      int tau = q * 128 + tid;
      int row = tau >> 2, kc = (tau & 3) << 3;
      *(short8v*)&As[row * 40 + kc] =
          *(const short8v*)(Ag + (long)row * H_ + kt + kc);
    }
#pragma unroll
    for (int q = 0; q < 4; ++q) {
      int tau = q * 128 + tid;
      int row = tau >> 2, kc = (tau & 3) << 3;
      *(short8v*)&Bs[row * 40 + kc] =
          *(const short8v*)(Bg + (long)row * H_ + kt + kc);
    }
    __syncthreads();

    short8v a0 = *(short8v*)&As[(w * 32 + l15) * 40 + l4 * 8];
    short8v a1 = *(short8v*)&As[(w * 32 + 16 + l15) * 40 + l4 * 8];
#pragma unroll
    for (int nt = 0; nt < 8; ++nt) {
      short8v bf = *(short8v*)&Bs[(nt * 16 + l15) * 40 + l4 * 8];
      acc[0][nt] = __builtin_amdgcn_mfma_f32_16x16x32_bf16(a0, bf, acc[0][nt], 0, 0, 0);
      acc[1][nt] = __builtin_amdgcn_mfma_f32_16x16x32_bf16(a1, bf, acc[1][nt], 0, 0, 0);
    }
  }

  const int rb = l4 << 2;
#pragma unroll
  for (int mt = 0; mt < 2; ++mt) {
    const int growb = bm + w * 32 + mt * 16 + rb;
#pragma unroll
    for (int nt = 0; nt < 8; ++nt) {
      const int gcol = bn + nt * 16 + l15;
      if (isA1) {
        const int bb = growb >> 8, t0 = growb & 255;
        ushort4 ev;
        ev.x = f2bf(__builtin_amdgcn_exp2f(C_TANH * acc[mt][nt][0]));
        ev.y = f2bf(__builtin_amdgcn_exp2f(C_TANH * acc[mt][nt][1]));
        ev.z = f2bf(__builtin_amdgcn_exp2f(C_TANH * acc[mt][nt][2]));
        ev.w = f2bf(__builtin_amdgcn_exp2f(C_TANH * acc[mt][nt][3]));
        *(ushort4*)(E_T + ((size_t)bb * H_ + gcol) * TE_ + t0) = ev;
      } else {
#pragma unroll
        for (int r = 0; r < 4; ++r)
          eU[(size_t)(growb + r) * H_ + gcol] =
              __builtin_amdgcn_exp2f(C_TANH * acc[mt][nt][r]);
      }
    }
  }
}

// ---------------------------------------------------------------------------
// bf16 MFMA GEMM for phase C (BT supplied transposed), plain store.
// ---------------------------------------------------------------------------
__global__ __launch_bounds__(128) void gemm_ctx(
    const ushort* __restrict__ A, int lda, long sA,
    const ushort* __restrict__ BT, int ldb, long sB,
    float* __restrict__ C, int ldc, long sC, int K)
{
  __shared__ __attribute__((aligned(16))) ushort As[64 * 40];
  __shared__ __attribute__((aligned(16))) ushort Bs[128 * 40];

  const int tid = threadIdx.x;
  const int l = tid & 63;
  const int w = tid >> 6;
  const int l15 = l & 15, l4 = l >> 4;
  const long z = blockIdx.z;
  const int bn = blockIdx.x * 128, bm = blockIdx.y * 64;

  const ushort* Ag = A + z * sA + (long)bm * lda;
  const ushort* Bg = BT + z * sB + (long)bn * ldb;

  floatx4 acc[2][8] = {};

  for (int kt = 0; kt < K; kt += 32) {
    __syncthreads();
#pragma unroll
    for (int q = 0; q < 2; ++q) {
      int tau = q * 128 + tid;
      int row = tau >> 2, kc = (tau & 3) << 3;
      *(short8v*)&As[row * 40 + kc] =
          *(const short8v*)(Ag + (long)row * lda + kt + kc);
    }
#pragma unroll
    for (int q = 0; q < 4; ++q) {
      int tau = q * 128 + tid;
      int row = tau >> 2, kc = (tau & 3) << 3;
      *(short8v*)&Bs[row * 40 + kc] =
          *(const short8v*)(Bg + (long)row * ldb + kt + kc);
    }
    __syncthreads();

    short8v a0 = *(short8v*)&As[(w * 32 + l15) * 40 + l4 * 8];
    short8v a1 = *(short8v*)&As[(w * 32 + 16 + l15) * 40 + l4 * 8];
#pragma unroll
    for (int nt = 0; nt < 8; ++nt) {
      short8v bf = *(short8v*)&Bs[(nt * 16 + l15) * 40 + l4 * 8];
      acc[0][nt] = __builtin_amdgcn_mfma_f32_16x16x32_bf16(a0, bf, acc[0][nt], 0, 0, 0);
      acc[1][nt] = __builtin_amdgcn_mfma_f32_16x16x32_bf16(a1, bf, acc[1][nt], 0, 0, 0);
    }
  }

  const int rb = l4 << 2;
#pragma unroll
  for (int mt = 0; mt < 2; ++mt) {
    const int growb = bm + w * 32 + mt * 16 + rb;
#pragma unroll
    for (int nt = 0; nt < 8; ++nt) {
      const int gcol = bn + nt * 16 + l15;
#pragma unroll
      for (int r = 0; r < 4; ++r)
        C[z * sC + (long)(growb + r) * ldc + gcol] = acc[mt][nt][r];
    }
  }
}

// ---------------------------------------------------------------------------
// Energies + softmax from precomputed exponentials.
//   E_T[b][h][t] = bf16(exp2(C*Ws)),  eU[b][d][h] = exp2(C*Uh)
//   tanh(Ws+Uh) = 1 - 2 * rcp(E*eU + 1)
// 1-D grid of 512 blocks, XCD-swizzled so each XCD's blocks share 2 b values
// (E working set 0.5 MB -> L2-resident). 512 thr = 8 waves; wave w owns
// h in [64w,64w+64) for all 4 d rows (16 indep rcp chains/lane). Lane owns
// t-quad [4L..4L+3]. Partials combined in LDS; waves 0-3 do the softmaxes.
// ---------------------------------------------------------------------------
__global__ __launch_bounds__(512) void energies_softmax(
    const ushort* __restrict__ E_T, const float* __restrict__ eU,
    const float* __restrict__ Va, float* __restrict__ e_out,
    ushort* __restrict__ eB)
{
  __shared__ float part[4][8][TE_];

  const int tid  = threadIdx.x;
  const int lane = tid & 63;
  const int wv   = __builtin_amdgcn_readfirstlane(tid >> 6);  // h-eighth
  const int id   = blockIdx.x;           // 0..511
  const int xcd  = id & 7, j = id >> 3;  // XCD swizzle: XCD x -> b in {2x,2x+1}
  const int b    = (xcd << 1) | (j >> 5);
  const int d0   = (j & 31) << 2;

  // total sum of V over all h (tanh identity constant)
  float4 v0 = *(const float4*)(Va + (lane << 2));
  float4 v1 = *(const float4*)(Va + 256 + (lane << 2));
  const float svtot =
      wave_sum(v0.x + v0.y + v0.z + v0.w + v1.x + v1.y + v1.z + v1.w);

  const float* u0 = eU + (size_t)(b * TD_ + d0 + 0) * H_ + wv * 64;
  const float* u1 = eU + (size_t)(b * TD_ + d0 + 1) * H_ + wv * 64;
  const float* u2 = eU + (size_t)(b * TD_ + d0 + 2) * H_ + wv * 64;
  const float* u3 = eU + (size_t)(b * TD_ + d0 + 3) * H_ + wv * 64;
  const float* vp = Va + wv * 64;
  const ushort* ep = E_T + ((size_t)(b * H_) + wv * 64) * TE_ + (lane << 2);

  float p0[4] = {}, p1[4] = {}, p2[4] = {}, p3[4] = {};

#pragma unroll 2
  for (int h = 0; h < 64; ++h) {
    const float sV = vp[h];
    const float sU0 = u0[h], sU1 = u1[h], sU2 = u2[h], sU3 = u3[h];
    ushort4 ew = *(const ushort4*)(ep + (size_t)h * TE_);
    float e0 = bf2f(ew.x), e1 = bf2f(ew.y), e2 = bf2f(ew.z), e3 = bf2f(ew.w);
    p0[0] = fmaf(sV, __builtin_amdgcn_rcpf(fmaf(e0, sU0, 1.f)), p0[0]);
    p0[1] = fmaf(sV, __builtin_amdgcn_rcpf(fmaf(e1, sU0, 1.f)), p0[1]);
    p0[2] = fmaf(sV, __builtin_amdgcn_rcpf(fmaf(e2, sU0, 1.f)), p0[2]);
    p0[3] = fmaf(sV, __builtin_amdgcn_rcpf(fmaf(e3, sU0, 1.f)), p0[3]);
    p1[0] = fmaf(sV, __builtin_amdgcn_rcpf(fmaf(e0, sU1, 1.f)), p1[0]);
    p1[1] = fmaf(sV, __builtin_amdgcn_rcpf(fmaf(e1, sU1, 1.f)), p1[1]);
    p1[2] = fmaf(sV, __builtin_amdgcn_rcpf(fmaf(e2, sU1, 1.f)), p1[2]);
    p1[3] = fmaf(sV, __builtin_amdgcn_rcpf(fmaf(e3, sU1, 1.f)), p1[3]);
    p2[0] = fmaf(sV, __builtin_amdgcn_rcpf(fmaf(e0, sU2, 1.f)), p2[0]);
    p2[1] = fmaf(sV, __builtin_amdgcn_rcpf(fmaf(e1, sU2, 1.f)), p2[1]);
    p2[2] = fmaf(sV, __builtin_amdgcn_rcpf(fmaf(e2, sU2, 1.f)), p2[2]);
    p2[3] = fmaf(sV, __builtin_amdgcn_rcpf(fmaf(e3, sU2, 1.f)), p2[3]);
    p3[0] = fmaf(sV, __builtin_amdgcn_rcpf(fmaf(e0, sU3, 1.f)), p3[0]);
    p3[1] = fmaf(sV, __builtin_amdgcn_rcpf(fmaf(e1, sU3, 1.f)), p3[1]);
    p3[2] = fmaf(sV, __builtin_amdgcn_rcpf(fmaf(e2, sU3, 1.f)), p3[2]);
    p3[3] = fmaf(sV, __builtin_amdgcn_rcpf(fmaf(e3, sU3, 1.f)), p3[3]);
  }

  *(float4*)&part[0][wv][lane << 2] = *(float4*)p0;
  *(float4*)&part[1][wv][lane << 2] = *(float4*)p1;
  *(float4*)&part[2][wv][lane << 2] = *(float4*)p2;
  *(float4*)&part[3][wv][lane << 2] = *(float4*)p3;
  __syncthreads();

  if (wv < 4) {  // wave w -> d = d0 + w
    float l[4] = {0.f, 0.f, 0.f, 0.f};
#pragma unroll
    for (int w = 0; w < 8; ++w) {
      float4 q = *(const float4*)&part[wv][w][lane << 2];
      l[0] += q.x; l[1] += q.y; l[2] += q.z; l[3] += q.w;
    }
#pragma unroll
    for (int q = 0; q < 4; ++q) l[q] = svtot - 2.f * l[q];
    float m = wave_max(fmaxf(fmaxf(l[0], l[1]), fmaxf(l[2], l[3])));
    float p[4];
    float s = 0.f;
#pragma unroll
    for (int q = 0; q < 4; ++q) {
      p[q] = __builtin_amdgcn_exp2f((l[q] - m) * LOG2E);
      s += p[q];
    }
    s = wave_sum(s);
    const float inv = 1.0f / s;
    float4 ov = {p[0] * inv, p[1] * inv, p[2] * inv, p[3] * inv};
    const size_t ro = (size_t)(b * TD_ + d0 + wv) * TE_ + (lane << 2);
    *(float4*)(e_out + ro) = ov;
    ushort4 ob = {f2bf(ov.x), f2bf(ov.y), f2bf(ov.z), f2bf(ov.w)};
    *(ushort4*)(eB + ro) = ob;
  }
}

// ---------------------------------------------------------------------------
extern "C" void kernel_launch(void* const* d_in, const int* in_sizes, int n_in,
                              void* d_out, int out_size, void* d_ws, size_t ws_size,
                              hipStream_t stream) {
  const float* enc = (const float*)d_in[0];  // [B, TE, H]
  const float* dec = (const float*)d_in[1];  // [B, TD, H]
  const float* Wa  = (const float*)d_in[2];  // [H, H]
  const float* Ua  = (const float*)d_in[3];  // [H, H]
  const float* Va  = (const float*)d_in[4];  // [H]

  float* out_c = (float*)d_out;                       // [B, TD, H]
  float* out_e = out_c + (size_t)B_ * TD_ * H_;       // [B, TD, TE]

  char* w8 = (char*)d_ws;                             // 20 MB used
  ushort* E_T  = (ushort*)(w8);                       // [B][H][TE] bf16  4 MB
  float*  eU   = (float*)(w8 + (4u << 20));           // [B][TD][H] f32   4 MB
  ushort* encB = (ushort*)(w8 + (8u << 20));          // [B*TE][H]  bf16  4 MB
  ushort* decB = (ushort*)(w8 + (12u << 20));         // [B*TD][H]  bf16  2 MB
  ushort* WaT  = (ushort*)(w8 + (14u << 20));         // [H][H]     bf16 .5 MB
  ushort* UaT  = (ushort*)(w8 + (14u << 20) + (512u << 10));
  ushort* encT = (ushort*)(w8 + (15u << 20));         // [B][H][TE] bf16  4 MB
  ushort* eB   = (ushort*)(w8 + (19u << 20));         // [B][TD][TE]bf16  1 MB

  // Prep: all conversions/transposes in one launch
  prep_all<<<dim3(16, 14, 16), 256, 0, stream>>>(
      enc, dec, Wa, Ua, encB, decB, encT, WaT, UaT);

  // A1+A2 fused: E_T (bf16, transposed) and eU (f32)
  gemm_phaseA<<<dim3(4, 96, 1), 128, 0, stream>>>(
      encB, WaT, E_T, decB, UaT, eU);

  // B: energies + softmax -> out_e (f32) + eB (bf16)
  energies_softmax<<<512, 512, 0, stream>>>(E_T, eU, Va, out_e, eB);

  // C: c[b] = e[b] @ enc[b] via bf16 MFMA (BT = encT)
  gemm_ctx<<<dim3(4, 2, 16), 128, 0, stream>>>(
      eB, TE_, (long)TD_ * TE_, encT, TE_, (long)H_ * TE_,
      out_c, H_, (long)TD_ * H_, TE_);
}

// Round 8
// 65.725 us; speedup vs baseline: 2.6548x; 1.0850x over previous
//
#include <hip/hip_runtime.h>

// Problem shapes (fixed by setup_inputs)
#define B_  16
#define TE_ 256
#define TD_ 128
#define H_  512

#define C_TANH 2.88539008177792681472f  // 2*log2(e):  tanh(x) = 1 - 2/(exp2(C*x)+1)
#define LOG2E  1.44269504088896340736f

typedef __attribute__((ext_vector_type(8))) short short8v;   // 8 x bf16 (4 VGPR)
typedef __attribute__((ext_vector_type(4))) float floatx4;   // MFMA acc

__device__ __forceinline__ float wave_sum(float v) {
#pragma unroll
  for (int m = 32; m; m >>= 1) v += __shfl_xor(v, m, 64);
  return v;
}
__device__ __forceinline__ float wave_max(float v) {
#pragma unroll
  for (int m = 32; m; m >>= 1) v = fmaxf(v, __shfl_xor(v, m, 64));
  return v;
}
__device__ __forceinline__ ushort f2bf(float f) {  // RNE fp32->bf16
  unsigned u = __builtin_bit_cast(unsigned, f);
  u += 0x7fffu + ((u >> 16) & 1u);
  return (ushort)(u >> 16);
}
__device__ __forceinline__ float bf2f(ushort u) {
  return __builtin_bit_cast(float, (unsigned)u << 16);
}

// ---------------------------------------------------------------------------
// One prep kernel (grid (16, 14, 16), 256 thr):
//  y in [0,8):  enc b=z tile -> encB (row cvt) + encT (transpose cvt)
//  y in [8,12): dec b=z tile -> decB (row cvt)
//  y == 12/13:  Wa/Ua tile (r0=z*32, c0=x*32) -> WaT/UaT (transpose cvt)
// ---------------------------------------------------------------------------
__global__ __launch_bounds__(256) void prep_all(
    const float* __restrict__ enc, const float* __restrict__ dec,
    const float* __restrict__ Wa, const float* __restrict__ Ua,
    ushort* __restrict__ encB, ushort* __restrict__ decB,
    ushort* __restrict__ encT, ushort* __restrict__ WaT,
    ushort* __restrict__ UaT)
{
  __shared__ float tl[32][33];
  const int tx = threadIdx.x & 31, ty = threadIdx.x >> 5;
  const int x = blockIdx.x, y = blockIdx.y, z = blockIdx.z;

  if (y < 8) {
    const float* s = enc + (size_t)z * TE_ * H_;
    ushort* dB = encB + (size_t)z * TE_ * H_;
    ushort* dT = encT + (size_t)z * H_ * TE_;
    const int r0 = y * 32, c0 = x * 32;
#pragma unroll
    for (int i = 0; i < 4; ++i) {
      float v = s[(size_t)(r0 + ty + 8 * i) * H_ + c0 + tx];
      tl[ty + 8 * i][tx] = v;
      dB[(size_t)(r0 + ty + 8 * i) * H_ + c0 + tx] = f2bf(v);
    }
    __syncthreads();
#pragma unroll
    for (int i = 0; i < 4; ++i)
      dT[(size_t)(c0 + ty + 8 * i) * TE_ + r0 + tx] = f2bf(tl[tx][ty + 8 * i]);
  } else if (y < 12) {
    const float* s = dec + (size_t)z * TD_ * H_;
    ushort* d = decB + (size_t)z * TD_ * H_;
    const int r0 = (y - 8) * 32, c0 = x * 32;
#pragma unroll
    for (int i = 0; i < 4; ++i)
      d[(size_t)(r0 + ty + 8 * i) * H_ + c0 + tx] =
          f2bf(s[(size_t)(r0 + ty + 8 * i) * H_ + c0 + tx]);
  } else {
    const float* s = (y == 12) ? Wa : Ua;
    ushort* d = (y == 12) ? WaT : UaT;
    const int r0 = z * 32, c0 = x * 32;
#pragma unroll
    for (int i = 0; i < 4; ++i)
      tl[ty + 8 * i][tx] = s[(size_t)(r0 + ty + 8 * i) * H_ + c0 + tx];
    __syncthreads();
#pragma unroll
    for (int i = 0; i < 4; ++i)
      d[(size_t)(c0 + ty + 8 * i) * H_ + r0 + tx] = f2bf(tl[tx][ty + 8 * i]);
  }
}

// ---------------------------------------------------------------------------
// Fused phase-A GEMM, 4 waves/block (256 thr). BM=64 BN=128 BK=32; wave w
// owns m-rows [16w,16w+16), acc[8] over N.
//  blocks [0,256):  A1-FLIPPED: D[h][m] = WaT[h][:] . encB[m][:]  (M=512,
//                   N=4096, m = b*256+t); store E_T[b][h][t] =
//                   bf16(exp2(C*D)) -- coalesced along t.
//  blocks [256,384): A2: eU[m][h] = exp2(C * decB[m][:] . UaT[h][:])
//                   (M=2048, N=512), row-major f32.
// ---------------------------------------------------------------------------
__global__ __launch_bounds__(256) void gemm_phaseA(
    const ushort* __restrict__ encB, const ushort* __restrict__ WaT,
    ushort* __restrict__ E_T,
    const ushort* __restrict__ decB, const ushort* __restrict__ UaT,
    float* __restrict__ eU)
{
  __shared__ __attribute__((aligned(16))) ushort As[64 * 40];   // pitch 40
  __shared__ __attribute__((aligned(16))) ushort Bs[128 * 40];

  const int tid = threadIdx.x;
  const int l = tid & 63;
  const int w = tid >> 6;
  const int l15 = l & 15, l4 = l >> 4;
  const int id = blockIdx.x;
  const bool isA1 = id < 256;
  int bm, bn;
  const ushort *Ag, *Bg;
  if (isA1) {
    bm = (id >> 5) * 64;          // h-tile (M=512)
    bn = (id & 31) * 128;         // m-tile (N=4096)
    Ag = WaT + (long)bm * H_;
    Bg = encB + (long)bn * H_;
  } else {
    const int i2 = id - 256;
    bm = (i2 >> 2) * 64;          // m-tile (M=2048)
    bn = (i2 & 3) * 128;          // h-tile (N=512)
    Ag = decB + (long)bm * H_;
    Bg = UaT + (long)bn * H_;
  }

  floatx4 acc[8] = {};

  for (int kt = 0; kt < H_; kt += 32) {
    __syncthreads();
    {  // A tile: 64x32, 1 chunk of 8 bf16 per thread
      int row = tid >> 2, kc = (tid & 3) << 3;
      *(short8v*)&As[row * 40 + kc] =
          *(const short8v*)(Ag + (long)row * H_ + kt + kc);
    }
#pragma unroll
    for (int q = 0; q < 2; ++q) {  // B tile: 128x32, 2 chunks per thread
      int tau = q * 256 + tid;
      int row = tau >> 2, kc = (tau & 3) << 3;
      *(short8v*)&Bs[row * 40 + kc] =
          *(const short8v*)(Bg + (long)row * H_ + kt + kc);
    }
    __syncthreads();

    short8v a0 = *(short8v*)&As[(w * 16 + l15) * 40 + l4 * 8];
#pragma unroll
    for (int nt = 0; nt < 8; ++nt) {
      short8v bf = *(short8v*)&Bs[(nt * 16 + l15) * 40 + l4 * 8];
      acc[nt] = __builtin_amdgcn_mfma_f32_16x16x32_bf16(a0, bf, acc[nt], 0, 0, 0);
    }
  }

  const int rb = l4 << 2;
  const int growb = bm + w * 16 + rb;
  if (isA1) {
    // E_T[b][h][t], b = gcol>>8 (block-uniform), t = gcol&255, h = grow
    const int bb = bn >> 8;
#pragma unroll
    for (int nt = 0; nt < 8; ++nt) {
      const int t = (bn & 255) + nt * 16 + l15;
#pragma unroll
      for (int r = 0; r < 4; ++r) {
        const int h = growb + r;
        E_T[((size_t)bb * H_ + h) * TE_ + t] =
            f2bf(__builtin_amdgcn_exp2f(C_TANH * acc[nt][r]));
      }
    }
  } else {
#pragma unroll
    for (int nt = 0; nt < 8; ++nt) {
      const int gcol = bn + nt * 16 + l15;
#pragma unroll
      for (int r = 0; r < 4; ++r)
        eU[(size_t)(growb + r) * H_ + gcol] =
            __builtin_amdgcn_exp2f(C_TANH * acc[nt][r]);
    }
  }
}

// ---------------------------------------------------------------------------
// bf16 MFMA GEMM for phase C, 4 waves/block (BT supplied transposed).
// BM=64 BN=128 BK=32; wave owns 16 rows.
// ---------------------------------------------------------------------------
__global__ __launch_bounds__(256) void gemm_ctx(
    const ushort* __restrict__ A, int lda, long sA,
    const ushort* __restrict__ BT, int ldb, long sB,
    float* __restrict__ C, int ldc, long sC, int K)
{
  __shared__ __attribute__((aligned(16))) ushort As[64 * 40];
  __shared__ __attribute__((aligned(16))) ushort Bs[128 * 40];

  const int tid = threadIdx.x;
  const int l = tid & 63;
  const int w = tid >> 6;
  const int l15 = l & 15, l4 = l >> 4;
  const long z = blockIdx.z;
  const int bn = blockIdx.x * 128, bm = blockIdx.y * 64;

  const ushort* Ag = A + z * sA + (long)bm * lda;
  const ushort* Bg = BT + z * sB + (long)bn * ldb;

  floatx4 acc[8] = {};

  for (int kt = 0; kt < K; kt += 32) {
    __syncthreads();
    {
      int row = tid >> 2, kc = (tid & 3) << 3;
      *(short8v*)&As[row * 40 + kc] =
          *(const short8v*)(Ag + (long)row * lda + kt + kc);
    }
#pragma unroll
    for (int q = 0; q < 2; ++q) {
      int tau = q * 256 + tid;
      int row = tau >> 2, kc = (tau & 3) << 3;
      *(short8v*)&Bs[row * 40 + kc] =
          *(const short8v*)(Bg + (long)row * ldb + kt + kc);
    }
    __syncthreads();

    short8v a0 = *(short8v*)&As[(w * 16 + l15) * 40 + l4 * 8];
#pragma unroll
    for (int nt = 0; nt < 8; ++nt) {
      short8v bf = *(short8v*)&Bs[(nt * 16 + l15) * 40 + l4 * 8];
      acc[nt] = __builtin_amdgcn_mfma_f32_16x16x32_bf16(a0, bf, acc[nt], 0, 0, 0);
    }
  }

  const int growb = bm + w * 16 + (l4 << 2);
#pragma unroll
  for (int nt = 0; nt < 8; ++nt) {
    const int gcol = bn + nt * 16 + l15;
#pragma unroll
    for (int r = 0; r < 4; ++r)
      C[z * sC + (long)(growb + r) * ldc + gcol] = acc[nt][r];
  }
}

// ---------------------------------------------------------------------------
// Energies + softmax from precomputed exponentials (unchanged structure).
//   E_T[b][h][t] = bf16(exp2(C*Ws)),  eU[b][d][h] = exp2(C*Uh)
//   tanh(Ws+Uh) = 1 - 2 * rcp(E*eU + 1)
// 512 blocks XCD-swizzled (2 b per XCD -> L2-resident E), 8 waves; wave w
// owns h in [64w,64w+64) for all 4 d rows. Lane owns t-quad [4L..4L+3].
// ---------------------------------------------------------------------------
__global__ __launch_bounds__(512) void energies_softmax(
    const ushort* __restrict__ E_T, const float* __restrict__ eU,
    const float* __restrict__ Va, float* __restrict__ e_out,
    ushort* __restrict__ eB)
{
  __shared__ float part[4][8][TE_];

  const int tid  = threadIdx.x;
  const int lane = tid & 63;
  const int wv   = __builtin_amdgcn_readfirstlane(tid >> 6);  // h-eighth
  const int id   = blockIdx.x;           // 0..511
  const int xcd  = id & 7, j = id >> 3;  // XCD x -> b in {2x, 2x+1}
  const int b    = (xcd << 1) | (j >> 5);
  const int d0   = (j & 31) << 2;

  float4 v0 = *(const float4*)(Va + (lane << 2));
  float4 v1 = *(const float4*)(Va + 256 + (lane << 2));
  const float svtot =
      wave_sum(v0.x + v0.y + v0.z + v0.w + v1.x + v1.y + v1.z + v1.w);

  const float* u0 = eU + (size_t)(b * TD_ + d0 + 0) * H_ + wv * 64;
  const float* u1 = eU + (size_t)(b * TD_ + d0 + 1) * H_ + wv * 64;
  const float* u2 = eU + (size_t)(b * TD_ + d0 + 2) * H_ + wv * 64;
  const float* u3 = eU + (size_t)(b * TD_ + d0 + 3) * H_ + wv * 64;
  const float* vp = Va + wv * 64;
  const ushort* ep = E_T + ((size_t)(b * H_) + wv * 64) * TE_ + (lane << 2);

  float p0[4] = {}, p1[4] = {}, p2[4] = {}, p3[4] = {};

#pragma unroll 4
  for (int h = 0; h < 64; ++h) {
    const float sV = vp[h];
    const float sU0 = u0[h], sU1 = u1[h], sU2 = u2[h], sU3 = u3[h];
    ushort4 ew = *(const ushort4*)(ep + (size_t)h * TE_);
    float e0 = bf2f(ew.x), e1 = bf2f(ew.y), e2 = bf2f(ew.z), e3 = bf2f(ew.w);
    p0[0] = fmaf(sV, __builtin_amdgcn_rcpf(fmaf(e0, sU0, 1.f)), p0[0]);
    p0[1] = fmaf(sV, __builtin_amdgcn_rcpf(fmaf(e1, sU0, 1.f)), p0[1]);
    p0[2] = fmaf(sV, __builtin_amdgcn_rcpf(fmaf(e2, sU0, 1.f)), p0[2]);
    p0[3] = fmaf(sV, __builtin_amdgcn_rcpf(fmaf(e3, sU0, 1.f)), p0[3]);
    p1[0] = fmaf(sV, __builtin_amdgcn_rcpf(fmaf(e0, sU1, 1.f)), p1[0]);
    p1[1] = fmaf(sV, __builtin_amdgcn_rcpf(fmaf(e1, sU1, 1.f)), p1[1]);
    p1[2] = fmaf(sV, __builtin_amdgcn_rcpf(fmaf(e2, sU1, 1.f)), p1[2]);
    p1[3] = fmaf(sV, __builtin_amdgcn_rcpf(fmaf(e3, sU1, 1.f)), p1[3]);
    p2[0] = fmaf(sV, __builtin_amdgcn_rcpf(fmaf(e0, sU2, 1.f)), p2[0]);
    p2[1] = fmaf(sV, __builtin_amdgcn_rcpf(fmaf(e1, sU2, 1.f)), p2[1]);
    p2[2] = fmaf(sV, __builtin_amdgcn_rcpf(fmaf(e2, sU2, 1.f)), p2[2]);
    p2[3] = fmaf(sV, __builtin_amdgcn_rcpf(fmaf(e3, sU2, 1.f)), p2[3]);
    p3[0] = fmaf(sV, __builtin_amdgcn_rcpf(fmaf(e0, sU3, 1.f)), p3[0]);
    p3[1] = fmaf(sV, __builtin_amdgcn_rcpf(fmaf(e1, sU3, 1.f)), p3[1]);
    p3[2] = fmaf(sV, __builtin_amdgcn_rcpf(fmaf(e2, sU3, 1.f)), p3[2]);
    p3[3] = fmaf(sV, __builtin_amdgcn_rcpf(fmaf(e3, sU3, 1.f)), p3[3]);
  }

  *(float4*)&part[0][wv][lane << 2] = *(float4*)p0;
  *(float4*)&part[1][wv][lane << 2] = *(float4*)p1;
  *(float4*)&part[2][wv][lane << 2] = *(float4*)p2;
  *(float4*)&part[3][wv][lane << 2] = *(float4*)p3;
  __syncthreads();

  if (wv < 4) {  // wave w -> d = d0 + w
    float l[4] = {0.f, 0.f, 0.f, 0.f};
#pragma unroll
    for (int w = 0; w < 8; ++w) {
      float4 q = *(const float4*)&part[wv][w][lane << 2];
      l[0] += q.x; l[1] += q.y; l[2] += q.z; l[3] += q.w;
    }
#pragma unroll
    for (int q = 0; q < 4; ++q) l[q] = svtot - 2.f * l[q];
    float m = wave_max(fmaxf(fmaxf(l[0], l[1]), fmaxf(l[2], l[3])));
    float p[4];
    float s = 0.f;
#pragma unroll
    for (int q = 0; q < 4; ++q) {
      p[q] = __builtin_amdgcn_exp2f((l[q] - m) * LOG2E);
      s += p[q];
    }
    s = wave_sum(s);
    const float inv = 1.0f / s;
    float4 ov = {p[0] * inv, p[1] * inv, p[2] * inv, p[3] * inv};
    const size_t ro = (size_t)(b * TD_ + d0 + wv) * TE_ + (lane << 2);
    *(float4*)(e_out + ro) = ov;
    ushort4 ob = {f2bf(ov.x), f2bf(ov.y), f2bf(ov.z), f2bf(ov.w)};
    *(ushort4*)(eB + ro) = ob;
  }
}

// ---------------------------------------------------------------------------
extern "C" void kernel_launch(void* const* d_in, const int* in_sizes, int n_in,
                              void* d_out, int out_size, void* d_ws, size_t ws_size,
                              hipStream_t stream) {
  const float* enc = (const float*)d_in[0];  // [B, TE, H]
  const float* dec = (const float*)d_in[1];  // [B, TD, H]
  const float* Wa  = (const float*)d_in[2];  // [H, H]
  const float* Ua  = (const float*)d_in[3];  // [H, H]
  const float* Va  = (const float*)d_in[4];  // [H]

  float* out_c = (float*)d_out;                       // [B, TD, H]
  float* out_e = out_c + (size_t)B_ * TD_ * H_;       // [B, TD, TE]

  char* w8 = (char*)d_ws;                             // 20 MB used
  ushort* E_T  = (ushort*)(w8);                       // [B][H][TE] bf16  4 MB
  float*  eU   = (float*)(w8 + (4u << 20));           // [B][TD][H] f32   4 MB
  ushort* encB = (ushort*)(w8 + (8u << 20));          // [B*TE][H]  bf16  4 MB
  ushort* decB = (ushort*)(w8 + (12u << 20));         // [B*TD][H]  bf16  2 MB
  ushort* WaT  = (ushort*)(w8 + (14u << 20));         // [H][H]     bf16 .5 MB
  ushort* UaT  = (ushort*)(w8 + (14u << 20) + (512u << 10));
  ushort* encT = (ushort*)(w8 + (15u << 20));         // [B][H][TE] bf16  4 MB
  ushort* eB   = (ushort*)(w8 + (19u << 20));         // [B][TD][TE]bf16  1 MB

  // Prep: all conversions/transposes in one launch
  prep_all<<<dim3(16, 14, 16), 256, 0, stream>>>(
      enc, dec, Wa, Ua, encB, decB, encT, WaT, UaT);

  // A1(flipped)+A2 fused: E_T (bf16, [b][h][t]) and eU (f32 row-major)
  gemm_phaseA<<<384, 256, 0, stream>>>(encB, WaT, E_T, decB, UaT, eU);

  // B: energies + softmax -> out_e (f32) + eB (bf16)
  energies_softmax<<<512, 512, 0, stream>>>(E_T, eU, Va, out_e, eB);

  // C: c[b] = e[b] @ enc[b] via bf16 MFMA (BT = encT)
  gemm_ctx<<<dim3(4, 2, 16), 256, 0, stream>>>(
      eB, TE_, (long)TD_ * TE_, encT, TE_, (long)H_ * TE_,
      out_c, H_, (long)TD_ * H_, TE_);
}

// Round 9
// 61.364 us; speedup vs baseline: 2.8435x; 1.0711x over previous
//
#include <hip/hip_runtime.h>

// Problem shapes (fixed by setup_inputs)
#define B_  16
#define TE_ 256
#define TD_ 128
#define H_  512

#define C_TANH 2.88539008177792681472f  // 2*log2(e):  tanh(x) = 1 - 2/(exp2(C*x)+1)
#define LOG2E  1.44269504088896340736f

typedef __attribute__((ext_vector_type(8))) short short8v;   // 8 x bf16 (4 VGPR)
typedef __attribute__((ext_vector_type(4))) float floatx4;   // MFMA acc

__device__ __forceinline__ float wave_sum(float v) {
#pragma unroll
  for (int m = 32; m; m >>= 1) v += __shfl_xor(v, m, 64);
  return v;
}
__device__ __forceinline__ float wave_max(float v) {
#pragma unroll
  for (int m = 32; m; m >>= 1) v = fmaxf(v, __shfl_xor(v, m, 64));
  return v;
}
__device__ __forceinline__ ushort f2bf(float f) {  // RNE fp32->bf16
  unsigned u = __builtin_bit_cast(unsigned, f);
  u += 0x7fffu + ((u >> 16) & 1u);
  return (ushort)(u >> 16);
}
__device__ __forceinline__ float bf2f(ushort u) {
  return __builtin_bit_cast(float, (unsigned)u << 16);
}
__device__ __forceinline__ unsigned pk2(float a, float b) {
  return (unsigned)f2bf(a) | ((unsigned)f2bf(b) << 16);
}

// ---------------------------------------------------------------------------
// Prep (grid (8, 14, 16), 256 thr), 32x64 tiles, fully vectorized:
//  y in [0,8):  enc b=z, rows t0=y*32, cols h0=x*64 -> encB (uint4 row cvt)
//               + encT (transpose cvt, uint4 stores)
//  y in [8,12): dec b=z, rows (y-8)*32 -> decB (uint4 row cvt)
//  y == 12/13:  Wa/Ua rows z*32, cols x*64 -> WaT/UaT (transpose, uint4)
// ---------------------------------------------------------------------------
__global__ __launch_bounds__(256) void prep_all(
    const float* __restrict__ enc, const float* __restrict__ dec,
    const float* __restrict__ Wa, const float* __restrict__ Ua,
    ushort* __restrict__ encB, ushort* __restrict__ decB,
    ushort* __restrict__ encT, ushort* __restrict__ WaT,
    ushort* __restrict__ UaT)
{
  __shared__ float tl[32 * 66];   // [32 rows][64 cols] pitch 66
  const int tid = threadIdx.x;
  const int x = blockIdx.x, y = blockIdx.y, z = blockIdx.z;
  const int r = tid >> 3, g = tid & 7;     // load: row 0..31, 8-float group
  const int hh = tid >> 2, tq = tid & 3;   // store: col 0..63, 8-elem quad

  if (y < 8) {
    const int t0 = y * 32, h0 = x * 64;
    const float* s = enc + ((size_t)z * TE_ + t0) * H_ + h0;
    float4 f0 = *(const float4*)(s + (size_t)r * H_ + g * 8);
    float4 f1 = *(const float4*)(s + (size_t)r * H_ + g * 8 + 4);
    uint4 pk = {pk2(f0.x, f0.y), pk2(f0.z, f0.w), pk2(f1.x, f1.y), pk2(f1.z, f1.w)};
    *(uint4*)(encB + ((size_t)z * TE_ + t0 + r) * H_ + h0 + g * 8) = pk;
    float* t = &tl[r * 66 + g * 8];
    t[0] = f0.x; t[1] = f0.y; t[2] = f0.z; t[3] = f0.w;
    t[4] = f1.x; t[5] = f1.y; t[6] = f1.z; t[7] = f1.w;
    __syncthreads();
    float v[8];
#pragma unroll
    for (int i = 0; i < 8; ++i) v[i] = tl[(tq * 8 + i) * 66 + hh];
    uint4 tp = {pk2(v[0], v[1]), pk2(v[2], v[3]), pk2(v[4], v[5]), pk2(v[6], v[7])};
    *(uint4*)(encT + ((size_t)z * H_ + h0 + hh) * TE_ + t0 + tq * 8) = tp;
  } else if (y < 12) {
    const int t0 = (y - 8) * 32, h0 = x * 64;
    const float* s = dec + ((size_t)z * TD_ + t0) * H_ + h0;
    float4 f0 = *(const float4*)(s + (size_t)r * H_ + g * 8);
    float4 f1 = *(const float4*)(s + (size_t)r * H_ + g * 8 + 4);
    uint4 pk = {pk2(f0.x, f0.y), pk2(f0.z, f0.w), pk2(f1.x, f1.y), pk2(f1.z, f1.w)};
    *(uint4*)(decB + ((size_t)z * TD_ + t0 + r) * H_ + h0 + g * 8) = pk;
  } else {
    const float* s = (y == 12) ? Wa : Ua;
    ushort* d = (y == 12) ? WaT : UaT;
    const int r0 = z * 32, c0 = x * 64;
    float4 f0 = *(const float4*)(s + (size_t)(r0 + r) * H_ + c0 + g * 8);
    float4 f1 = *(const float4*)(s + (size_t)(r0 + r) * H_ + c0 + g * 8 + 4);
    float* t = &tl[r * 66 + g * 8];
    t[0] = f0.x; t[1] = f0.y; t[2] = f0.z; t[3] = f0.w;
    t[4] = f1.x; t[5] = f1.y; t[6] = f1.z; t[7] = f1.w;
    __syncthreads();
    float v[8];
#pragma unroll
    for (int i = 0; i < 8; ++i) v[i] = tl[(tq * 8 + i) * 66 + hh];
    uint4 tp = {pk2(v[0], v[1]), pk2(v[2], v[3]), pk2(v[4], v[5]), pk2(v[6], v[7])};
    *(uint4*)(d + (size_t)(c0 + hh) * H_ + r0 + tq * 8) = tp;
  }
}

// ---------------------------------------------------------------------------
// Fused phase-A GEMM, 4 waves, 2-phase reg-staged pipeline. BM=64 BN=128
// BK=32; wave w owns m-rows [16w,16w+16), acc[8] over N.
//  blocks [0,256):  A1-FLIPPED: E_T[b][h][t] = bf16(exp2(C*(WaT.encB)))
//  blocks [256,384): A2: eU[m][h] = exp2(C*(decB.UaT)), row-major f32
// ---------------------------------------------------------------------------
__global__ __launch_bounds__(256) void gemm_phaseA(
    const ushort* __restrict__ encB, const ushort* __restrict__ WaT,
    ushort* __restrict__ E_T,
    const ushort* __restrict__ decB, const ushort* __restrict__ UaT,
    float* __restrict__ eU)
{
  __shared__ __attribute__((aligned(16))) ushort As[64 * 40];   // pitch 40
  __shared__ __attribute__((aligned(16))) ushort Bs[128 * 40];

  const int tid = threadIdx.x;
  const int l = tid & 63;
  const int w = tid >> 6;
  const int l15 = l & 15, l4 = l >> 4;
  const int id = blockIdx.x;
  const bool isA1 = id < 256;
  int bm, bn;
  const ushort *Ag, *Bg;
  if (isA1) {
    bm = (id >> 5) * 64;          // h-tile (M=512)
    bn = (id & 31) * 128;         // m-tile (N=4096)
    Ag = WaT + (long)bm * H_;
    Bg = encB + (long)bn * H_;
  } else {
    const int i2 = id - 256;
    bm = (i2 >> 2) * 64;          // m-tile (M=2048)
    bn = (i2 & 3) * 128;          // h-tile (N=512)
    Ag = decB + (long)bm * H_;
    Bg = UaT + (long)bn * H_;
  }

  const int rowA = tid >> 2, kcA = (tid & 3) << 3;
  short8v aR, bR0, bR1;
  aR  = *(const short8v*)(Ag + (long)rowA * H_ + kcA);
  bR0 = *(const short8v*)(Bg + (long)rowA * H_ + kcA);
  bR1 = *(const short8v*)(Bg + (long)(64 + rowA) * H_ + kcA);

  floatx4 acc[8] = {};

  for (int kt = 0; kt < H_; kt += 32) {
    if (kt) __syncthreads();               // prev iter's ds_reads done
    *(short8v*)&As[rowA * 40 + kcA] = aR;
    *(short8v*)&Bs[rowA * 40 + kcA] = bR0;
    *(short8v*)&Bs[(64 + rowA) * 40 + kcA] = bR1;
    __syncthreads();
    if (kt + 32 < H_) {                    // prefetch flies under the MFMAs
      aR  = *(const short8v*)(Ag + (long)rowA * H_ + kt + 32 + kcA);
      bR0 = *(const short8v*)(Bg + (long)rowA * H_ + kt + 32 + kcA);
      bR1 = *(const short8v*)(Bg + (long)(64 + rowA) * H_ + kt + 32 + kcA);
    }
    short8v a0 = *(short8v*)&As[(w * 16 + l15) * 40 + l4 * 8];
#pragma unroll
    for (int nt = 0; nt < 8; ++nt) {
      short8v bf = *(short8v*)&Bs[(nt * 16 + l15) * 40 + l4 * 8];
      acc[nt] = __builtin_amdgcn_mfma_f32_16x16x32_bf16(a0, bf, acc[nt], 0, 0, 0);
    }
  }

  const int growb = bm + w * 16 + (l4 << 2);
  if (isA1) {
    const int bb = bn >> 8;
#pragma unroll
    for (int nt = 0; nt < 8; ++nt) {
      const int t = (bn & 255) + nt * 16 + l15;
#pragma unroll
      for (int r = 0; r < 4; ++r) {
        const int h = growb + r;
        E_T[((size_t)bb * H_ + h) * TE_ + t] =
            f2bf(__builtin_amdgcn_exp2f(C_TANH * acc[nt][r]));
      }
    }
  } else {
#pragma unroll
    for (int nt = 0; nt < 8; ++nt) {
      const int gcol = bn + nt * 16 + l15;
#pragma unroll
      for (int r = 0; r < 4; ++r)
        eU[(size_t)(growb + r) * H_ + gcol] =
            __builtin_amdgcn_exp2f(C_TANH * acc[nt][r]);
    }
  }
}

// ---------------------------------------------------------------------------
// Phase-C bf16 MFMA GEMM (BT transposed), BM=64 BN=64 BK=32, 4 waves,
// 2-phase reg-staged pipeline. Grid (8, 2, 16) = 256 blocks.
// ---------------------------------------------------------------------------
__global__ __launch_bounds__(256) void gemm_ctx(
    const ushort* __restrict__ A, int lda, long sA,
    const ushort* __restrict__ BT, int ldb, long sB,
    float* __restrict__ C, int ldc, long sC, int K)
{
  __shared__ __attribute__((aligned(16))) ushort As[64 * 40];
  __shared__ __attribute__((aligned(16))) ushort Bs[64 * 40];

  const int tid = threadIdx.x;
  const int l = tid & 63;
  const int w = tid >> 6;
  const int l15 = l & 15, l4 = l >> 4;
  const long z = blockIdx.z;
  const int bn = blockIdx.x * 64, bm = blockIdx.y * 64;

  const ushort* Ag = A + z * sA + (long)bm * lda;
  const ushort* Bg = BT + z * sB + (long)bn * ldb;

  const int rowA = tid >> 2, kcA = (tid & 3) << 3;
  short8v aR = *(const short8v*)(Ag + (long)rowA * lda + kcA);
  short8v bR = *(const short8v*)(Bg + (long)rowA * ldb + kcA);

  floatx4 acc[4] = {};

  for (int kt = 0; kt < K; kt += 32) {
    if (kt) __syncthreads();
    *(short8v*)&As[rowA * 40 + kcA] = aR;
    *(short8v*)&Bs[rowA * 40 + kcA] = bR;
    __syncthreads();
    if (kt + 32 < K) {
      aR = *(const short8v*)(Ag + (long)rowA * lda + kt + 32 + kcA);
      bR = *(const short8v*)(Bg + (long)rowA * ldb + kt + 32 + kcA);
    }
    short8v a0 = *(short8v*)&As[(w * 16 + l15) * 40 + l4 * 8];
#pragma unroll
    for (int nt = 0; nt < 4; ++nt) {
      short8v bf = *(short8v*)&Bs[(nt * 16 + l15) * 40 + l4 * 8];
      acc[nt] = __builtin_amdgcn_mfma_f32_16x16x32_bf16(a0, bf, acc[nt], 0, 0, 0);
    }
  }

  const int growb = bm + w * 16 + (l4 << 2);
#pragma unroll
  for (int nt = 0; nt < 4; ++nt) {
    const int gcol = bn + nt * 16 + l15;
#pragma unroll
    for (int r = 0; r < 4; ++r)
      C[z * sC + (long)(growb + r) * ldc + gcol] = acc[nt][r];
  }
}

// ---------------------------------------------------------------------------
// Energies + softmax. E_T[b][h][t]=bf16(exp2(C*Ws)), eU[b][d][h]=exp2(C*Uh);
// tanh = 1 - 2*rcp(E*eU+1). 1024 blocks (XCD-swizzled: 2 b per XCD), 512 thr
// = 8 waves; block = (b, 2 d rows); wave w owns h in [64w,64w+64) for BOTH
// d rows (8 indep rcp chains/lane); lane owns t-quad. 100% occupancy target.
// ---------------------------------------------------------------------------
__global__ __launch_bounds__(512) void energies_softmax(
    const ushort* __restrict__ E_T, const float* __restrict__ eU,
    const float* __restrict__ Va, float* __restrict__ e_out,
    ushort* __restrict__ eB)
{
  __shared__ float part[2][8][TE_];

  const int tid  = threadIdx.x;
  const int lane = tid & 63;
  const int wv   = __builtin_amdgcn_readfirstlane(tid >> 6);  // h-eighth
  const int id   = blockIdx.x;            // 0..1023
  const int xcd  = id & 7, j = id >> 3;   // XCD x -> b in {2x, 2x+1}
  const int b    = (xcd << 1) | (j >> 6);
  const int d0   = (j & 63) << 1;

  float4 v0 = *(const float4*)(Va + (lane << 2));
  float4 v1 = *(const float4*)(Va + 256 + (lane << 2));
  const float svtot =
      wave_sum(v0.x + v0.y + v0.z + v0.w + v1.x + v1.y + v1.z + v1.w);

  const float* u0 = eU + (size_t)(b * TD_ + d0 + 0) * H_ + wv * 64;
  const float* u1 = eU + (size_t)(b * TD_ + d0 + 1) * H_ + wv * 64;
  const float* vp = Va + wv * 64;
  const ushort* ep = E_T + ((size_t)(b * H_) + wv * 64) * TE_ + (lane << 2);

  float p0[4] = {}, p1[4] = {};

#pragma unroll 4
  for (int h = 0; h < 64; ++h) {
    const float sV = vp[h];
    const float sU0 = u0[h], sU1 = u1[h];
    ushort4 ew = *(const ushort4*)(ep + (size_t)h * TE_);
    float e0 = bf2f(ew.x), e1 = bf2f(ew.y), e2 = bf2f(ew.z), e3 = bf2f(ew.w);
    p0[0] = fmaf(sV, __builtin_amdgcn_rcpf(fmaf(e0, sU0, 1.f)), p0[0]);
    p0[1] = fmaf(sV, __builtin_amdgcn_rcpf(fmaf(e1, sU0, 1.f)), p0[1]);
    p0[2] = fmaf(sV, __builtin_amdgcn_rcpf(fmaf(e2, sU0, 1.f)), p0[2]);
    p0[3] = fmaf(sV, __builtin_amdgcn_rcpf(fmaf(e3, sU0, 1.f)), p0[3]);
    p1[0] = fmaf(sV, __builtin_amdgcn_rcpf(fmaf(e0, sU1, 1.f)), p1[0]);
    p1[1] = fmaf(sV, __builtin_amdgcn_rcpf(fmaf(e1, sU1, 1.f)), p1[1]);
    p1[2] = fmaf(sV, __builtin_amdgcn_rcpf(fmaf(e2, sU1, 1.f)), p1[2]);
    p1[3] = fmaf(sV, __builtin_amdgcn_rcpf(fmaf(e3, sU1, 1.f)), p1[3]);
  }

  *(float4*)&part[0][wv][lane << 2] = *(float4*)p0;
  *(float4*)&part[1][wv][lane << 2] = *(float4*)p1;
  __syncthreads();

  if (wv < 2) {  // wave w -> d = d0 + w
    float l4v[4] = {0.f, 0.f, 0.f, 0.f};
#pragma unroll
    for (int w = 0; w < 8; ++w) {
      float4 q = *(const float4*)&part[wv][w][lane << 2];
      l4v[0] += q.x; l4v[1] += q.y; l4v[2] += q.z; l4v[3] += q.w;
    }
#pragma unroll
    for (int q = 0; q < 4; ++q) l4v[q] = svtot - 2.f * l4v[q];
    float m = wave_max(fmaxf(fmaxf(l4v[0], l4v[1]), fmaxf(l4v[2], l4v[3])));
    float p[4];
    float s = 0.f;
#pragma unroll
    for (int q = 0; q < 4; ++q) {
      p[q] = __builtin_amdgcn_exp2f((l4v[q] - m) * LOG2E);
      s += p[q];
    }
    s = wave_sum(s);
    const float inv = 1.0f / s;
    float4 ov = {p[0] * inv, p[1] * inv, p[2] * inv, p[3] * inv};
    const size_t ro = (size_t)(b * TD_ + d0 + wv) * TE_ + (lane << 2);
    *(float4*)(e_out + ro) = ov;
    ushort4 ob = {f2bf(ov.x), f2bf(ov.y), f2bf(ov.z), f2bf(ov.w)};
    *(ushort4*)(eB + ro) = ob;
  }
}

// ---------------------------------------------------------------------------
extern "C" void kernel_launch(void* const* d_in, const int* in_sizes, int n_in,
                              void* d_out, int out_size, void* d_ws, size_t ws_size,
                              hipStream_t stream) {
  const float* enc = (const float*)d_in[0];  // [B, TE, H]
  const float* dec = (const float*)d_in[1];  // [B, TD, H]
  const float* Wa  = (const float*)d_in[2];  // [H, H]
  const float* Ua  = (const float*)d_in[3];  // [H, H]
  const float* Va  = (const float*)d_in[4];  // [H]

  float* out_c = (float*)d_out;                       // [B, TD, H]
  float* out_e = out_c + (size_t)B_ * TD_ * H_;       // [B, TD, TE]

  char* w8 = (char*)d_ws;                             // 20 MB used
  ushort* E_T  = (ushort*)(w8);                       // [B][H][TE] bf16  4 MB
  float*  eU   = (float*)(w8 + (4u << 20));           // [B][TD][H] f32   4 MB
  ushort* encB = (ushort*)(w8 + (8u << 20));          // [B*TE][H]  bf16  4 MB
  ushort* decB = (ushort*)(w8 + (12u << 20));         // [B*TD][H]  bf16  2 MB
  ushort* WaT  = (ushort*)(w8 + (14u << 20));         // [H][H]     bf16 .5 MB
  ushort* UaT  = (ushort*)(w8 + (14u << 20) + (512u << 10));
  ushort* encT = (ushort*)(w8 + (15u << 20));         // [B][H][TE] bf16  4 MB
  ushort* eB   = (ushort*)(w8 + (19u << 20));         // [B][TD][TE]bf16  1 MB

  // Prep: all conversions/transposes, vectorized
  prep_all<<<dim3(8, 14, 16), 256, 0, stream>>>(
      enc, dec, Wa, Ua, encB, decB, encT, WaT, UaT);

  // A1(flipped)+A2 fused: E_T (bf16, [b][h][t]) and eU (f32 row-major)
  gemm_phaseA<<<384, 256, 0, stream>>>(encB, WaT, E_T, decB, UaT, eU);

  // B: energies + softmax -> out_e (f32) + eB (bf16)
  energies_softmax<<<1024, 512, 0, stream>>>(E_T, eU, Va, out_e, eB);

  // C: c[b] = e[b] @ enc[b] via bf16 MFMA (BT = encT)
  gemm_ctx<<<dim3(8, 2, 16), 256, 0, stream>>>(
      eB, TE_, (long)TD_ * TE_, encT, TE_, (long)H_ * TE_,
      out_c, H_, (long)TD_ * H_, TE_);
}

// Round 10
// 60.483 us; speedup vs baseline: 2.8849x; 1.0146x over previous
//
#include <hip/hip_runtime.h>

// Problem shapes (fixed by setup_inputs)
#define B_  16
#define TE_ 256
#define TD_ 128
#define H_  512

#define C_TANH 2.88539008177792681472f  // 2*log2(e):  tanh(x) = 1 - 2/(exp2(C*x)+1)
#define LOG2E  1.44269504088896340736f

typedef __attribute__((ext_vector_type(8))) short short8v;   // 8 x bf16 (4 VGPR)
typedef __attribute__((ext_vector_type(4))) float floatx4;   // MFMA acc

__device__ __forceinline__ float wave_sum(float v) {
#pragma unroll
  for (int m = 32; m; m >>= 1) v += __shfl_xor(v, m, 64);
  return v;
}
__device__ __forceinline__ float wave_max(float v) {
#pragma unroll
  for (int m = 32; m; m >>= 1) v = fmaxf(v, __shfl_xor(v, m, 64));
  return v;
}
__device__ __forceinline__ ushort f2bf(float f) {  // RNE fp32->bf16
  unsigned u = __builtin_bit_cast(unsigned, f);
  u += 0x7fffu + ((u >> 16) & 1u);
  return (ushort)(u >> 16);
}
__device__ __forceinline__ float bf2f(ushort u) {
  return __builtin_bit_cast(float, (unsigned)u << 16);
}
__device__ __forceinline__ unsigned pk2(float a, float b) {
  return (unsigned)f2bf(a) | ((unsigned)f2bf(b) << 16);
}

// ---------------------------------------------------------------------------
// Prep (grid (8, 10, 16), 256 thr): transposes only (enc/dec row converts
// now happen on the fly inside phaseA staging).
//  y in [0,8): enc b=z, t-tile y, h-tile x -> encT[b][h][t] (bf16)
//  y == 8/9:   Wa/Ua k-rows z*32, h-cols x*64 -> WaT/UaT [h][k] (bf16)
// ---------------------------------------------------------------------------
__global__ __launch_bounds__(256) void prep_T(
    const float* __restrict__ enc, const float* __restrict__ Wa,
    const float* __restrict__ Ua, ushort* __restrict__ encT,
    ushort* __restrict__ WaT, ushort* __restrict__ UaT)
{
  __shared__ float tl[32 * 66];   // [32 rows][64 cols] pitch 66
  const int tid = threadIdx.x;
  const int x = blockIdx.x, y = blockIdx.y, z = blockIdx.z;
  const int r = tid >> 3, g = tid & 7;     // load: row 0..31, 8-float group
  const int hh = tid >> 2, tq = tid & 3;   // store: col 0..63, 8-elem quad

  const float* s;
  ushort* d;
  long dstr;   // dest row stride
  int r0, c0;
  if (y < 8) {
    s = enc + (size_t)z * TE_ * H_;
    d = encT + (size_t)z * H_ * TE_;
    dstr = TE_;
    r0 = y * 32; c0 = x * 64;
  } else {
    s = (y == 8) ? Wa : Ua;
    d = (y == 8) ? WaT : UaT;
    dstr = H_;
    r0 = z * 32; c0 = x * 64;
  }

  float4 f0 = *(const float4*)(s + (size_t)(r0 + r) * H_ + c0 + g * 8);
  float4 f1 = *(const float4*)(s + (size_t)(r0 + r) * H_ + c0 + g * 8 + 4);
  float* t = &tl[r * 66 + g * 8];
  t[0] = f0.x; t[1] = f0.y; t[2] = f0.z; t[3] = f0.w;
  t[4] = f1.x; t[5] = f1.y; t[6] = f1.z; t[7] = f1.w;
  __syncthreads();
  float v[8];
#pragma unroll
  for (int i = 0; i < 8; ++i) v[i] = tl[(tq * 8 + i) * 66 + hh];
  uint4 tp = {pk2(v[0], v[1]), pk2(v[2], v[3]), pk2(v[4], v[5]), pk2(v[6], v[7])};
  *(uint4*)(d + (size_t)(c0 + hh) * dstr + r0 + tq * 8) = tp;
}

// ---------------------------------------------------------------------------
// Shared GEMM body: BM=64 BN=64 BK=32, 4 waves, 2-phase reg pipeline.
// CVTA/CVTB: that operand is f32 source, converted to bf16 during staging.
// EPI 0: E_T[b][h][t] = bf16(exp2(C*v)) (A1-flipped);  EPI 1: eU f32 row-major.
// ---------------------------------------------------------------------------
template <bool CVTA, bool CVTB, int EPI>
__device__ __forceinline__ void gemm64_body(
    const void* Asrc, const void* Bsrc, void* dst, int bm, int bn,
    ushort* As, ushort* Bs)
{
  const int tid = threadIdx.x;
  const int l = tid & 63, w = tid >> 6;
  const int l15 = l & 15, l4 = l >> 4;
  const int rowS = tid >> 2, kc = (tid & 3) << 3;

  const float*  Af = (const float*)Asrc;
  const ushort* Ab = (const ushort*)Asrc;
  const float*  Bf = (const float*)Bsrc;
  const ushort* Bb = (const ushort*)Bsrc;
  const long arow = (long)(bm * 64 + rowS) * H_ + kc;
  const long brow = (long)(bn * 64 + rowS) * H_ + kc;

  short8v aR, bR;
  float4 fa0, fa1, fb0, fb1;
  if (CVTA) { fa0 = *(const float4*)(Af + arow); fa1 = *(const float4*)(Af + arow + 4); }
  else      { aR = *(const short8v*)(Ab + arow); }
  if (CVTB) { fb0 = *(const float4*)(Bf + brow); fb1 = *(const float4*)(Bf + brow + 4); }
  else      { bR = *(const short8v*)(Bb + brow); }

  floatx4 acc[4] = {};

  for (int kt = 0; kt < H_; kt += 32) {
    if (kt) __syncthreads();
    if (CVTA) {
      uint4 p = {pk2(fa0.x, fa0.y), pk2(fa0.z, fa0.w), pk2(fa1.x, fa1.y), pk2(fa1.z, fa1.w)};
      *(uint4*)&As[rowS * 40 + kc] = p;
    } else {
      *(short8v*)&As[rowS * 40 + kc] = aR;
    }
    if (CVTB) {
      uint4 p = {pk2(fb0.x, fb0.y), pk2(fb0.z, fb0.w), pk2(fb1.x, fb1.y), pk2(fb1.z, fb1.w)};
      *(uint4*)&Bs[rowS * 40 + kc] = p;
    } else {
      *(short8v*)&Bs[rowS * 40 + kc] = bR;
    }
    __syncthreads();
    if (kt + 32 < H_) {  // prefetch next K-tile under the MFMAs
      if (CVTA) { fa0 = *(const float4*)(Af + arow + kt + 32);
                  fa1 = *(const float4*)(Af + arow + kt + 36); }
      else      { aR = *(const short8v*)(Ab + arow + kt + 32); }
      if (CVTB) { fb0 = *(const float4*)(Bf + brow + kt + 32);
                  fb1 = *(const float4*)(Bf + brow + kt + 36); }
      else      { bR = *(const short8v*)(Bb + brow + kt + 32); }
    }
    short8v a0 = *(short8v*)&As[(w * 16 + l15) * 40 + l4 * 8];
#pragma unroll
    for (int nt = 0; nt < 4; ++nt) {
      short8v bf = *(short8v*)&Bs[(nt * 16 + l15) * 40 + l4 * 8];
      acc[nt] = __builtin_amdgcn_mfma_f32_16x16x32_bf16(a0, bf, acc[nt], 0, 0, 0);
    }
  }

  if (EPI == 0) {
    // D[h][m]: h = bm*64 + w*16 + l4*4 + r;  m = bn*64 + nt*16 + l15
    // b = m>>8 (uniform: 64 | 256), t = m&255
    ushort* E = (ushort*)dst;
    const int bb = bn >> 2, t0 = (bn & 3) * 64;
    const int hb = bm * 64 + w * 16 + (l4 << 2);
#pragma unroll
    for (int nt = 0; nt < 4; ++nt) {
      const int t = t0 + nt * 16 + l15;
#pragma unroll
      for (int r = 0; r < 4; ++r)
        E[((size_t)bb * H_ + hb + r) * TE_ + t] =
            f2bf(__builtin_amdgcn_exp2f(C_TANH * acc[nt][r]));
    }
  } else {
    float* U = (float*)dst;
    const int growb = bm * 64 + w * 16 + (l4 << 2);
#pragma unroll
    for (int nt = 0; nt < 4; ++nt) {
      const int gcol = bn * 64 + nt * 16 + l15;
#pragma unroll
      for (int r = 0; r < 4; ++r)
        U[(size_t)(growb + r) * H_ + gcol] =
            __builtin_amdgcn_exp2f(C_TANH * acc[nt][r]);
    }
  }
}

// ---------------------------------------------------------------------------
// Fused phase-A, 768 blocks, XCD-swizzled so producer XCD == consumer XCD:
//  ids [0,512):  A1-flipped E_T = exp2(C*(WaT . enc^bf16)): XCD x covers
//                m-tiles bn in [8x,8x+8) (b = {2x,2x+1}) for all 8 h-tiles.
//  ids [512,768): A2 eU = exp2(C*(dec^bf16 . UaT)): XCD x covers m-tiles
//                bm in [4x,4x+4) (same b = {2x,2x+1}) for all 8 h-tiles.
// ---------------------------------------------------------------------------
__global__ __launch_bounds__(256) void gemm_phaseA(
    const float* __restrict__ enc, const ushort* __restrict__ WaT,
    ushort* __restrict__ E_T,
    const float* __restrict__ dec, const ushort* __restrict__ UaT,
    float* __restrict__ eU)
{
  __shared__ __attribute__((aligned(16))) ushort As[64 * 40];
  __shared__ __attribute__((aligned(16))) ushort Bs[64 * 40];

  const int id = blockIdx.x;
  if (id < 512) {
    const int x = id & 7, k = id >> 3;          // physical XCD = id & 7
    const int bm = k & 7;                        // h-tile 0..7
    const int bn = x * 8 + (k >> 3);             // m-tile 0..63
    gemm64_body<false, true, 0>(WaT, enc, E_T, bm, bn, As, Bs);
  } else {
    const int i2 = id - 512;
    const int x = i2 & 7, k = i2 >> 3;           // k 0..31
    const int bm = x * 4 + (k & 3);              // m-tile 0..31
    const int bn = k >> 2;                       // h-tile 0..7
    gemm64_body<true, false, 1>(dec, UaT, eU, bm, bn, As, Bs);
  }
}

// ---------------------------------------------------------------------------
// Phase-C bf16 MFMA GEMM (BT = encT), BM=64 BN=64 BK=32, 4 waves, 2-phase
// reg pipeline. Grid (8, 2, 16) = 256 blocks.
// ---------------------------------------------------------------------------
__global__ __launch_bounds__(256) void gemm_ctx(
    const ushort* __restrict__ A, int lda, long sA,
    const ushort* __restrict__ BT, int ldb, long sB,
    float* __restrict__ C, int ldc, long sC, int K)
{
  __shared__ __attribute__((aligned(16))) ushort As[64 * 40];
  __shared__ __attribute__((aligned(16))) ushort Bs[64 * 40];

  const int tid = threadIdx.x;
  const int l = tid & 63;
  const int w = tid >> 6;
  const int l15 = l & 15, l4 = l >> 4;
  const long z = blockIdx.z;
  const int bn = blockIdx.x * 64, bm = blockIdx.y * 64;

  const ushort* Ag = A + z * sA + (long)bm * lda;
  const ushort* Bg = BT + z * sB + (long)bn * ldb;

  const int rowA = tid >> 2, kcA = (tid & 3) << 3;
  short8v aR = *(const short8v*)(Ag + (long)rowA * lda + kcA);
  short8v bR = *(const short8v*)(Bg + (long)rowA * ldb + kcA);

  floatx4 acc[4] = {};

  for (int kt = 0; kt < K; kt += 32) {
    if (kt) __syncthreads();
    *(short8v*)&As[rowA * 40 + kcA] = aR;
    *(short8v*)&Bs[rowA * 40 + kcA] = bR;
    __syncthreads();
    if (kt + 32 < K) {
      aR = *(const short8v*)(Ag + (long)rowA * lda + kt + 32 + kcA);
      bR = *(const short8v*)(Bg + (long)rowA * ldb + kt + 32 + kcA);
    }
    short8v a0 = *(short8v*)&As[(w * 16 + l15) * 40 + l4 * 8];
#pragma unroll
    for (int nt = 0; nt < 4; ++nt) {
      short8v bf = *(short8v*)&Bs[(nt * 16 + l15) * 40 + l4 * 8];
      acc[nt] = __builtin_amdgcn_mfma_f32_16x16x32_bf16(a0, bf, acc[nt], 0, 0, 0);
    }
  }

  const int growb = bm + w * 16 + (l4 << 2);
#pragma unroll
  for (int nt = 0; nt < 4; ++nt) {
    const int gcol = bn + nt * 16 + l15;
#pragma unroll
    for (int r = 0; r < 4; ++r)
      C[z * sC + (long)(growb + r) * ldc + gcol] = acc[nt][r];
  }
}

// ---------------------------------------------------------------------------
// Energies + softmax (structure unchanged from round 9).
// E_T[b][h][t]=bf16(exp2(C*Ws)), eU[b][d][h]=exp2(C*Uh);
// tanh = 1 - 2*rcp(E*eU+1). 1024 blocks (XCD x -> b in {2x,2x+1}), 8 waves;
// block = (b, 2 d rows); wave w owns h in [64w,64w+64) for both d rows.
// ---------------------------------------------------------------------------
__global__ __launch_bounds__(512) void energies_softmax(
    const ushort* __restrict__ E_T, const float* __restrict__ eU,
    const float* __restrict__ Va, float* __restrict__ e_out,
    ushort* __restrict__ eB)
{
  __shared__ float part[2][8][TE_];

  const int tid  = threadIdx.x;
  const int lane = tid & 63;
  const int wv   = __builtin_amdgcn_readfirstlane(tid >> 6);  // h-eighth
  const int id   = blockIdx.x;            // 0..1023
  const int xcd  = id & 7, j = id >> 3;   // XCD x -> b in {2x, 2x+1}
  const int b    = (xcd << 1) | (j >> 6);
  const int d0   = (j & 63) << 1;

  float4 v0 = *(const float4*)(Va + (lane << 2));
  float4 v1 = *(const float4*)(Va + 256 + (lane << 2));
  const float svtot =
      wave_sum(v0.x + v0.y + v0.z + v0.w + v1.x + v1.y + v1.z + v1.w);

  const float* u0 = eU + (size_t)(b * TD_ + d0 + 0) * H_ + wv * 64;
  const float* u1 = eU + (size_t)(b * TD_ + d0 + 1) * H_ + wv * 64;
  const float* vp = Va + wv * 64;
  const ushort* ep = E_T + ((size_t)(b * H_) + wv * 64) * TE_ + (lane << 2);

  float p0[4] = {}, p1[4] = {};

#pragma unroll 4
  for (int h = 0; h < 64; ++h) {
    const float sV = vp[h];
    const float sU0 = u0[h], sU1 = u1[h];
    ushort4 ew = *(const ushort4*)(ep + (size_t)h * TE_);
    float e0 = bf2f(ew.x), e1 = bf2f(ew.y), e2 = bf2f(ew.z), e3 = bf2f(ew.w);
    p0[0] = fmaf(sV, __builtin_amdgcn_rcpf(fmaf(e0, sU0, 1.f)), p0[0]);
    p0[1] = fmaf(sV, __builtin_amdgcn_rcpf(fmaf(e1, sU0, 1.f)), p0[1]);
    p0[2] = fmaf(sV, __builtin_amdgcn_rcpf(fmaf(e2, sU0, 1.f)), p0[2]);
    p0[3] = fmaf(sV, __builtin_amdgcn_rcpf(fmaf(e3, sU0, 1.f)), p0[3]);
    p1[0] = fmaf(sV, __builtin_amdgcn_rcpf(fmaf(e0, sU1, 1.f)), p1[0]);
    p1[1] = fmaf(sV, __builtin_amdgcn_rcpf(fmaf(e1, sU1, 1.f)), p1[1]);
    p1[2] = fmaf(sV, __builtin_amdgcn_rcpf(fmaf(e2, sU1, 1.f)), p1[2]);
    p1[3] = fmaf(sV, __builtin_amdgcn_rcpf(fmaf(e3, sU1, 1.f)), p1[3]);
  }

  *(float4*)&part[0][wv][lane << 2] = *(float4*)p0;
  *(float4*)&part[1][wv][lane << 2] = *(float4*)p1;
  __syncthreads();

  if (wv < 2) {  // wave w -> d = d0 + w
    float l4v[4] = {0.f, 0.f, 0.f, 0.f};
#pragma unroll
    for (int w = 0; w < 8; ++w) {
      float4 q = *(const float4*)&part[wv][w][lane << 2];
      l4v[0] += q.x; l4v[1] += q.y; l4v[2] += q.z; l4v[3] += q.w;
    }
#pragma unroll
    for (int q = 0; q < 4; ++q) l4v[q] = svtot - 2.f * l4v[q];
    float m = wave_max(fmaxf(fmaxf(l4v[0], l4v[1]), fmaxf(l4v[2], l4v[3])));
    float p[4];
    float s = 0.f;
#pragma unroll
    for (int q = 0; q < 4; ++q) {
      p[q] = __builtin_amdgcn_exp2f((l4v[q] - m) * LOG2E);
      s += p[q];
    }
    s = wave_sum(s);
    const float inv = 1.0f / s;
    float4 ov = {p[0] * inv, p[1] * inv, p[2] * inv, p[3] * inv};
    const size_t ro = (size_t)(b * TD_ + d0 + wv) * TE_ + (lane << 2);
    *(float4*)(e_out + ro) = ov;
    ushort4 ob = {f2bf(ov.x), f2bf(ov.y), f2bf(ov.z), f2bf(ov.w)};
    *(ushort4*)(eB + ro) = ob;
  }
}

// ---------------------------------------------------------------------------
extern "C" void kernel_launch(void* const* d_in, const int* in_sizes, int n_in,
                              void* d_out, int out_size, void* d_ws, size_t ws_size,
                              hipStream_t stream) {
  const float* enc = (const float*)d_in[0];  // [B, TE, H]
  const float* dec = (const float*)d_in[1];  // [B, TD, H]
  const float* Wa  = (const float*)d_in[2];  // [H, H]
  const float* Ua  = (const float*)d_in[3];  // [H, H]
  const float* Va  = (const float*)d_in[4];  // [H]

  float* out_c = (float*)d_out;                       // [B, TD, H]
  float* out_e = out_c + (size_t)B_ * TD_ * H_;       // [B, TD, TE]

  char* w8 = (char*)d_ws;                             // 14 MB used
  ushort* E_T  = (ushort*)(w8);                       // [B][H][TE] bf16  4 MB
  float*  eU   = (float*)(w8 + (4u << 20));           // [B][TD][H] f32   4 MB
  ushort* WaT  = (ushort*)(w8 + (8u << 20));          // [H][H]     bf16 .5 MB
  ushort* UaT  = (ushort*)(w8 + (8u << 20) + (512u << 10));
  ushort* encT = (ushort*)(w8 + (9u << 20));          // [B][H][TE] bf16  4 MB
  ushort* eB   = (ushort*)(w8 + (13u << 20));         // [B][TD][TE]bf16  1 MB

  // Prep: transposes only (encT, WaT, UaT)
  prep_T<<<dim3(8, 10, 16), 256, 0, stream>>>(enc, Wa, Ua, encT, WaT, UaT);

  // A1(flipped)+A2 fused, XCD-aligned with energies consumer mapping
  gemm_phaseA<<<768, 256, 0, stream>>>(enc, WaT, E_T, dec, UaT, eU);

  // B: energies + softmax -> out_e (f32) + eB (bf16)
  energies_softmax<<<1024, 512, 0, stream>>>(E_T, eU, Va, out_e, eB);

  // C: c[b] = e[b] @ enc[b] via bf16 MFMA (BT = encT)
  gemm_ctx<<<dim3(8, 2, 16), 256, 0, stream>>>(
      eB, TE_, (long)TD_ * TE_, encT, TE_, (long)H_ * TE_,
      out_c, H_, (long)TD_ * H_, TE_);
}

// Round 11
// 58.653 us; speedup vs baseline: 2.9750x; 1.0312x over previous
//
#include <hip/hip_runtime.h>

// Problem shapes (fixed by setup_inputs)
#define B_  16
#define TE_ 256
#define TD_ 128
#define H_  512

#define C_TANH 2.88539008177792681472f  // 2*log2(e):  tanh(x) = 1 - 2/(exp2(C*x)+1)
#define LOG2E  1.44269504088896340736f

typedef __attribute__((ext_vector_type(8))) short short8v;   // 8 x bf16 (4 VGPR)
typedef __attribute__((ext_vector_type(4))) float floatx4;   // MFMA acc

__device__ __forceinline__ float wave_sum(float v) {
#pragma unroll
  for (int m = 32; m; m >>= 1) v += __shfl_xor(v, m, 64);
  return v;
}
__device__ __forceinline__ float wave_max(float v) {
#pragma unroll
  for (int m = 32; m; m >>= 1) v = fmaxf(v, __shfl_xor(v, m, 64));
  return v;
}
__device__ __forceinline__ ushort f2bf(float f) {  // RNE fp32->bf16
  unsigned u = __builtin_bit_cast(unsigned, f);
  u += 0x7fffu + ((u >> 16) & 1u);
  return (ushort)(u >> 16);
}
__device__ __forceinline__ float bf2f(ushort u) {
  return __builtin_bit_cast(float, (unsigned)u << 16);
}
__device__ __forceinline__ unsigned pk2(float a, float b) {
  return (unsigned)f2bf(a) | ((unsigned)f2bf(b) << 16);
}

// ---------------------------------------------------------------------------
// Prep (grid (8, 10, 16), 256 thr): transposes only.
//  y in [0,8): enc b=z, t-tile y, h-tile x -> encT[b][h][t] (bf16)
//  y == 8/9:   Wa/Ua k-rows z*32, h-cols x*64 -> WaT/UaT [h][k] (bf16)
// ---------------------------------------------------------------------------
__global__ __launch_bounds__(256) void prep_T(
    const float* __restrict__ enc, const float* __restrict__ Wa,
    const float* __restrict__ Ua, ushort* __restrict__ encT,
    ushort* __restrict__ WaT, ushort* __restrict__ UaT)
{
  __shared__ float tl[32 * 66];   // [32 rows][64 cols] pitch 66
  const int tid = threadIdx.x;
  const int x = blockIdx.x, y = blockIdx.y, z = blockIdx.z;
  const int r = tid >> 3, g = tid & 7;     // load: row 0..31, 8-float group
  const int hh = tid >> 2, tq = tid & 3;   // store: col 0..63, 8-elem quad

  const float* s;
  ushort* d;
  long dstr;
  int r0, c0;
  if (y < 8) {
    s = enc + (size_t)z * TE_ * H_;
    d = encT + (size_t)z * H_ * TE_;
    dstr = TE_;
    r0 = y * 32; c0 = x * 64;
  } else {
    s = (y == 8) ? Wa : Ua;
    d = (y == 8) ? WaT : UaT;
    dstr = H_;
    r0 = z * 32; c0 = x * 64;
  }

  float4 f0 = *(const float4*)(s + (size_t)(r0 + r) * H_ + c0 + g * 8);
  float4 f1 = *(const float4*)(s + (size_t)(r0 + r) * H_ + c0 + g * 8 + 4);
  float* t = &tl[r * 66 + g * 8];
  t[0] = f0.x; t[1] = f0.y; t[2] = f0.z; t[3] = f0.w;
  t[4] = f1.x; t[5] = f1.y; t[6] = f1.z; t[7] = f1.w;
  __syncthreads();
  float v[8];
#pragma unroll
  for (int i = 0; i < 8; ++i) v[i] = tl[(tq * 8 + i) * 66 + hh];
  uint4 tp = {pk2(v[0], v[1]), pk2(v[2], v[3]), pk2(v[4], v[5]), pk2(v[6], v[7])};
  *(uint4*)(d + (size_t)(c0 + hh) * dstr + r0 + tq * 8) = tp;
}

// ---------------------------------------------------------------------------
// GEMM core: BM=64 BN=64 BK=64, 4 waves (256 thr), 2-phase reg pipeline.
// LDS layout per operand: [2 k-slices][64 rows][pitch 40] (proven pattern).
// 8 MFMAs per wave between each barrier pair (2 k-slices x 4 n-tiles);
// K/64 steps. CVTA/CVTB: that operand streams f32 with on-the-fly bf16 cvt.
// ---------------------------------------------------------------------------
template <bool CVTA, bool CVTB>
__device__ __forceinline__ void gemm_core(
    const void* Asrc, const void* Bsrc, long lda, long ldb, int K,
    int arow0, int brow0, ushort* As, ushort* Bs, floatx4* acc)
{
  const int tid = threadIdx.x;
  const int l = tid & 63, w = tid >> 6;
  const int l15 = l & 15, l4 = l >> 4;
  const int srow = tid >> 3, kg = tid & 7;       // staging slot: row, k-group
  const int ks = kg >> 2, kc = (kg & 3) << 3;    // k-slice, k-offset in slice
  const int dsA = ks * 2560 + kc;                // + row*40

  const float*  Af = (const float*)Asrc;
  const ushort* Ab = (const ushort*)Asrc;
  const float*  Bf = (const float*)Bsrc;
  const ushort* Bb = (const ushort*)Bsrc;

  const long aoff0 = (long)(arow0 + srow) * lda + kg * 8;
  const long aoff1 = (long)(arow0 + 32 + srow) * lda + kg * 8;
  const long boff0 = (long)(brow0 + srow) * ldb + kg * 8;
  const long boff1 = (long)(brow0 + 32 + srow) * ldb + kg * 8;

  short8v a0r, a1r, b0r, b1r;
  float4 fa00, fa01, fa10, fa11, fb00, fb01, fb10, fb11;

  auto LD = [&](int kt) {
    if constexpr (CVTA) {
      fa00 = *(const float4*)(Af + aoff0 + kt);
      fa01 = *(const float4*)(Af + aoff0 + kt + 4);
      fa10 = *(const float4*)(Af + aoff1 + kt);
      fa11 = *(const float4*)(Af + aoff1 + kt + 4);
    } else {
      a0r = *(const short8v*)(Ab + aoff0 + kt);
      a1r = *(const short8v*)(Ab + aoff1 + kt);
    }
    if constexpr (CVTB) {
      fb00 = *(const float4*)(Bf + boff0 + kt);
      fb01 = *(const float4*)(Bf + boff0 + kt + 4);
      fb10 = *(const float4*)(Bf + boff1 + kt);
      fb11 = *(const float4*)(Bf + boff1 + kt + 4);
    } else {
      b0r = *(const short8v*)(Bb + boff0 + kt);
      b1r = *(const short8v*)(Bb + boff1 + kt);
    }
  };
  auto ST = [&]() {
    if constexpr (CVTA) {
      uint4 p0 = {pk2(fa00.x, fa00.y), pk2(fa00.z, fa00.w),
                  pk2(fa01.x, fa01.y), pk2(fa01.z, fa01.w)};
      uint4 p1 = {pk2(fa10.x, fa10.y), pk2(fa10.z, fa10.w),
                  pk2(fa11.x, fa11.y), pk2(fa11.z, fa11.w)};
      *(uint4*)&As[dsA + srow * 40] = p0;
      *(uint4*)&As[dsA + (32 + srow) * 40] = p1;
    } else {
      *(short8v*)&As[dsA + srow * 40] = a0r;
      *(short8v*)&As[dsA + (32 + srow) * 40] = a1r;
    }
    if constexpr (CVTB) {
      uint4 p0 = {pk2(fb00.x, fb00.y), pk2(fb00.z, fb00.w),
                  pk2(fb01.x, fb01.y), pk2(fb01.z, fb01.w)};
      uint4 p1 = {pk2(fb10.x, fb10.y), pk2(fb10.z, fb10.w),
                  pk2(fb11.x, fb11.y), pk2(fb11.z, fb11.w)};
      *(uint4*)&Bs[dsA + srow * 40] = p0;
      *(uint4*)&Bs[dsA + (32 + srow) * 40] = p1;
    } else {
      *(short8v*)&Bs[dsA + srow * 40] = b0r;
      *(short8v*)&Bs[dsA + (32 + srow) * 40] = b1r;
    }
  };

  LD(0);
  for (int kt = 0; kt < K; kt += 64) {
    if (kt) __syncthreads();
    ST();
    __syncthreads();
    if (kt + 64 < K) LD(kt + 64);   // flies under the MFMAs
#pragma unroll
    for (int kk = 0; kk < 2; ++kk) {
      short8v av = *(short8v*)&As[kk * 2560 + (w * 16 + l15) * 40 + l4 * 8];
#pragma unroll
      for (int nt = 0; nt < 4; ++nt) {
        short8v bv = *(short8v*)&Bs[kk * 2560 + (nt * 16 + l15) * 40 + l4 * 8];
        acc[nt] = __builtin_amdgcn_mfma_f32_16x16x32_bf16(av, bv, acc[nt], 0, 0, 0);
      }
    }
  }
}

// ---------------------------------------------------------------------------
// Fused phase-A, 768 blocks, XCD-aligned with energies consumer (id&7 = XCD
// -> b in {2x,2x+1}):
//  ids [0,512):  A1-flipped: E_T[b][h][t] = bf16(exp2(C*(WaT . enc)))
//  ids [512,768): A2: eU[m][h] = exp2(C*(dec . UaT)), f32 row-major
// ---------------------------------------------------------------------------
__global__ __launch_bounds__(256) void gemm_phaseA(
    const float* __restrict__ enc, const ushort* __restrict__ WaT,
    ushort* __restrict__ E_T,
    const float* __restrict__ dec, const ushort* __restrict__ UaT,
    float* __restrict__ eU)
{
  __shared__ __attribute__((aligned(16))) ushort As[5120];
  __shared__ __attribute__((aligned(16))) ushort Bs[5120];

  const int tid = threadIdx.x;
  const int l = tid & 63, w = tid >> 6;
  const int l15 = l & 15, l4 = l >> 4;
  const int id = blockIdx.x;

  floatx4 acc[4] = {};

  if (id < 512) {
    const int x = id & 7, k = id >> 3;
    const int bm = k >> 3;               // h-tile 0..7
    const int bn = x * 8 + (k & 7);      // m-tile 0..63 (b = bn>>2)
    gemm_core<false, true>(WaT, enc, H_, H_, H_, bm * 64, bn * 64, As, Bs, acc);
    const int bb = bn >> 2, t0 = (bn & 3) * 64;
    const int hb = bm * 64 + w * 16 + (l4 << 2);
#pragma unroll
    for (int nt = 0; nt < 4; ++nt) {
      const int t = t0 + nt * 16 + l15;
#pragma unroll
      for (int r = 0; r < 4; ++r)
        E_T[((size_t)bb * H_ + hb + r) * TE_ + t] =
            f2bf(__builtin_amdgcn_exp2f(C_TANH * acc[nt][r]));
    }
  } else {
    const int i2 = id - 512;
    const int x = i2 & 7, k = i2 >> 3;
    const int bm = x * 4 + (k & 3);      // m-tile 0..31 (b = bm>>1)
    const int bn = k >> 2;               // h-tile 0..7
    gemm_core<true, false>(dec, UaT, H_, H_, H_, bm * 64, bn * 64, As, Bs, acc);
    const int growb = bm * 64 + w * 16 + (l4 << 2);
#pragma unroll
    for (int nt = 0; nt < 4; ++nt) {
      const int gcol = bn * 64 + nt * 16 + l15;
#pragma unroll
      for (int r = 0; r < 4; ++r)
        eU[(size_t)(growb + r) * H_ + gcol] =
            __builtin_amdgcn_exp2f(C_TANH * acc[nt][r]);
    }
  }
}

// ---------------------------------------------------------------------------
// Phase-C GEMM: c[b] = eB[b] @ encT[b]^T via the same core. Grid (8,2,16).
// ---------------------------------------------------------------------------
__global__ __launch_bounds__(256) void gemm_ctx(
    const ushort* __restrict__ eB, const ushort* __restrict__ encT,
    float* __restrict__ C)
{
  __shared__ __attribute__((aligned(16))) ushort As[5120];
  __shared__ __attribute__((aligned(16))) ushort Bs[5120];

  const int tid = threadIdx.x;
  const int l = tid & 63, w = tid >> 6;
  const int l15 = l & 15, l4 = l >> 4;
  const long z = blockIdx.z;
  const int bm = blockIdx.y, bn = blockIdx.x;

  floatx4 acc[4] = {};
  gemm_core<false, false>(eB + z * TD_ * TE_, encT + z * (long)H_ * TE_,
                          TE_, TE_, TE_, bm * 64, bn * 64, As, Bs, acc);

  const int growb = bm * 64 + w * 16 + (l4 << 2);
#pragma unroll
  for (int nt = 0; nt < 4; ++nt) {
    const int gcol = bn * 64 + nt * 16 + l15;
#pragma unroll
    for (int r = 0; r < 4; ++r)
      C[(z * TD_ + growb + r) * (long)H_ + gcol] = acc[nt][r];
  }
}

// ---------------------------------------------------------------------------
// Energies + softmax (unchanged control). E_T[b][h][t]=bf16(exp2(C*Ws)),
// eU[b][d][h]=exp2(C*Uh); tanh = 1 - 2*rcp(E*eU+1). 1024 blocks
// (XCD x -> b in {2x,2x+1}), 8 waves; block = (b, 2 d rows); wave w owns
// h in [64w,64w+64) for both d rows.
// ---------------------------------------------------------------------------
__global__ __launch_bounds__(512) void energies_softmax(
    const ushort* __restrict__ E_T, const float* __restrict__ eU,
    const float* __restrict__ Va, float* __restrict__ e_out,
    ushort* __restrict__ eB)
{
  __shared__ float part[2][8][TE_];

  const int tid  = threadIdx.x;
  const int lane = tid & 63;
  const int wv   = __builtin_amdgcn_readfirstlane(tid >> 6);  // h-eighth
  const int id   = blockIdx.x;            // 0..1023
  const int xcd  = id & 7, j = id >> 3;   // XCD x -> b in {2x, 2x+1}
  const int b    = (xcd << 1) | (j >> 6);
  const int d0   = (j & 63) << 1;

  float4 v0 = *(const float4*)(Va + (lane << 2));
  float4 v1 = *(const float4*)(Va + 256 + (lane << 2));
  const float svtot =
      wave_sum(v0.x + v0.y + v0.z + v0.w + v1.x + v1.y + v1.z + v1.w);

  const float* u0 = eU + (size_t)(b * TD_ + d0 + 0) * H_ + wv * 64;
  const float* u1 = eU + (size_t)(b * TD_ + d0 + 1) * H_ + wv * 64;
  const float* vp = Va + wv * 64;
  const ushort* ep = E_T + ((size_t)(b * H_) + wv * 64) * TE_ + (lane << 2);

  float p0[4] = {}, p1[4] = {};

#pragma unroll 4
  for (int h = 0; h < 64; ++h) {
    const float sV = vp[h];
    const float sU0 = u0[h], sU1 = u1[h];
    ushort4 ew = *(const ushort4*)(ep + (size_t)h * TE_);
    float e0 = bf2f(ew.x), e1 = bf2f(ew.y), e2 = bf2f(ew.z), e3 = bf2f(ew.w);
    p0[0] = fmaf(sV, __builtin_amdgcn_rcpf(fmaf(e0, sU0, 1.f)), p0[0]);
    p0[1] = fmaf(sV, __builtin_amdgcn_rcpf(fmaf(e1, sU0, 1.f)), p0[1]);
    p0[2] = fmaf(sV, __builtin_amdgcn_rcpf(fmaf(e2, sU0, 1.f)), p0[2]);
    p0[3] = fmaf(sV, __builtin_amdgcn_rcpf(fmaf(e3, sU0, 1.f)), p0[3]);
    p1[0] = fmaf(sV, __builtin_amdgcn_rcpf(fmaf(e0, sU1, 1.f)), p1[0]);
    p1[1] = fmaf(sV, __builtin_amdgcn_rcpf(fmaf(e1, sU1, 1.f)), p1[1]);
    p1[2] = fmaf(sV, __builtin_amdgcn_rcpf(fmaf(e2, sU1, 1.f)), p1[2]);
    p1[3] = fmaf(sV, __builtin_amdgcn_rcpf(fmaf(e3, sU1, 1.f)), p1[3]);
  }

  *(float4*)&part[0][wv][lane << 2] = *(float4*)p0;
  *(float4*)&part[1][wv][lane << 2] = *(float4*)p1;
  __syncthreads();

  if (wv < 2) {  // wave w -> d = d0 + w
    float l4v[4] = {0.f, 0.f, 0.f, 0.f};
#pragma unroll
    for (int w = 0; w < 8; ++w) {
      float4 q = *(const float4*)&part[wv][w][lane << 2];
      l4v[0] += q.x; l4v[1] += q.y; l4v[2] += q.z; l4v[3] += q.w;
    }
#pragma unroll
    for (int q = 0; q < 4; ++q) l4v[q] = svtot - 2.f * l4v[q];
    float m = wave_max(fmaxf(fmaxf(l4v[0], l4v[1]), fmaxf(l4v[2], l4v[3])));
    float p[4];
    float s = 0.f;
#pragma unroll
    for (int q = 0; q < 4; ++q) {
      p[q] = __builtin_amdgcn_exp2f((l4v[q] - m) * LOG2E);
      s += p[q];
    }
    s = wave_sum(s);
    const float inv = 1.0f / s;
    float4 ov = {p[0] * inv, p[1] * inv, p[2] * inv, p[3] * inv};
    const size_t ro = (size_t)(b * TD_ + d0 + wv) * TE_ + (lane << 2);
    *(float4*)(e_out + ro) = ov;
    ushort4 ob = {f2bf(ov.x), f2bf(ov.y), f2bf(ov.z), f2bf(ov.w)};
    *(ushort4*)(eB + ro) = ob;
  }
}

// ---------------------------------------------------------------------------
extern "C" void kernel_launch(void* const* d_in, const int* in_sizes, int n_in,
                              void* d_out, int out_size, void* d_ws, size_t ws_size,
                              hipStream_t stream) {
  const float* enc = (const float*)d_in[0];  // [B, TE, H]
  const float* dec = (const float*)d_in[1];  // [B, TD, H]
  const float* Wa  = (const float*)d_in[2];  // [H, H]
  const float* Ua  = (const float*)d_in[3];  // [H, H]
  const float* Va  = (const float*)d_in[4];  // [H]

  float* out_c = (float*)d_out;                       // [B, TD, H]
  float* out_e = out_c + (size_t)B_ * TD_ * H_;       // [B, TD, TE]

  char* w8 = (char*)d_ws;                             // 14 MB used
  ushort* E_T  = (ushort*)(w8);                       // [B][H][TE] bf16  4 MB
  float*  eU   = (float*)(w8 + (4u << 20));           // [B][TD][H] f32   4 MB
  ushort* WaT  = (ushort*)(w8 + (8u << 20));          // [H][H]     bf16 .5 MB
  ushort* UaT  = (ushort*)(w8 + (8u << 20) + (512u << 10));
  ushort* encT = (ushort*)(w8 + (9u << 20));          // [B][H][TE] bf16  4 MB
  ushort* eB   = (ushort*)(w8 + (13u << 20));         // [B][TD][TE]bf16  1 MB

  // Prep: transposes only (encT, WaT, UaT)
  prep_T<<<dim3(8, 10, 16), 256, 0, stream>>>(enc, Wa, Ua, encT, WaT, UaT);

  // A1(flipped)+A2 fused, BK=64 dense-MFMA core, XCD-aligned
  gemm_phaseA<<<768, 256, 0, stream>>>(enc, WaT, E_T, dec, UaT, eU);

  // B: energies + softmax -> out_e (f32) + eB (bf16)
  energies_softmax<<<1024, 512, 0, stream>>>(E_T, eU, Va, out_e, eB);

  // C: c[b] = e[b] @ enc[b] via bf16 MFMA (BT = encT)
  gemm_ctx<<<dim3(8, 2, 16), 256, 0, stream>>>(eB, encT, out_c);
}

// Round 12
// 58.522 us; speedup vs baseline: 2.9816x; 1.0022x over previous
//
#include <hip/hip_runtime.h>

// Problem shapes (fixed by setup_inputs)
#define B_  16
#define TE_ 256
#define TD_ 128
#define H_  512

#define C_TANH 2.88539008177792681472f  // 2*log2(e):  tanh(x) = 1 - 2/(exp2(C*x)+1)
#define LOG2E  1.44269504088896340736f

typedef __attribute__((ext_vector_type(8))) short short8v;   // 8 x bf16 (4 VGPR)
typedef __attribute__((ext_vector_type(4))) float floatx4;   // MFMA acc

__device__ __forceinline__ float wave_sum(float v) {
#pragma unroll
  for (int m = 32; m; m >>= 1) v += __shfl_xor(v, m, 64);
  return v;
}
__device__ __forceinline__ float wave_max(float v) {
#pragma unroll
  for (int m = 32; m; m >>= 1) v = fmaxf(v, __shfl_xor(v, m, 64));
  return v;
}
__device__ __forceinline__ ushort f2bf(float f) {  // RNE fp32->bf16
  unsigned u = __builtin_bit_cast(unsigned, f);
  u += 0x7fffu + ((u >> 16) & 1u);
  return (ushort)(u >> 16);
}
__device__ __forceinline__ float bf2f(ushort u) {
  return __builtin_bit_cast(float, (unsigned)u << 16);
}
__device__ __forceinline__ unsigned pk2(float a, float b) {
  return (unsigned)f2bf(a) | ((unsigned)f2bf(b) << 16);
}

// ---------------------------------------------------------------------------
// GEMM core: BM=64 BN=64 BK=64, 4 waves (256 thr), 2-phase reg pipeline.
// LDS per operand: [2 k-slices][64 rows][pitch 40 ushort].
// Operand modes (MA/MB):
//   0 = bf16 row-major [n][k] direct
//   1 = f32  row-major [n][k], bf16-convert during staging
//   2 = f32  [k][n] source, TRANSPOSED during staging (kills prep kernels):
//       thread = (k-pair kp=tid>>3, h-group hg=tid&7); loads 2 adjacent
//       k-rows' float4 pairs, pk2-packs (k,k+1) into b32 LDS writes.
// row0 params: n-dim tile base for that operand (rows for modes 0/1,
// cols for mode 2).
// ---------------------------------------------------------------------------
template <int MA, int MB>
__device__ __forceinline__ void gemm_core(
    const void* Asrc, const void* Bsrc, long lda, long ldb, int K,
    int arow0, int brow0, ushort* As, ushort* Bs, floatx4* acc)
{
  const int tid = threadIdx.x;
  const int l = tid & 63, w = tid >> 6;
  const int l15 = l & 15, l4 = l >> 4;
  // modes 0/1 staging map: two rows (srow, srow+32), 8-elem k-group
  const int srow = tid >> 3, kg = tid & 7;
  const int dsRC = (kg >> 2) * 2560 + ((kg & 3) << 3);   // + row*40
  // mode 2 staging map: k-pair + 8-col group
  const int kp = tid >> 3, hg = tid & 7;                 // kp 0..31, hg 0..7
  const int dsT = (kp >> 4) * 2560 + ((kp << 1) & 31);   // + h*40

  const float*  Af = (const float*)Asrc;
  const ushort* Ab = (const ushort*)Asrc;
  const float*  Bf = (const float*)Bsrc;
  const ushort* Bb = (const ushort*)Bsrc;

  const long aoff0 = (long)(arow0 + srow) * lda + kg * 8;
  const long aoff1 = (long)(arow0 + 32 + srow) * lda + kg * 8;
  const long boff0 = (long)(brow0 + srow) * ldb + kg * 8;
  const long boff1 = (long)(brow0 + 32 + srow) * ldb + kg * 8;

  short8v a0r, a1r, b0r, b1r;
  float4 fa0, fa1, fa2, fa3, fb0, fb1, fb2, fb3;

  auto LD = [&](int kt) {
    if constexpr (MA == 0) {
      a0r = *(const short8v*)(Ab + aoff0 + kt);
      a1r = *(const short8v*)(Ab + aoff1 + kt);
    } else if constexpr (MA == 1) {
      fa0 = *(const float4*)(Af + aoff0 + kt);
      fa1 = *(const float4*)(Af + aoff0 + kt + 4);
      fa2 = *(const float4*)(Af + aoff1 + kt);
      fa3 = *(const float4*)(Af + aoff1 + kt + 4);
    } else {
      const long base = (long)(kt + 2 * kp) * lda + arow0 + hg * 8;
      fa0 = *(const float4*)(Af + base);
      fa1 = *(const float4*)(Af + base + 4);
      fa2 = *(const float4*)(Af + base + lda);
      fa3 = *(const float4*)(Af + base + lda + 4);
    }
    if constexpr (MB == 0) {
      b0r = *(const short8v*)(Bb + boff0 + kt);
      b1r = *(const short8v*)(Bb + boff1 + kt);
    } else if constexpr (MB == 1) {
      fb0 = *(const float4*)(Bf + boff0 + kt);
      fb1 = *(const float4*)(Bf + boff0 + kt + 4);
      fb2 = *(const float4*)(Bf + boff1 + kt);
      fb3 = *(const float4*)(Bf + boff1 + kt + 4);
    } else {
      const long base = (long)(kt + 2 * kp) * ldb + brow0 + hg * 8;
      fb0 = *(const float4*)(Bf + base);
      fb1 = *(const float4*)(Bf + base + 4);
      fb2 = *(const float4*)(Bf + base + ldb);
      fb3 = *(const float4*)(Bf + base + ldb + 4);
    }
  };
  auto ST = [&]() {
    if constexpr (MA == 0) {
      *(short8v*)&As[dsRC + srow * 40] = a0r;
      *(short8v*)&As[dsRC + (32 + srow) * 40] = a1r;
    } else if constexpr (MA == 1) {
      uint4 p0 = {pk2(fa0.x, fa0.y), pk2(fa0.z, fa0.w),
                  pk2(fa1.x, fa1.y), pk2(fa1.z, fa1.w)};
      uint4 p1 = {pk2(fa2.x, fa2.y), pk2(fa2.z, fa2.w),
                  pk2(fa3.x, fa3.y), pk2(fa3.z, fa3.w)};
      *(uint4*)&As[dsRC + srow * 40] = p0;
      *(uint4*)&As[dsRC + (32 + srow) * 40] = p1;
    } else {
      const int h0 = hg * 8;
      *(unsigned*)&As[dsT + (h0 + 0) * 40] = pk2(fa0.x, fa2.x);
      *(unsigned*)&As[dsT + (h0 + 1) * 40] = pk2(fa0.y, fa2.y);
      *(unsigned*)&As[dsT + (h0 + 2) * 40] = pk2(fa0.z, fa2.z);
      *(unsigned*)&As[dsT + (h0 + 3) * 40] = pk2(fa0.w, fa2.w);
      *(unsigned*)&As[dsT + (h0 + 4) * 40] = pk2(fa1.x, fa3.x);
      *(unsigned*)&As[dsT + (h0 + 5) * 40] = pk2(fa1.y, fa3.y);
      *(unsigned*)&As[dsT + (h0 + 6) * 40] = pk2(fa1.z, fa3.z);
      *(unsigned*)&As[dsT + (h0 + 7) * 40] = pk2(fa1.w, fa3.w);
    }
    if constexpr (MB == 0) {
      *(short8v*)&Bs[dsRC + srow * 40] = b0r;
      *(short8v*)&Bs[dsRC + (32 + srow) * 40] = b1r;
    } else if constexpr (MB == 1) {
      uint4 p0 = {pk2(fb0.x, fb0.y), pk2(fb0.z, fb0.w),
                  pk2(fb1.x, fb1.y), pk2(fb1.z, fb1.w)};
      uint4 p1 = {pk2(fb2.x, fb2.y), pk2(fb2.z, fb2.w),
                  pk2(fb3.x, fb3.y), pk2(fb3.z, fb3.w)};
      *(uint4*)&Bs[dsRC + srow * 40] = p0;
      *(uint4*)&Bs[dsRC + (32 + srow) * 40] = p1;
    } else {
      const int h0 = hg * 8;
      *(unsigned*)&Bs[dsT + (h0 + 0) * 40] = pk2(fb0.x, fb2.x);
      *(unsigned*)&Bs[dsT + (h0 + 1) * 40] = pk2(fb0.y, fb2.y);
      *(unsigned*)&Bs[dsT + (h0 + 2) * 40] = pk2(fb0.z, fb2.z);
      *(unsigned*)&Bs[dsT + (h0 + 3) * 40] = pk2(fb0.w, fb2.w);
      *(unsigned*)&Bs[dsT + (h0 + 4) * 40] = pk2(fb1.x, fb3.x);
      *(unsigned*)&Bs[dsT + (h0 + 5) * 40] = pk2(fb1.y, fb3.y);
      *(unsigned*)&Bs[dsT + (h0 + 6) * 40] = pk2(fb1.z, fb3.z);
      *(unsigned*)&Bs[dsT + (h0 + 7) * 40] = pk2(fb1.w, fb3.w);
    }
  };

  LD(0);
  for (int kt = 0; kt < K; kt += 64) {
    if (kt) __syncthreads();
    ST();
    __syncthreads();
    if (kt + 64 < K) LD(kt + 64);   // flies under the MFMAs
#pragma unroll
    for (int kk = 0; kk < 2; ++kk) {
      short8v av = *(short8v*)&As[kk * 2560 + (w * 16 + l15) * 40 + l4 * 8];
#pragma unroll
      for (int nt = 0; nt < 4; ++nt) {
        short8v bv = *(short8v*)&Bs[kk * 2560 + (nt * 16 + l15) * 40 + l4 * 8];
        acc[nt] = __builtin_amdgcn_mfma_f32_16x16x32_bf16(av, bv, acc[nt], 0, 0, 0);
      }
    }
  }
}

// ---------------------------------------------------------------------------
// Fused phase-A, 768 blocks, XCD-aligned with energies consumer (id&7 = XCD
// -> b in {2x,2x+1}). NO pre-transposed weights: Wa/Ua staged transposed.
//  ids [0,512):  A1-flipped: E_T[b][h][t] = bf16(exp2(C*(Wa^T . enc)))
//                A = Wa f32 [k][h] mode2;  B = enc f32 [m][k] mode1
//  ids [512,768): A2: eU[m][h] = exp2(C*(dec . Ua)), f32 row-major
//                A = dec f32 [m][k] mode1; B = Ua f32 [k][h] mode2
// ---------------------------------------------------------------------------
__global__ __launch_bounds__(256) void gemm_phaseA(
    const float* __restrict__ enc, const float* __restrict__ Wa,
    ushort* __restrict__ E_T,
    const float* __restrict__ dec, const float* __restrict__ Ua,
    float* __restrict__ eU)
{
  __shared__ __attribute__((aligned(16))) ushort As[5120];
  __shared__ __attribute__((aligned(16))) ushort Bs[5120];

  const int tid = threadIdx.x;
  const int l = tid & 63, w = tid >> 6;
  const int l15 = l & 15, l4 = l >> 4;
  const int id = blockIdx.x;

  floatx4 acc[4] = {};

  if (id < 512) {
    const int x = id & 7, k = id >> 3;
    const int bm = k >> 3;               // h-tile 0..7
    const int bn = x * 8 + (k & 7);      // m-tile 0..63 (b = bn>>2)
    gemm_core<2, 1>(Wa, enc, H_, H_, H_, bm * 64, bn * 64, As, Bs, acc);
    const int bb = bn >> 2, t0 = (bn & 3) * 64;
    const int hb = bm * 64 + w * 16 + (l4 << 2);
#pragma unroll
    for (int nt = 0; nt < 4; ++nt) {
      const int t = t0 + nt * 16 + l15;
#pragma unroll
      for (int r = 0; r < 4; ++r)
        E_T[((size_t)bb * H_ + hb + r) * TE_ + t] =
            f2bf(__builtin_amdgcn_exp2f(C_TANH * acc[nt][r]));
    }
  } else {
    const int i2 = id - 512;
    const int x = i2 & 7, k = i2 >> 3;
    const int bm = x * 4 + (k & 3);      // m-tile 0..31 (b = bm>>1)
    const int bn = k >> 2;               // h-tile 0..7
    gemm_core<1, 2>(dec, Ua, H_, H_, H_, bm * 64, bn * 64, As, Bs, acc);
    const int growb = bm * 64 + w * 16 + (l4 << 2);
#pragma unroll
    for (int nt = 0; nt < 4; ++nt) {
      const int gcol = bn * 64 + nt * 16 + l15;
#pragma unroll
      for (int r = 0; r < 4; ++r)
        eU[(size_t)(growb + r) * H_ + gcol] =
            __builtin_amdgcn_exp2f(C_TANH * acc[nt][r]);
    }
  }
}

// ---------------------------------------------------------------------------
// Phase-C GEMM: c[b] = eB[b] @ enc[b], enc staged transposed (mode 2).
// Grid (8, 2, 16). A = eB bf16 [d][t]; B = enc f32 [t][h].
// ---------------------------------------------------------------------------
__global__ __launch_bounds__(256) void gemm_ctx(
    const ushort* __restrict__ eB, const float* __restrict__ enc,
    float* __restrict__ C)
{
  __shared__ __attribute__((aligned(16))) ushort As[5120];
  __shared__ __attribute__((aligned(16))) ushort Bs[5120];

  const int tid = threadIdx.x;
  const int l = tid & 63, w = tid >> 6;
  const int l15 = l & 15, l4 = l >> 4;
  const long z = blockIdx.z;
  const int bm = blockIdx.y, bn = blockIdx.x;

  floatx4 acc[4] = {};
  gemm_core<0, 2>(eB + z * TD_ * TE_, enc + z * (long)TE_ * H_,
                  TE_, H_, TE_, bm * 64, bn * 64, As, Bs, acc);

  const int growb = bm * 64 + w * 16 + (l4 << 2);
#pragma unroll
  for (int nt = 0; nt < 4; ++nt) {
    const int gcol = bn * 64 + nt * 16 + l15;
#pragma unroll
    for (int r = 0; r < 4; ++r)
      C[(z * TD_ + growb + r) * (long)H_ + gcol] = acc[nt][r];
  }
}

// ---------------------------------------------------------------------------
// Energies + softmax (unchanged control). E_T[b][h][t]=bf16(exp2(C*Ws)),
// eU[b][d][h]=exp2(C*Uh); tanh = 1 - 2*rcp(E*eU+1). 1024 blocks
// (XCD x -> b in {2x,2x+1}), 8 waves; block = (b, 2 d rows); wave w owns
// h in [64w,64w+64) for both d rows.
// ---------------------------------------------------------------------------
__global__ __launch_bounds__(512) void energies_softmax(
    const ushort* __restrict__ E_T, const float* __restrict__ eU,
    const float* __restrict__ Va, float* __restrict__ e_out,
    ushort* __restrict__ eB)
{
  __shared__ float part[2][8][TE_];

  const int tid  = threadIdx.x;
  const int lane = tid & 63;
  const int wv   = __builtin_amdgcn_readfirstlane(tid >> 6);  // h-eighth
  const int id   = blockIdx.x;            // 0..1023
  const int xcd  = id & 7, j = id >> 3;   // XCD x -> b in {2x, 2x+1}
  const int b    = (xcd << 1) | (j >> 6);
  const int d0   = (j & 63) << 1;

  float4 v0 = *(const float4*)(Va + (lane << 2));
  float4 v1 = *(const float4*)(Va + 256 + (lane << 2));
  const float svtot =
      wave_sum(v0.x + v0.y + v0.z + v0.w + v1.x + v1.y + v1.z + v1.w);

  const float* u0 = eU + (size_t)(b * TD_ + d0 + 0) * H_ + wv * 64;
  const float* u1 = eU + (size_t)(b * TD_ + d0 + 1) * H_ + wv * 64;
  const float* vp = Va + wv * 64;
  const ushort* ep = E_T + ((size_t)(b * H_) + wv * 64) * TE_ + (lane << 2);

  float p0[4] = {}, p1[4] = {};

#pragma unroll 4
  for (int h = 0; h < 64; ++h) {
    const float sV = vp[h];
    const float sU0 = u0[h], sU1 = u1[h];
    ushort4 ew = *(const ushort4*)(ep + (size_t)h * TE_);
    float e0 = bf2f(ew.x), e1 = bf2f(ew.y), e2 = bf2f(ew.z), e3 = bf2f(ew.w);
    p0[0] = fmaf(sV, __builtin_amdgcn_rcpf(fmaf(e0, sU0, 1.f)), p0[0]);
    p0[1] = fmaf(sV, __builtin_amdgcn_rcpf(fmaf(e1, sU0, 1.f)), p0[1]);
    p0[2] = fmaf(sV, __builtin_amdgcn_rcpf(fmaf(e2, sU0, 1.f)), p0[2]);
    p0[3] = fmaf(sV, __builtin_amdgcn_rcpf(fmaf(e3, sU0, 1.f)), p0[3]);
    p1[0] = fmaf(sV, __builtin_amdgcn_rcpf(fmaf(e0, sU1, 1.f)), p1[0]);
    p1[1] = fmaf(sV, __builtin_amdgcn_rcpf(fmaf(e1, sU1, 1.f)), p1[1]);
    p1[2] = fmaf(sV, __builtin_amdgcn_rcpf(fmaf(e2, sU1, 1.f)), p1[2]);
    p1[3] = fmaf(sV, __builtin_amdgcn_rcpf(fmaf(e3, sU1, 1.f)), p1[3]);
  }

  *(float4*)&part[0][wv][lane << 2] = *(float4*)p0;
  *(float4*)&part[1][wv][lane << 2] = *(float4*)p1;
  __syncthreads();

  if (wv < 2) {  // wave w -> d = d0 + w
    float l4v[4] = {0.f, 0.f, 0.f, 0.f};
#pragma unroll
    for (int w = 0; w < 8; ++w) {
      float4 q = *(const float4*)&part[wv][w][lane << 2];
      l4v[0] += q.x; l4v[1] += q.y; l4v[2] += q.z; l4v[3] += q.w;
    }
#pragma unroll
    for (int q = 0; q < 4; ++q) l4v[q] = svtot - 2.f * l4v[q];
    float m = wave_max(fmaxf(fmaxf(l4v[0], l4v[1]), fmaxf(l4v[2], l4v[3])));
    float p[4];
    float s = 0.f;
#pragma unroll
    for (int q = 0; q < 4; ++q) {
      p[q] = __builtin_amdgcn_exp2f((l4v[q] - m) * LOG2E);
      s += p[q];
    }
    s = wave_sum(s);
    const float inv = 1.0f / s;
    float4 ov = {p[0] * inv, p[1] * inv, p[2] * inv, p[3] * inv};
    const size_t ro = (size_t)(b * TD_ + d0 + wv) * TE_ + (lane << 2);
    *(float4*)(e_out + ro) = ov;
    ushort4 ob = {f2bf(ov.x), f2bf(ov.y), f2bf(ov.z), f2bf(ov.w)};
    *(ushort4*)(eB + ro) = ob;
  }
}

// ---------------------------------------------------------------------------
extern "C" void kernel_launch(void* const* d_in, const int* in_sizes, int n_in,
                              void* d_out, int out_size, void* d_ws, size_t ws_size,
                              hipStream_t stream) {
  const float* enc = (const float*)d_in[0];  // [B, TE, H]
  const float* dec = (const float*)d_in[1];  // [B, TD, H]
  const float* Wa  = (const float*)d_in[2];  // [H, H]
  const float* Ua  = (const float*)d_in[3];  // [H, H]
  const float* Va  = (const float*)d_in[4];  // [H]

  float* out_c = (float*)d_out;                       // [B, TD, H]
  float* out_e = out_c + (size_t)B_ * TD_ * H_;       // [B, TD, TE]

  char* w8 = (char*)d_ws;                             // 9 MB used
  ushort* E_T = (ushort*)(w8);                        // [B][H][TE] bf16  4 MB
  float*  eU  = (float*)(w8 + (4u << 20));            // [B][TD][H] f32   4 MB
  ushort* eB  = (ushort*)(w8 + (8u << 20));           // [B][TD][TE]bf16  1 MB

  // A1(flipped)+A2 fused, BK=64 core, transposes folded into staging
  gemm_phaseA<<<768, 256, 0, stream>>>(enc, Wa, E_T, dec, Ua, eU);

  // B: energies + softmax -> out_e (f32) + eB (bf16)
  energies_softmax<<<1024, 512, 0, stream>>>(E_T, eU, Va, out_e, eB);

  // C: c[b] = e[b] @ enc[b] (enc transposed in staging)
  gemm_ctx<<<dim3(8, 2, 16), 256, 0, stream>>>(eB, enc, out_c);
}

// Round 13
// 50.807 us; speedup vs baseline: 3.4343x; 1.1518x over previous
//
#include <hip/hip_runtime.h>

// Problem shapes (fixed by setup_inputs)
#define B_  16
#define TE_ 256
#define TD_ 128
#define H_  512

#define C_TANH 2.88539008177792681472f  // 2*log2(e):  tanh(x) = 1 - 2/(exp2(C*x)+1)
#define LOG2E  1.44269504088896340736f

typedef __attribute__((ext_vector_type(8))) short short8v;   // 8 x bf16 (4 VGPR)
typedef __attribute__((ext_vector_type(4))) float floatx4;   // MFMA acc

__device__ __forceinline__ float wave_sum(float v) {
#pragma unroll
  for (int m = 32; m; m >>= 1) v += __shfl_xor(v, m, 64);
  return v;
}
__device__ __forceinline__ float wave_max(float v) {
#pragma unroll
  for (int m = 32; m; m >>= 1) v = fmaxf(v, __shfl_xor(v, m, 64));
  return v;
}
__device__ __forceinline__ ushort f2bf(float f) {  // RNE fp32->bf16
  unsigned u = __builtin_bit_cast(unsigned, f);
  u += 0x7fffu + ((u >> 16) & 1u);
  return (ushort)(u >> 16);
}
__device__ __forceinline__ float bf2f(ushort u) {
  return __builtin_bit_cast(float, (unsigned)u << 16);
}
__device__ __forceinline__ unsigned pk2(float a, float b) {
  return (unsigned)f2bf(a) | ((unsigned)f2bf(b) << 16);
}

// ---------------------------------------------------------------------------
// GEMM core: BM=64 BN=64 BK=64, 4 waves (256 thr), 2-phase reg pipeline.
// LDS per operand: [2 k-slices][64 rows][pitch 40 ushort].
// Operand modes (MA/MB):
//   0 = bf16 row-major [n][k] direct
//   1 = f32  row-major [n][k], bf16-convert during staging
//   2 = f32  [k][n] source, TRANSPOSED during staging
// ---------------------------------------------------------------------------
template <int MA, int MB>
__device__ __forceinline__ void gemm_core(
    const void* Asrc, const void* Bsrc, long lda, long ldb, int K,
    int arow0, int brow0, ushort* As, ushort* Bs, floatx4* acc)
{
  const int tid = threadIdx.x;
  const int l = tid & 63, w = tid >> 6;
  const int l15 = l & 15, l4 = l >> 4;
  const int srow = tid >> 3, kg = tid & 7;
  const int dsRC = (kg >> 2) * 2560 + ((kg & 3) << 3);   // + row*40
  const int kp = tid >> 3, hg = tid & 7;                 // kp 0..31, hg 0..7
  const int dsT = (kp >> 4) * 2560 + ((kp << 1) & 31);   // + h*40

  const float*  Af = (const float*)Asrc;
  const ushort* Ab = (const ushort*)Asrc;
  const float*  Bf = (const float*)Bsrc;
  const ushort* Bb = (const ushort*)Bsrc;

  const long aoff0 = (long)(arow0 + srow) * lda + kg * 8;
  const long aoff1 = (long)(arow0 + 32 + srow) * lda + kg * 8;
  const long boff0 = (long)(brow0 + srow) * ldb + kg * 8;
  const long boff1 = (long)(brow0 + 32 + srow) * ldb + kg * 8;

  short8v a0r, a1r, b0r, b1r;
  float4 fa0, fa1, fa2, fa3, fb0, fb1, fb2, fb3;

  auto LD = [&](int kt) {
    if constexpr (MA == 0) {
      a0r = *(const short8v*)(Ab + aoff0 + kt);
      a1r = *(const short8v*)(Ab + aoff1 + kt);
    } else if constexpr (MA == 1) {
      fa0 = *(const float4*)(Af + aoff0 + kt);
      fa1 = *(const float4*)(Af + aoff0 + kt + 4);
      fa2 = *(const float4*)(Af + aoff1 + kt);
      fa3 = *(const float4*)(Af + aoff1 + kt + 4);
    } else {
      const long base = (long)(kt + 2 * kp) * lda + arow0 + hg * 8;
      fa0 = *(const float4*)(Af + base);
      fa1 = *(const float4*)(Af + base + 4);
      fa2 = *(const float4*)(Af + base + lda);
      fa3 = *(const float4*)(Af + base + lda + 4);
    }
    if constexpr (MB == 0) {
      b0r = *(const short8v*)(Bb + boff0 + kt);
      b1r = *(const short8v*)(Bb + boff1 + kt);
    } else if constexpr (MB == 1) {
      fb0 = *(const float4*)(Bf + boff0 + kt);
      fb1 = *(const float4*)(Bf + boff0 + kt + 4);
      fb2 = *(const float4*)(Bf + boff1 + kt);
      fb3 = *(const float4*)(Bf + boff1 + kt + 4);
    } else {
      const long base = (long)(kt + 2 * kp) * ldb + brow0 + hg * 8;
      fb0 = *(const float4*)(Bf + base);
      fb1 = *(const float4*)(Bf + base + 4);
      fb2 = *(const float4*)(Bf + base + ldb);
      fb3 = *(const float4*)(Bf + base + ldb + 4);
    }
  };
  auto ST = [&]() {
    if constexpr (MA == 0) {
      *(short8v*)&As[dsRC + srow * 40] = a0r;
      *(short8v*)&As[dsRC + (32 + srow) * 40] = a1r;
    } else if constexpr (MA == 1) {
      uint4 p0 = {pk2(fa0.x, fa0.y), pk2(fa0.z, fa0.w),
                  pk2(fa1.x, fa1.y), pk2(fa1.z, fa1.w)};
      uint4 p1 = {pk2(fa2.x, fa2.y), pk2(fa2.z, fa2.w),
                  pk2(fa3.x, fa3.y), pk2(fa3.z, fa3.w)};
      *(uint4*)&As[dsRC + srow * 40] = p0;
      *(uint4*)&As[dsRC + (32 + srow) * 40] = p1;
    } else {
      const int h0 = hg * 8;
      *(unsigned*)&As[dsT + (h0 + 0) * 40] = pk2(fa0.x, fa2.x);
      *(unsigned*)&As[dsT + (h0 + 1) * 40] = pk2(fa0.y, fa2.y);
      *(unsigned*)&As[dsT + (h0 + 2) * 40] = pk2(fa0.z, fa2.z);
      *(unsigned*)&As[dsT + (h0 + 3) * 40] = pk2(fa0.w, fa2.w);
      *(unsigned*)&As[dsT + (h0 + 4) * 40] = pk2(fa1.x, fa3.x);
      *(unsigned*)&As[dsT + (h0 + 5) * 40] = pk2(fa1.y, fa3.y);
      *(unsigned*)&As[dsT + (h0 + 6) * 40] = pk2(fa1.z, fa3.z);
      *(unsigned*)&As[dsT + (h0 + 7) * 40] = pk2(fa1.w, fa3.w);
    }
    if constexpr (MB == 0) {
      *(short8v*)&Bs[dsRC + srow * 40] = b0r;
      *(short8v*)&Bs[dsRC + (32 + srow) * 40] = b1r;
    } else if constexpr (MB == 1) {
      uint4 p0 = {pk2(fb0.x, fb0.y), pk2(fb0.z, fb0.w),
                  pk2(fb1.x, fb1.y), pk2(fb1.z, fb1.w)};
      uint4 p1 = {pk2(fb2.x, fb2.y), pk2(fb2.z, fb2.w),
                  pk2(fb3.x, fb3.y), pk2(fb3.z, fb3.w)};
      *(uint4*)&Bs[dsRC + srow * 40] = p0;
      *(uint4*)&Bs[dsRC + (32 + srow) * 40] = p1;
    } else {
      const int h0 = hg * 8;
      *(unsigned*)&Bs[dsT + (h0 + 0) * 40] = pk2(fb0.x, fb2.x);
      *(unsigned*)&Bs[dsT + (h0 + 1) * 40] = pk2(fb0.y, fb2.y);
      *(unsigned*)&Bs[dsT + (h0 + 2) * 40] = pk2(fb0.z, fb2.z);
      *(unsigned*)&Bs[dsT + (h0 + 3) * 40] = pk2(fb0.w, fb2.w);
      *(unsigned*)&Bs[dsT + (h0 + 4) * 40] = pk2(fb1.x, fb3.x);
      *(unsigned*)&Bs[dsT + (h0 + 5) * 40] = pk2(fb1.y, fb3.y);
      *(unsigned*)&Bs[dsT + (h0 + 6) * 40] = pk2(fb1.z, fb3.z);
      *(unsigned*)&Bs[dsT + (h0 + 7) * 40] = pk2(fb1.w, fb3.w);
    }
  };

  LD(0);
  for (int kt = 0; kt < K; kt += 64) {
    if (kt) __syncthreads();
    ST();
    __syncthreads();
    if (kt + 64 < K) LD(kt + 64);   // flies under the MFMAs
#pragma unroll
    for (int kk = 0; kk < 2; ++kk) {
      short8v av = *(short8v*)&As[kk * 2560 + (w * 16 + l15) * 40 + l4 * 8];
#pragma unroll
      for (int nt = 0; nt < 4; ++nt) {
        short8v bv = *(short8v*)&Bs[kk * 2560 + (nt * 16 + l15) * 40 + l4 * 8];
        acc[nt] = __builtin_amdgcn_mfma_f32_16x16x32_bf16(av, bv, acc[nt], 0, 0, 0);
      }
    }
  }
}

// ---------------------------------------------------------------------------
// Fused phase-A, 768 blocks, XCD-aligned with energies consumer (id&7 = XCD
// -> b in {2x,2x+1}). Wa/Ua staged transposed on the fly.
// ---------------------------------------------------------------------------
__global__ __launch_bounds__(256) void gemm_phaseA(
    const float* __restrict__ enc, const float* __restrict__ Wa,
    ushort* __restrict__ E_T,
    const float* __restrict__ dec, const float* __restrict__ Ua,
    float* __restrict__ eU)
{
  __shared__ __attribute__((aligned(16))) ushort As[5120];
  __shared__ __attribute__((aligned(16))) ushort Bs[5120];

  const int tid = threadIdx.x;
  const int l = tid & 63, w = tid >> 6;
  const int l15 = l & 15, l4 = l >> 4;
  const int id = blockIdx.x;

  floatx4 acc[4] = {};

  if (id < 512) {
    const int x = id & 7, k = id >> 3;
    const int bm = k >> 3;               // h-tile 0..7
    const int bn = x * 8 + (k & 7);      // m-tile 0..63 (b = bn>>2)
    gemm_core<2, 1>(Wa, enc, H_, H_, H_, bm * 64, bn * 64, As, Bs, acc);
    const int bb = bn >> 2, t0 = (bn & 3) * 64;
    const int hb = bm * 64 + w * 16 + (l4 << 2);
#pragma unroll
    for (int nt = 0; nt < 4; ++nt) {
      const int t = t0 + nt * 16 + l15;
#pragma unroll
      for (int r = 0; r < 4; ++r)
        E_T[((size_t)bb * H_ + hb + r) * TE_ + t] =
            f2bf(__builtin_amdgcn_exp2f(C_TANH * acc[nt][r]));
    }
  } else {
    const int i2 = id - 512;
    const int x = i2 & 7, k = i2 >> 3;
    const int bm = x * 4 + (k & 3);      // m-tile 0..31 (b = bm>>1)
    const int bn = k >> 2;               // h-tile 0..7
    gemm_core<1, 2>(dec, Ua, H_, H_, H_, bm * 64, bn * 64, As, Bs, acc);
    const int growb = bm * 64 + w * 16 + (l4 << 2);
#pragma unroll
    for (int nt = 0; nt < 4; ++nt) {
      const int gcol = bn * 64 + nt * 16 + l15;
#pragma unroll
      for (int r = 0; r < 4; ++r)
        eU[(size_t)(growb + r) * H_ + gcol] =
            __builtin_amdgcn_exp2f(C_TANH * acc[nt][r]);
    }
  }
}

// ---------------------------------------------------------------------------
// Phase-C GEMM: c[b] = eB[b] @ enc[b], enc staged transposed (mode 2).
// ---------------------------------------------------------------------------
__global__ __launch_bounds__(256) void gemm_ctx(
    const ushort* __restrict__ eB, const float* __restrict__ enc,
    float* __restrict__ C)
{
  __shared__ __attribute__((aligned(16))) ushort As[5120];
  __shared__ __attribute__((aligned(16))) ushort Bs[5120];

  const int tid = threadIdx.x;
  const int l = tid & 63, w = tid >> 6;
  const int l15 = l & 15, l4 = l >> 4;
  const long z = blockIdx.z;
  const int bm = blockIdx.y, bn = blockIdx.x;

  floatx4 acc[4] = {};
  gemm_core<0, 2>(eB + z * TD_ * TE_, enc + z * (long)TE_ * H_,
                  TE_, H_, TE_, bm * 64, bn * 64, As, Bs, acc);

  const int growb = bm * 64 + w * 16 + (l4 << 2);
#pragma unroll
  for (int nt = 0; nt < 4; ++nt) {
    const int gcol = bn * 64 + nt * 16 + l15;
#pragma unroll
    for (int r = 0; r < 4; ++r)
      C[(z * TD_ + growb + r) * (long)H_ + gcol] = acc[nt][r];
  }
}

// ---------------------------------------------------------------------------
// Energies + softmax, 4-way h-merged reciprocal (1 rcp per 4 elements):
//   Sum_{i=0..3} V_i/d_i = [(V0 d1 + V1 d0)q + (V2 d3 + V3 d2)p] / (p q),
//   p = d0 d1, q = d2 d3, d_i = 1 + E_i * U_i  (all d_i >= 1, product < 2^52,
//   no overflow; a few ulp rel. error, far under the 5e-3 budget).
// softmax is shift-invariant, so the sum(V) constant is dropped: l = -2p.
// 1024 blocks (XCD x -> b in {2x,2x+1}), 8 waves; block = (b, 2 d rows);
// wave w owns h in [64w,64w+64) for both d rows; lane owns t-quad.
// ---------------------------------------------------------------------------
__global__ __launch_bounds__(512) void energies_softmax(
    const ushort* __restrict__ E_T, const float* __restrict__ eU,
    const float* __restrict__ Va, float* __restrict__ e_out,
    ushort* __restrict__ eB)
{
  __shared__ float part[2][8][TE_];

  const int tid  = threadIdx.x;
  const int lane = tid & 63;
  const int wv   = __builtin_amdgcn_readfirstlane(tid >> 6);  // h-eighth
  const int id   = blockIdx.x;            // 0..1023
  const int xcd  = id & 7, j = id >> 3;   // XCD x -> b in {2x, 2x+1}
  const int b    = (xcd << 1) | (j >> 6);
  const int d0   = (j & 63) << 1;

  const float* u0 = eU + (size_t)(b * TD_ + d0 + 0) * H_ + wv * 64;
  const float* u1 = eU + (size_t)(b * TD_ + d0 + 1) * H_ + wv * 64;
  const float* vp = Va + wv * 64;
  const ushort* ep = E_T + ((size_t)(b * H_) + wv * 64) * TE_ + (lane << 2);

  float p0[4] = {}, p1[4] = {};

#pragma unroll 2
  for (int hq = 0; hq < 16; ++hq) {
    const float4 vq  = *(const float4*)(vp + hq * 4);
    const float4 uq0 = *(const float4*)(u0 + hq * 4);
    const float4 uq1 = *(const float4*)(u1 + hq * 4);
    const ushort4 w0 = *(const ushort4*)(ep + (size_t)(hq * 4 + 0) * TE_);
    const ushort4 w1 = *(const ushort4*)(ep + (size_t)(hq * 4 + 1) * TE_);
    const ushort4 w2 = *(const ushort4*)(ep + (size_t)(hq * 4 + 2) * TE_);
    const ushort4 w3 = *(const ushort4*)(ep + (size_t)(hq * 4 + 3) * TE_);
    const float eh0[4] = {bf2f(w0.x), bf2f(w0.y), bf2f(w0.z), bf2f(w0.w)};
    const float eh1[4] = {bf2f(w1.x), bf2f(w1.y), bf2f(w1.z), bf2f(w1.w)};
    const float eh2[4] = {bf2f(w2.x), bf2f(w2.y), bf2f(w2.z), bf2f(w2.w)};
    const float eh3[4] = {bf2f(w3.x), bf2f(w3.y), bf2f(w3.z), bf2f(w3.w)};
#pragma unroll
    for (int t = 0; t < 4; ++t) {
      {  // d-row 0
        float d1 = fmaf(eh0[t], uq0.x, 1.f);
        float d2 = fmaf(eh1[t], uq0.y, 1.f);
        float d3 = fmaf(eh2[t], uq0.z, 1.f);
        float d4 = fmaf(eh3[t], uq0.w, 1.f);
        float p = d1 * d2, q = d3 * d4;
        float n12 = fmaf(vq.y, d1, vq.x * d2);
        float n34 = fmaf(vq.w, d3, vq.z * d4);
        float N = fmaf(n34, p, n12 * q);
        float r = __builtin_amdgcn_rcpf(p * q);
        p0[t] = fmaf(N, r, p0[t]);
      }
      {  // d-row 1
        float d1 = fmaf(eh0[t], uq1.x, 1.f);
        float d2 = fmaf(eh1[t], uq1.y, 1.f);
        float d3 = fmaf(eh2[t], uq1.z, 1.f);
        float d4 = fmaf(eh3[t], uq1.w, 1.f);
        float p = d1 * d2, q = d3 * d4;
        float n12 = fmaf(vq.y, d1, vq.x * d2);
        float n34 = fmaf(vq.w, d3, vq.z * d4);
        float N = fmaf(n34, p, n12 * q);
        float r = __builtin_amdgcn_rcpf(p * q);
        p1[t] = fmaf(N, r, p1[t]);
      }
    }
  }

  *(float4*)&part[0][wv][lane << 2] = *(float4*)p0;
  *(float4*)&part[1][wv][lane << 2] = *(float4*)p1;
  __syncthreads();

  if (wv < 2) {  // wave w -> d = d0 + w
    float l4v[4] = {0.f, 0.f, 0.f, 0.f};
#pragma unroll
    for (int w = 0; w < 8; ++w) {
      float4 q = *(const float4*)&part[wv][w][lane << 2];
      l4v[0] += q.x; l4v[1] += q.y; l4v[2] += q.z; l4v[3] += q.w;
    }
#pragma unroll
    for (int q = 0; q < 4; ++q) l4v[q] = -2.f * l4v[q];   // shift-invariant
    float m = wave_max(fmaxf(fmaxf(l4v[0], l4v[1]), fmaxf(l4v[2], l4v[3])));
    float p[4];
    float s = 0.f;
#pragma unroll
    for (int q = 0; q < 4; ++q) {
      p[q] = __builtin_amdgcn_exp2f((l4v[q] - m) * LOG2E);
      s += p[q];
    }
    s = wave_sum(s);
    const float inv = 1.0f / s;
    float4 ov = {p[0] * inv, p[1] * inv, p[2] * inv, p[3] * inv};
    const size_t ro = (size_t)(b * TD_ + d0 + wv) * TE_ + (lane << 2);
    *(float4*)(e_out + ro) = ov;
    ushort4 ob = {f2bf(ov.x), f2bf(ov.y), f2bf(ov.z), f2bf(ov.w)};
    *(ushort4*)(eB + ro) = ob;
  }
}

// ---------------------------------------------------------------------------
extern "C" void kernel_launch(void* const* d_in, const int* in_sizes, int n_in,
                              void* d_out, int out_size, void* d_ws, size_t ws_size,
                              hipStream_t stream) {
  const float* enc = (const float*)d_in[0];  // [B, TE, H]
  const float* dec = (const float*)d_in[1];  // [B, TD, H]
  const float* Wa  = (const float*)d_in[2];  // [H, H]
  const float* Ua  = (const float*)d_in[3];  // [H, H]
  const float* Va  = (const float*)d_in[4];  // [H]

  float* out_c = (float*)d_out;                       // [B, TD, H]
  float* out_e = out_c + (size_t)B_ * TD_ * H_;       // [B, TD, TE]

  char* w8 = (char*)d_ws;                             // 9 MB used
  ushort* E_T = (ushort*)(w8);                        // [B][H][TE] bf16  4 MB
  float*  eU  = (float*)(w8 + (4u << 20));            // [B][TD][H] f32   4 MB
  ushort* eB  = (ushort*)(w8 + (8u << 20));           // [B][TD][TE]bf16  1 MB

  // A1(flipped)+A2 fused, BK=64 core, transposes folded into staging
  gemm_phaseA<<<768, 256, 0, stream>>>(enc, Wa, E_T, dec, Ua, eU);

  // B: energies + softmax (4-way h-merged rcp) -> out_e (f32) + eB (bf16)
  energies_softmax<<<1024, 512, 0, stream>>>(E_T, eU, Va, out_e, eB);

  // C: c[b] = e[b] @ enc[b] (enc transposed in staging)
  gemm_ctx<<<dim3(8, 2, 16), 256, 0, stream>>>(eB, enc, out_c);
}